// Round 13
// baseline (692.471 us; speedup 1.0000x reference)
//
#include <hip/hip_runtime.h>

#define NCC 1024
#define MODIN 198
#define MODOUT 68
#define HMODL 128

typedef __attribute__((ext_vector_type(8))) short s8v;   // 8 bf16 = 4 VGPR
typedef __attribute__((ext_vector_type(4))) float f4v;   // MFMA acc
typedef unsigned short ushort_t;
typedef unsigned int uint_t;

// ws layout (ushort elems): sw1 @0 (32768), sw2 @32768 (16384), mw1 @49152 (16384), mw2 @65536 (16384)
#define OFF_SW1 0
#define OFF_SW2 32768
#define OFF_MW1 49152
#define OFF_MW2 65536
#define FEATS_BYTE_OFF 262144   // feats: 8192 cells x 132 f32

__device__ __forceinline__ float fast_tanh(float x) {
    const float e = __builtin_amdgcn_exp2f(x * 2.885390081777927f);   // e^{2x}
    const float r = __builtin_amdgcn_rcpf(e + 1.f);
    return fmaf(-2.f, r, 1.f);
}
__device__ __forceinline__ float fast_sigmoid(float x) {
    const float e = __builtin_amdgcn_exp2f(x * -1.4426950408889634f);
    return __builtin_amdgcn_rcpf(e + 1.f);
}
__device__ __forceinline__ ushort_t f2bf(float x) {   // RNE f32->bf16
    uint_t u = __builtin_bit_cast(uint_t, x);
    u += 0x7FFFu + ((u >> 16) & 1u);
    return (ushort_t)(u >> 16);
}
__device__ __forceinline__ uint_t pk2(float a, float b) {
    return (uint_t)f2bf(a) | ((uint_t)f2bf(b) << 16);
}
// XOR swizzle on LDS byte offsets (16B granule)
#define SWZ(byteoff, row) ((byteoff) ^ (((row) & 7) << 4))

// ---------------------------------------------------------------------------
// Kernel 0: convert the 4 shared MLP weight matrices to bf16 once per launch
// ---------------------------------------------------------------------------
__global__ __launch_bounds__(256)
void mg_cvtw(const float* __restrict__ sw1, const float* __restrict__ sw2,
             const float* __restrict__ mw1, const float* __restrict__ mw2,
             ushort_t* __restrict__ o) {
    const int i = blockIdx.x * 256 + threadIdx.x;   // grid 320 -> 81920 exact
    float v;
    if (i < 32768)      v = sw1[i];
    else if (i < 49152) v = sw2[i - 32768];
    else if (i < 65536) v = mw1[i - 49152];
    else                v = mw2[i - 65536];
    o[i] = f2bf(v);
}

// ---------------------------------------------------------------------------
// Kernel 0b: inject[b,c,o] = x[b,c,:] . iw[g(c)][o,:] + ib[g(c)][o]
// Output -> first 1KB of each out_h tile (P1 reads it, state epilogue overwrites).
// ---------------------------------------------------------------------------
__global__ __launch_bounds__(256, 4)
void mg_inject(const float* __restrict__ xp, const float* __restrict__ iw,
               const float* __restrict__ ibias, const int* __restrict__ c2g,
               float* __restrict__ injb) {
    const int c = blockIdx.x, t = threadIdx.x;
    const int g = c2g[c];
    __shared__ float s_x[8][64];
    for (int idx = t; idx < 512; idx += 256)
        s_x[idx >> 6][idx & 63] = xp[(size_t)(idx >> 6) * (NCC * 64) + c * 64 + (idx & 63)];
    __syncthreads();
    const float* wrow = iw + (size_t)g * 16384 + t * 64;
    float a0 = 0.f, a1 = 0.f, a2 = 0.f, a3 = 0.f, a4 = 0.f, a5 = 0.f, a6 = 0.f, a7 = 0.f;
    #pragma unroll
    for (int i = 0; i < 64; i += 4) {
        const float4 w4 = *(const float4*)(wrow + i);
        const float4 x0 = *(const float4*)&s_x[0][i];
        const float4 x1 = *(const float4*)&s_x[1][i];
        const float4 x2 = *(const float4*)&s_x[2][i];
        const float4 x3 = *(const float4*)&s_x[3][i];
        const float4 x4 = *(const float4*)&s_x[4][i];
        const float4 x5 = *(const float4*)&s_x[5][i];
        const float4 x6 = *(const float4*)&s_x[6][i];
        const float4 x7 = *(const float4*)&s_x[7][i];
        a0 = fmaf(w4.x, x0.x, a0); a0 = fmaf(w4.y, x0.y, a0); a0 = fmaf(w4.z, x0.z, a0); a0 = fmaf(w4.w, x0.w, a0);
        a1 = fmaf(w4.x, x1.x, a1); a1 = fmaf(w4.y, x1.y, a1); a1 = fmaf(w4.z, x1.z, a1); a1 = fmaf(w4.w, x1.w, a1);
        a2 = fmaf(w4.x, x2.x, a2); a2 = fmaf(w4.y, x2.y, a2); a2 = fmaf(w4.z, x2.z, a2); a2 = fmaf(w4.w, x2.w, a2);
        a3 = fmaf(w4.x, x3.x, a3); a3 = fmaf(w4.y, x3.y, a3); a3 = fmaf(w4.z, x3.z, a3); a3 = fmaf(w4.w, x3.w, a3);
        a4 = fmaf(w4.x, x4.x, a4); a4 = fmaf(w4.y, x4.y, a4); a4 = fmaf(w4.z, x4.z, a4); a4 = fmaf(w4.w, x4.w, a4);
        a5 = fmaf(w4.x, x5.x, a5); a5 = fmaf(w4.y, x5.y, a5); a5 = fmaf(w4.z, x5.z, a5); a5 = fmaf(w4.w, x5.w, a5);
        a6 = fmaf(w4.x, x6.x, a6); a6 = fmaf(w4.y, x6.y, a6); a6 = fmaf(w4.z, x6.z, a6); a6 = fmaf(w4.w, x6.w, a6);
        a7 = fmaf(w4.x, x7.x, a7); a7 = fmaf(w4.y, x7.y, a7); a7 = fmaf(w4.z, x7.z, a7); a7 = fmaf(w4.w, x7.w, a7);
    }
    const float bv = ibias[g * 256 + t];
    const float acc[8] = {a0, a1, a2, a3, a4, a5, a6, a7};
    #pragma unroll
    for (int b = 0; b < 8; b++)
        injb[((size_t)b * NCC + c) * 4096 + t] = acc[b] + bv;
}

// ---------------------------------------------------------------------------
// Kernel 1: per (b, cell) block; 1024 threads = 16 waves; 6 barriers (round-5
// structure). Work split across 16 waves:
//   P3/P5: wave w owns hid cols [16w, 16w+16)   (1 ct x 4 rt)
//   P1/P4/P6: d-group = w&3 (16 cols), row-quarter rh = w>>2 (1 rt)
// 2 blocks/CU x 16 waves = 32 waves/CU = 8 waves/SIMD (hardware max).
// launch_bounds(1024,8) caps VGPR at 64 — proven adequate at 2x this
// per-wave state in round 12 (VGPR=64, zero spill traffic).
// mfma_f32_16x16x32_bf16: A row=lane&15, k=(lane>>4)*8+j; B col=lane&15,
// k contiguous from [N][K]; D col=lane&15, row=(lane>>4)*4+reg.
// ---------------------------------------------------------------------------
__global__ __launch_bounds__(1024, 8)
void mg_cell_kernel(
    const float* __restrict__ hp,   const float* __restrict__ msgp,
    const float* __restrict__ Wp,   const float* __restrict__ decayp,
    const float* __restrict__ bglp, const float* __restrict__ nidp,
    const float* __restrict__ sb1,  const float* __restrict__ sgs1,
    const float* __restrict__ sgb1, const float* __restrict__ sb2,
    const float* __restrict__ sgs2, const float* __restrict__ sgb2,
    const float* __restrict__ mb1,  const float* __restrict__ mgs1,
    const float* __restrict__ mgb1, const float* __restrict__ mb2,
    const float* __restrict__ mgs2, const float* __restrict__ mgb2,
    const int*   __restrict__ c2g,  const ushort_t* __restrict__ wb,
    float* __restrict__ out_read, float* __restrict__ out_h,
    float* __restrict__ out_msg,  float* __restrict__ wsf)
{
    const int t  = threadIdx.x;
    const int bc = blockIdx.x;
    const int b  = bc >> 10, c = bc & 1023;
    const int gh = c >> 5, gwc = c & 31;
    const int lane = t & 63, w = t >> 6;      // w in 0..15
    const int cl = lane & 15, q = lane >> 4;
    const int g  = c2g[c];
    const size_t tile = (size_t)bc * 4096;

    __shared__ ushort_t sHid[16384];   // [64][256] bf16 32KB; first 16KB overlays sW|sMsgT
    __shared__ ushort_t sIn[8192];     // [64][128] bf16: [received/h_new | h]
    __shared__ float s_scr[512];       // border [0:256); later h-parts[4][64] @0, m-parts[4][64] @256
    __shared__ float s_dec[64];
    __shared__ float s_wsum[16];
    __shared__ float s_dsum;

    ushort_t* sW    = sHid;            // [64][64], row stride 128B
    ushort_t* sMsgT = sHid + 4096;     // [64 d][64 m]

    // ================= P0: staging + border + decay =================
    {   // W -> sW bf16 (+ sum|W|): n = t>>4, 4 cols each (1024 thr x 4 = 4096)
        const int n = t >> 4, m0 = (t & 15) * 4;
        const float4 v = *(const float4*)(Wp + tile + (size_t)n * 64 + m0);
        float wsum = fabsf(v.x) + fabsf(v.y) + fabsf(v.z) + fabsf(v.w);
        *(uint_t*)((char*)sW + SWZ(n * 128 + (m0 + 0) * 2, n)) = pk2(v.x, v.y);
        *(uint_t*)((char*)sW + SWZ(n * 128 + (m0 + 2) * 2, n)) = pk2(v.z, v.w);
        #pragma unroll
        for (int off = 32; off > 0; off >>= 1) wsum += __shfl_down(wsum, off);
        if (lane == 0) s_wsum[w] = wsum;
    }
    {   // msg^T -> sMsgT bf16 (one float4 per thread)
        const int m = t >> 4, d0 = (t & 15) * 4;
        const float4 v = *(const float4*)(msgp + tile + (size_t)m * 64 + d0);
        *(ushort_t*)((char*)sMsgT + SWZ((d0 + 0) * 128 + m * 2, d0 + 0)) = f2bf(v.x);
        *(ushort_t*)((char*)sMsgT + SWZ((d0 + 1) * 128 + m * 2, d0 + 1)) = f2bf(v.y);
        *(ushort_t*)((char*)sMsgT + SWZ((d0 + 2) * 128 + m * 2, d0 + 2)) = f2bf(v.z);
        *(ushort_t*)((char*)sMsgT + SWZ((d0 + 3) * 128 + m * 2, d0 + 3)) = f2bf(v.w);
    }
    {   // h -> sIn[:,64:128] bf16 (one float4 per thread)
        const int n = t >> 4, d0 = (t & 15) * 4;
        const float4 v = *(const float4*)(hp + tile + (size_t)n * 64 + d0);
        *(uint_t*)((char*)sIn + SWZ(n * 256 + (64 + d0) * 2, n))     = pk2(v.x, v.y);
        *(uint_t*)((char*)sIn + SWZ(n * 256 + (64 + d0 + 2) * 2, n)) = pk2(v.z, v.w);
    }
    if (t < 256) {   // gated border incoming: wave p = w (0..3)
        const int p = w, dd = lane;
        int ok, nc2, qq;
        if      (p == 0) { ok = (gh > 0);   nc2 = c - 32; qq = 1; }
        else if (p == 1) { ok = (gh < 31);  nc2 = c + 32; qq = 0; }
        else if (p == 2) { ok = (gwc > 0);  nc2 = c - 1;  qq = 3; }
        else             { ok = (gwc < 31); nc2 = c + 1;  qq = 2; }
        float v = 0.f;
        if (ok) v = msgp[((size_t)b * NCC + nc2) * 4096 + (8 + qq) * 64 + dd];
        s_scr[p * 64 + dd] = fast_sigmoid(bglp[(size_t)bc * 4 + p]) * v;
    }
    if (w == 4) {   // decay sigmoid table + logit sum
        const float dl = decayp[(size_t)bc * 64 + lane];
        s_dec[lane] = fast_sigmoid(dl);
        float v = dl;
        #pragma unroll
        for (int off = 32; off > 0; off >>= 1) v += __shfl_down(v, off);
        if (lane == 0) s_dsum = v;
    }
    __syncthreads();   // B1

    const f4v fzero = {0.f, 0.f, 0.f, 0.f};
    const int d  = 16 * (w & 3) + cl;   // d-column for P1/P4/P6
    const int rh = w >> 2;              // row-quarter (0..3) for P1/P4/P6

    // ========== P1: W@msg (MFMA) + inject(precomputed) + border -> sIn[:,0:64] ==========
    {
        f4v wm = fzero;
        float injv[4] = {0.f, 0.f, 0.f, 0.f};
        if (rh == 0 && q == 0) {
            #pragma unroll
            for (int r = 0; r < 4; r++) injv[r] = out_h[tile + r * 64 + d];
        }
        __builtin_amdgcn_s_setprio(1);
        #pragma unroll
        for (int ks = 0; ks < 2; ks++) {
            const int k0 = ks * 32 + q * 8;
            const s8v bf = *(const s8v*)((const char*)sMsgT + SWZ(d * 128 + k0 * 2, d));
            const int ar = rh * 16 + cl;
            const s8v af = *(const s8v*)((const char*)sW + SWZ(ar * 128 + k0 * 2, ar));
            wm = __builtin_amdgcn_mfma_f32_16x16x32_bf16(af, bf, wm, 0, 0, 0);
        }
        __builtin_amdgcn_s_setprio(0);
        #pragma unroll
        for (int r = 0; r < 4; r++) {
            const int n = rh * 16 + q * 4 + r;
            float v = wm[r];
            if (n < 4)                 v += injv[r];
            else if (n >= 8 && n < 12) v += s_scr[(n - 8) * 64 + d];
            *(ushort_t*)((char*)sIn + SWZ(n * 256 + d * 2, n)) = f2bf(v);
        }
    }
    __syncthreads();   // B2 (P1's sW/sMsgT reads done -> sHid overlay safe)

    // ===== P3: state L1 [64x128]@[128x256]^T -> sHid; wave w: cols [16w,16w+16) =====
    {
        f4v acc[4] = {fzero, fzero, fzero, fzero};
        const ushort_t* wb1 = wb + OFF_SW1;
        const int hcol = 16 * w + cl;
        __builtin_amdgcn_s_setprio(1);
        #pragma unroll
        for (int ks = 0; ks < 4; ks++) {
            const int k0 = ks * 32 + q * 8;
            const s8v bf = *(const s8v*)(wb1 + (size_t)hcol * 128 + k0);
            #pragma unroll
            for (int rt = 0; rt < 4; rt++) {
                const int ar = rt * 16 + cl;
                const s8v af = *(const s8v*)((const char*)sIn + SWZ(ar * 256 + k0 * 2, ar));
                acc[rt] = __builtin_amdgcn_mfma_f32_16x16x32_bf16(af, bf, acc[rt], 0, 0, 0);
            }
        }
        __builtin_amdgcn_s_setprio(0);
        const float b1 = sb1[hcol], g1 = sgs1[g * 256 + hcol], o1 = sgb1[g * 256 + hcol];
        #pragma unroll
        for (int rt = 0; rt < 4; rt++)
            #pragma unroll
            for (int r = 0; r < 4; r++) {
                const int n = rt * 16 + q * 4 + r;
                const float vv = fast_tanh(fmaf(acc[rt][r] + b1, g1, o1));
                *(ushort_t*)((char*)sHid + SWZ(n * 512 + hcol * 2, n)) = f2bf(vv);
            }
    }
    __syncthreads();   // B3

    // ===== P4: state L2 -> cand -> h_new (global + sIn bf16) + h_mean partials =====
    {
        f4v a2[2] = {fzero, fzero};
        const ushort_t* wb2 = wb + OFF_SW2;
        __builtin_amdgcn_s_setprio(1);
        #pragma unroll
        for (int ks = 0; ks < 8; ks++) {
            const int k0 = ks * 32 + q * 8;
            const s8v bf = *(const s8v*)(wb2 + (size_t)d * 256 + k0);
            const int ar = rh * 16 + cl;
            const s8v af = *(const s8v*)((const char*)sHid + SWZ(ar * 512 + k0 * 2, ar));
            a2[ks & 1] = __builtin_amdgcn_mfma_f32_16x16x32_bf16(af, bf, a2[ks & 1], 0, 0, 0);
        }
        __builtin_amdgcn_s_setprio(0);
        const float b2 = sb2[d], g2 = sgs2[g * 64 + d], o2 = sgb2[g * 64 + d];
        float hsum = 0.f;
        #pragma unroll
        for (int r = 0; r < 4; r++) {
            const int n = rh * 16 + q * 4 + r;
            const float cand = fast_tanh(fmaf(a2[0][r] + a2[1][r] + b2, g2, o2));
            const ushort_t hu = *(const ushort_t*)((const char*)sIn + SWZ(n * 256 + (64 + d) * 2, n));
            const float hv = __builtin_bit_cast(float, (uint_t)hu << 16);
            const float hn = fmaf(s_dec[n], hv - cand, cand);   // dec*h + (1-dec)*cand
            out_h[tile + (size_t)n * 64 + d] = hn;
            *(ushort_t*)((char*)sIn + SWZ(n * 256 + d * 2, n)) = f2bf(hn);
            hsum += hn;
        }
        hsum += __shfl_xor(hsum, 16);
        hsum += __shfl_xor(hsum, 32);
        if (q == 0) s_scr[rh * 64 + d] = hsum;   // h-part bands [0:256)
    }
    __syncthreads();   // B4: h_new in sIn visible

    // ===== P5: msg L1 [64x64]@[64x256]^T -> sHid; wave w: cols [16w,16w+16) =====
    {
        f4v acc[4] = {fzero, fzero, fzero, fzero};
        const ushort_t* wm1 = wb + OFF_MW1;
        const int hcol = 16 * w + cl;
        __builtin_amdgcn_s_setprio(1);
        #pragma unroll
        for (int ks = 0; ks < 2; ks++) {
            const int k0 = ks * 32 + q * 8;
            const s8v bf = *(const s8v*)(wm1 + (size_t)hcol * 64 + k0);
            #pragma unroll
            for (int rt = 0; rt < 4; rt++) {
                const int ar = rt * 16 + cl;
                const s8v af = *(const s8v*)((const char*)sIn + SWZ(ar * 256 + k0 * 2, ar));
                acc[rt] = __builtin_amdgcn_mfma_f32_16x16x32_bf16(af, bf, acc[rt], 0, 0, 0);
            }
        }
        __builtin_amdgcn_s_setprio(0);
        const float b1 = mb1[hcol], g1 = mgs1[g * 256 + hcol], o1 = mgb1[g * 256 + hcol];
        #pragma unroll
        for (int rt = 0; rt < 4; rt++)
            #pragma unroll
            for (int r = 0; r < 4; r++) {
                const int n = rt * 16 + q * 4 + r;
                const float vv = fast_tanh(fmaf(acc[rt][r] + b1, g1, o1));
                *(ushort_t*)((char*)sHid + SWZ(n * 512 + hcol * 2, n)) = f2bf(vv);
            }
    }
    __syncthreads();   // B5

    // ========== P6: msg L2 -> msg_new (+nid), msg_mean partials, readout ==========
    {
        float nv[4];
        #pragma unroll
        for (int r = 0; r < 4; r++) {
            const int n = rh * 16 + q * 4 + r;
            nv[r] = nidp[(size_t)c * 4096 + (size_t)n * 64 + d];
        }
        f4v a6[2] = {fzero, fzero};
        const ushort_t* wm2 = wb + OFF_MW2;
        __builtin_amdgcn_s_setprio(1);
        #pragma unroll
        for (int ks = 0; ks < 8; ks++) {
            const int k0 = ks * 32 + q * 8;
            const s8v bf = *(const s8v*)(wm2 + (size_t)d * 256 + k0);
            const int ar = rh * 16 + cl;
            const s8v af = *(const s8v*)((const char*)sHid + SWZ(ar * 512 + k0 * 2, ar));
            a6[ks & 1] = __builtin_amdgcn_mfma_f32_16x16x32_bf16(af, bf, a6[ks & 1], 0, 0, 0);
        }
        __builtin_amdgcn_s_setprio(0);
        const float b2 = mb2[d], g2 = mgs2[g * 64 + d], o2 = mgb2[g * 64 + d];
        float msum = 0.f, ro = 0.f;
        #pragma unroll
        for (int r = 0; r < 4; r++) {
            const int n = rh * 16 + q * 4 + r;
            const float mv = fast_tanh(fmaf(a6[0][r] + a6[1][r] + b2, g2, o2)) + nv[r];
            out_msg[tile + (size_t)n * 64 + d] = mv;
            msum += mv;
            ro += mv;   // meaningful only for (rh==0, q==1): rows 4..7
        }
        msum += __shfl_xor(msum, 16);
        msum += __shfl_xor(msum, 32);
        if (q == 0) s_scr[256 + rh * 64 + d] = msum;   // m-part bands [256:512)
        if (rh == 0 && q == 1) out_read[((size_t)b * NCC + c) * 64 + d] = ro * 0.5f;
    }
    __syncthreads();   // B6

    // ================= P7: feats record (130 values) =================
    if (t < 132) {
        float v = 0.f;
        if (t < 64) {
            v = (s_scr[t] + s_scr[64 + t] + s_scr[128 + t] + s_scr[192 + t]) * (1.f / 64.f);
        } else if (t < 128) {
            const int dd = t - 64;
            v = (s_scr[256 + dd] + s_scr[320 + dd] + s_scr[384 + dd] + s_scr[448 + dd]) * (1.f / 64.f);
        } else if (t == 128) {
            float s = 0.f;
            #pragma unroll
            for (int ww = 0; ww < 16; ww++) s += s_wsum[ww];
            v = s * (1.f / 4096.f);
        } else if (t == 129) v = s_dsum * (1.f / 64.f);
        wsf[(size_t)bc * 132 + t] = v;
    }
}

// ---------------------------------------------------------------------------
// Kernel 2: per-cell modulation MLP (distinct weights per cell)
// ---------------------------------------------------------------------------
__global__ __launch_bounds__(256, 2)
void mg_mod_kernel(
    const float* __restrict__ wsf,   const float* __restrict__ modw1,
    const float* __restrict__ modb1, const float* __restrict__ modw2,
    const float* __restrict__ modb2, const float* __restrict__ ctxp,
    const float* __restrict__ bglp,  float* __restrict__ out_ctx,
    float* __restrict__ out_bg)
{
    const int c = blockIdx.x;
    const int t = threadIdx.x;
    __shared__ float s_f[8][MODIN];
    __shared__ float s_h2[8][HMODL];

    for (int k = t; k < 8 * MODIN; k += 256) {
        const int b = k / MODIN, f = k - b * MODIN;
        float v;
        if (f < 130)      v = wsf[((size_t)b * NCC + c) * 132 + f];
        else if (f < 194) v = ctxp[((size_t)b * NCC + c) * 64 + (f - 130)];
        else              v = bglp[((size_t)b * NCC + c) * 4 + (f - 194)];
        s_f[b][f] = v;
    }
    __syncthreads();

    {
        const int hh = t & 127, bh = (t >> 7) * 4;
        float a0 = 0.f, a1 = 0.f, a2 = 0.f, a3 = 0.f;
        const float* wp = modw1 + (size_t)c * MODIN * HMODL + hh;
        for (int f = 0; f < MODIN; f++) {
            const float wv = wp[(size_t)f * HMODL];
            a0 = fmaf(s_f[bh + 0][f], wv, a0);
            a1 = fmaf(s_f[bh + 1][f], wv, a1);
            a2 = fmaf(s_f[bh + 2][f], wv, a2);
            a3 = fmaf(s_f[bh + 3][f], wv, a3);
        }
        const float bv = modb1[(size_t)c * HMODL + hh];
        s_h2[bh + 0][hh] = fast_tanh(a0 + bv);
        s_h2[bh + 1][hh] = fast_tanh(a1 + bv);
        s_h2[bh + 2][hh] = fast_tanh(a2 + bv);
        s_h2[bh + 3][hh] = fast_tanh(a3 + bv);
    }
    __syncthreads();

    for (int idx = t; idx < 8 * MODOUT; idx += 256) {
        const int b = idx / MODOUT, o = idx - b * MODOUT;
        float acc = modb2[(size_t)c * MODOUT + o];
        const float* wp = modw2 + (size_t)c * HMODL * MODOUT + o;
        const float* hrow = s_h2[b];
        for (int hh = 0; hh < HMODL; hh++)
            acc = fmaf(hrow[hh], wp[(size_t)hh * MODOUT], acc);
        if (o < 64)
            out_ctx[((size_t)b * NCC + c) * 64 + o] =
                ctxp[((size_t)b * NCC + c) * 64 + o] + acc;
        else
            out_bg[((size_t)b * NCC + c) * 4 + (o - 64)] =
                bglp[((size_t)b * NCC + c) * 4 + (o - 64)] + acc;
    }
}

extern "C" void kernel_launch(void* const* d_in, const int* in_sizes, int n_in,
                              void* d_out, int out_size, void* d_ws, size_t ws_size,
                              hipStream_t stream) {
    const float* xp     = (const float*)d_in[0];
    const float* hp     = (const float*)d_in[1];
    const float* msgp   = (const float*)d_in[2];
    const float* Wp     = (const float*)d_in[3];
    const float* decayp = (const float*)d_in[4];
    const float* ctxp   = (const float*)d_in[5];
    const float* bglp   = (const float*)d_in[6];
    const float* nidp   = (const float*)d_in[7];
    const float* sw1    = (const float*)d_in[8];
    const float* sb1    = (const float*)d_in[9];
    const float* sgs1   = (const float*)d_in[10];
    const float* sgb1   = (const float*)d_in[11];
    const float* sw2    = (const float*)d_in[12];
    const float* sb2    = (const float*)d_in[13];
    const float* sgs2   = (const float*)d_in[14];
    const float* sgb2   = (const float*)d_in[15];
    const float* mw1    = (const float*)d_in[16];
    const float* mb1    = (const float*)d_in[17];
    const float* mgs1   = (const float*)d_in[18];
    const float* mgb1   = (const float*)d_in[19];
    const float* mw2    = (const float*)d_in[20];
    const float* mb2    = (const float*)d_in[21];
    const float* mgs2   = (const float*)d_in[22];
    const float* mgb2   = (const float*)d_in[23];
    const float* iw     = (const float*)d_in[24];
    const float* ibias  = (const float*)d_in[25];
    const float* modw1  = (const float*)d_in[26];
    const float* modb1  = (const float*)d_in[27];
    const float* modw2  = (const float*)d_in[28];
    const float* modb2  = (const float*)d_in[29];
    const int*   c2g    = (const int*)d_in[30];

    float* out      = (float*)d_out;
    float* out_read = out;                 // 524288
    float* out_h    = out_read + 524288;   // 33554432
    float* out_msg  = out_h + 33554432;    // 33554432
    float* out_ctx  = out_msg + 33554432;  // 524288
    float* out_bg   = out_ctx + 524288;    // 32768

    ushort_t* wb  = (ushort_t*)d_ws;                          // 160KB bf16 weights
    float*    wsf = (float*)((char*)d_ws + FEATS_BYTE_OFF);   // 8192 x 132 f32

    mg_cvtw<<<320, 256, 0, stream>>>(sw1, sw2, mw1, mw2, wb);

    // inject -> head of each out_h tile (read by P1, overwritten by state epilogue)
    mg_inject<<<1024, 256, 0, stream>>>(xp, iw, ibias, c2g, out_h);

    mg_cell_kernel<<<8192, 1024, 0, stream>>>(
        hp, msgp, Wp, decayp, bglp, nidp,
        sb1, sgs1, sgb1, sb2, sgs2, sgb2,
        mb1, mgs1, mgb1, mb2, mgs2, mgb2,
        c2g, wb, out_read, out_h, out_msg, wsf);

    mg_mod_kernel<<<1024, 256, 0, stream>>>(
        wsf, modw1, modb1, modw2, modb2, ctxp, bglp, out_ctx, out_bg);
}

// Round 14
// 465.535 us; speedup vs baseline: 1.4875x; 1.4875x over previous
//
#include <hip/hip_runtime.h>

#define NCC 1024
#define MODIN 198
#define MODOUT 68
#define HMODL 128

typedef __attribute__((ext_vector_type(8))) short s8v;   // 8 bf16 = 4 VGPR
typedef __attribute__((ext_vector_type(4))) float f4v;   // MFMA acc
typedef unsigned short ushort_t;
typedef unsigned int uint_t;

// ws layout (ushort elems): sw1 @0 (32768), sw2 @32768 (16384), mw1 @49152 (16384), mw2 @65536 (16384)
#define OFF_SW1 0
#define OFF_SW2 32768
#define OFF_MW1 49152
#define OFF_MW2 65536
#define FEATS_BYTE_OFF 262144   // feats: 8192 cells x 132 f32

__device__ __forceinline__ float fast_tanh(float x) {
    const float e = __builtin_amdgcn_exp2f(x * 2.885390081777927f);   // e^{2x}
    const float r = __builtin_amdgcn_rcpf(e + 1.f);
    return fmaf(-2.f, r, 1.f);
}
__device__ __forceinline__ float fast_sigmoid(float x) {
    const float e = __builtin_amdgcn_exp2f(x * -1.4426950408889634f);
    return __builtin_amdgcn_rcpf(e + 1.f);
}
__device__ __forceinline__ ushort_t f2bf(float x) {   // RNE f32->bf16
    uint_t u = __builtin_bit_cast(uint_t, x);
    u += 0x7FFFu + ((u >> 16) & 1u);
    return (ushort_t)(u >> 16);
}
__device__ __forceinline__ uint_t pk2(float a, float b) {
    return (uint_t)f2bf(a) | ((uint_t)f2bf(b) << 16);
}
// XOR swizzle on LDS byte offsets (16B granule)
#define SWZ(byteoff, row) ((byteoff) ^ (((row) & 7) << 4))

// ---------------------------------------------------------------------------
// Kernel 0: convert the 4 shared MLP weight matrices to bf16 once per launch
// ---------------------------------------------------------------------------
__global__ __launch_bounds__(256)
void mg_cvtw(const float* __restrict__ sw1, const float* __restrict__ sw2,
             const float* __restrict__ mw1, const float* __restrict__ mw2,
             ushort_t* __restrict__ o) {
    const int i = blockIdx.x * 256 + threadIdx.x;   // grid 320 -> 81920 exact
    float v;
    if (i < 32768)      v = sw1[i];
    else if (i < 49152) v = sw2[i - 32768];
    else if (i < 65536) v = mw1[i - 49152];
    else                v = mw2[i - 65536];
    o[i] = f2bf(v);
}

// ---------------------------------------------------------------------------
// Kernel 0b: inject[b,c,o] = x[b,c,:] . iw[g(c)][o,:] + ib[g(c)][o]
// Output -> first 1KB of each out_h tile (P1 reads it, state epilogue overwrites).
// ---------------------------------------------------------------------------
__global__ __launch_bounds__(256, 4)
void mg_inject(const float* __restrict__ xp, const float* __restrict__ iw,
               const float* __restrict__ ibias, const int* __restrict__ c2g,
               float* __restrict__ injb) {
    const int c = blockIdx.x, t = threadIdx.x;
    const int g = c2g[c];
    __shared__ float s_x[8][64];
    for (int idx = t; idx < 512; idx += 256)
        s_x[idx >> 6][idx & 63] = xp[(size_t)(idx >> 6) * (NCC * 64) + c * 64 + (idx & 63)];
    __syncthreads();
    const float* wrow = iw + (size_t)g * 16384 + t * 64;
    float a0 = 0.f, a1 = 0.f, a2 = 0.f, a3 = 0.f, a4 = 0.f, a5 = 0.f, a6 = 0.f, a7 = 0.f;
    #pragma unroll
    for (int i = 0; i < 64; i += 4) {
        const float4 w4 = *(const float4*)(wrow + i);
        const float4 x0 = *(const float4*)&s_x[0][i];
        const float4 x1 = *(const float4*)&s_x[1][i];
        const float4 x2 = *(const float4*)&s_x[2][i];
        const float4 x3 = *(const float4*)&s_x[3][i];
        const float4 x4 = *(const float4*)&s_x[4][i];
        const float4 x5 = *(const float4*)&s_x[5][i];
        const float4 x6 = *(const float4*)&s_x[6][i];
        const float4 x7 = *(const float4*)&s_x[7][i];
        a0 = fmaf(w4.x, x0.x, a0); a0 = fmaf(w4.y, x0.y, a0); a0 = fmaf(w4.z, x0.z, a0); a0 = fmaf(w4.w, x0.w, a0);
        a1 = fmaf(w4.x, x1.x, a1); a1 = fmaf(w4.y, x1.y, a1); a1 = fmaf(w4.z, x1.z, a1); a1 = fmaf(w4.w, x1.w, a1);
        a2 = fmaf(w4.x, x2.x, a2); a2 = fmaf(w4.y, x2.y, a2); a2 = fmaf(w4.z, x2.z, a2); a2 = fmaf(w4.w, x2.w, a2);
        a3 = fmaf(w4.x, x3.x, a3); a3 = fmaf(w4.y, x3.y, a3); a3 = fmaf(w4.z, x3.z, a3); a3 = fmaf(w4.w, x3.w, a3);
        a4 = fmaf(w4.x, x4.x, a4); a4 = fmaf(w4.y, x4.y, a4); a4 = fmaf(w4.z, x4.z, a4); a4 = fmaf(w4.w, x4.w, a4);
        a5 = fmaf(w4.x, x5.x, a5); a5 = fmaf(w4.y, x5.y, a5); a5 = fmaf(w4.z, x5.z, a5); a5 = fmaf(w4.w, x5.w, a5);
        a6 = fmaf(w4.x, x6.x, a6); a6 = fmaf(w4.y, x6.y, a6); a6 = fmaf(w4.z, x6.z, a6); a6 = fmaf(w4.w, x6.w, a6);
        a7 = fmaf(w4.x, x7.x, a7); a7 = fmaf(w4.y, x7.y, a7); a7 = fmaf(w4.z, x7.z, a7); a7 = fmaf(w4.w, x7.w, a7);
    }
    const float bv = ibias[g * 256 + t];
    const float acc[8] = {a0, a1, a2, a3, a4, a5, a6, a7};
    #pragma unroll
    for (int b = 0; b < 8; b++)
        injb[((size_t)b * NCC + c) * 4096 + t] = acc[b] + bv;
}

// ---------------------------------------------------------------------------
// Kernel 1: per (b, cell) block; 512 threads = 8 waves; two-K-half MLPs so
// sHid is [64][128] bf16 -> total LDS ~34KB -> HW can fit 4 blocks/CU
// (32 waves/CU = 8 waves/SIMD) when VGPR<=64. launch_bounds(512,4) keeps the
// VGPR cap at 128 so the allocator is NOT starved (it chose 64 in round 12
// with larger per-wave state); occupancy comes from LDS+VGPR naturally.
// Work split across 8 waves:
//   L1 (P3/P5): wave w owns 16 cols [16w,16w+16) of the current 128-col half
//   P1/L2/epilogues: d-group = w&3 (16 cols), row-half rh = w>>2
// mfma_f32_16x16x32_bf16: A row=lane&15, k=(lane>>4)*8+j; B col=lane&15,
// k contiguous from [N][K]; D col=lane&15, row=(lane>>4)*4+reg.
// ---------------------------------------------------------------------------
__global__ __launch_bounds__(512, 4)
void mg_cell_kernel(
    const float* __restrict__ hp,   const float* __restrict__ msgp,
    const float* __restrict__ Wp,   const float* __restrict__ decayp,
    const float* __restrict__ bglp, const float* __restrict__ nidp,
    const float* __restrict__ sb1,  const float* __restrict__ sgs1,
    const float* __restrict__ sgb1, const float* __restrict__ sb2,
    const float* __restrict__ sgs2, const float* __restrict__ sgb2,
    const float* __restrict__ mb1,  const float* __restrict__ mgs1,
    const float* __restrict__ mgb1, const float* __restrict__ mb2,
    const float* __restrict__ mgs2, const float* __restrict__ mgb2,
    const int*   __restrict__ c2g,  const ushort_t* __restrict__ wb,
    float* __restrict__ out_read, float* __restrict__ out_h,
    float* __restrict__ out_msg,  float* __restrict__ wsf)
{
    const int t  = threadIdx.x;
    const int bc = blockIdx.x;
    const int b  = bc >> 10, c = bc & 1023;
    const int gh = c >> 5, gwc = c & 31;
    const int lane = t & 63, w = t >> 6;
    const int cl = lane & 15, q = lane >> 4;
    const int g  = c2g[c];
    const size_t tile = (size_t)bc * 4096;

    __shared__ ushort_t sHid[8192];    // [64][128] bf16 16KB; overlays sW|sMsgT
    __shared__ ushort_t sIn[8192];     // [64][128] bf16: [received/h_new | h]
    __shared__ float s_scr[256];       // border; later h-part[2][64] @0, m-part[2][64] @128
    __shared__ float s_dec[64];
    __shared__ float s_wsum[8];
    __shared__ float s_dsum;

    ushort_t* sW    = sHid;            // [64][64], row stride 128B
    ushort_t* sMsgT = sHid + 4096;     // [64 d][64 m]

    // ================= P0: staging + border + decay =================
    {   // W -> sW bf16 (+ sum|W|): n = t>>3, 8 cols each (512 thr x 8 = 4096)
        const int n = t >> 3, m0 = (t & 7) * 8;
        const float* src = Wp + tile + n * 64 + m0;
        const float4 v0 = *(const float4*)(src);
        const float4 v1 = *(const float4*)(src + 4);
        float wsum = fabsf(v0.x) + fabsf(v0.y) + fabsf(v0.z) + fabsf(v0.w)
                   + fabsf(v1.x) + fabsf(v1.y) + fabsf(v1.z) + fabsf(v1.w);
        *(uint_t*)((char*)sW + SWZ(n * 128 + (m0 + 0) * 2, n)) = pk2(v0.x, v0.y);
        *(uint_t*)((char*)sW + SWZ(n * 128 + (m0 + 2) * 2, n)) = pk2(v0.z, v0.w);
        *(uint_t*)((char*)sW + SWZ(n * 128 + (m0 + 4) * 2, n)) = pk2(v1.x, v1.y);
        *(uint_t*)((char*)sW + SWZ(n * 128 + (m0 + 6) * 2, n)) = pk2(v1.z, v1.w);
        #pragma unroll
        for (int off = 32; off > 0; off >>= 1) wsum += __shfl_down(wsum, off);
        if (lane == 0) s_wsum[w] = wsum;
    }
    #pragma unroll
    for (int i = 0; i < 2; i++) {   // msg^T -> sMsgT bf16
        const int m = (t >> 4) + i * 32, d0 = (t & 15) * 4;
        const float4 v = *(const float4*)(msgp + tile + (size_t)m * 64 + d0);
        *(ushort_t*)((char*)sMsgT + SWZ((d0 + 0) * 128 + m * 2, d0 + 0)) = f2bf(v.x);
        *(ushort_t*)((char*)sMsgT + SWZ((d0 + 1) * 128 + m * 2, d0 + 1)) = f2bf(v.y);
        *(ushort_t*)((char*)sMsgT + SWZ((d0 + 2) * 128 + m * 2, d0 + 2)) = f2bf(v.z);
        *(ushort_t*)((char*)sMsgT + SWZ((d0 + 3) * 128 + m * 2, d0 + 3)) = f2bf(v.w);
    }
    #pragma unroll
    for (int i = 0; i < 2; i++) {   // h -> sIn[:,64:128] bf16
        const int n = (t >> 4) + i * 32, d0 = (t & 15) * 4;
        const float4 v = *(const float4*)(hp + tile + (size_t)n * 64 + d0);
        *(uint_t*)((char*)sIn + SWZ(n * 256 + (64 + d0) * 2, n))     = pk2(v.x, v.y);
        *(uint_t*)((char*)sIn + SWZ(n * 256 + (64 + d0 + 2) * 2, n)) = pk2(v.z, v.w);
    }
    if (t < 256) {   // gated border incoming: wave p = w (0..3)
        const int p = w, dd = lane;
        int ok, nc2, qq;
        if      (p == 0) { ok = (gh > 0);   nc2 = c - 32; qq = 1; }
        else if (p == 1) { ok = (gh < 31);  nc2 = c + 32; qq = 0; }
        else if (p == 2) { ok = (gwc > 0);  nc2 = c - 1;  qq = 3; }
        else             { ok = (gwc < 31); nc2 = c + 1;  qq = 2; }
        float v = 0.f;
        if (ok) v = msgp[((size_t)b * NCC + nc2) * 4096 + (8 + qq) * 64 + dd];
        s_scr[p * 64 + dd] = fast_sigmoid(bglp[(size_t)bc * 4 + p]) * v;
    }
    if (w == 4) {   // decay sigmoid table + logit sum (wave not used by border)
        const float dl = decayp[(size_t)bc * 64 + lane];
        s_dec[lane] = fast_sigmoid(dl);
        float v = dl;
        #pragma unroll
        for (int off = 32; off > 0; off >>= 1) v += __shfl_down(v, off);
        if (lane == 0) s_dsum = v;
    }
    __syncthreads();   // B1

    const f4v fzero = {0.f, 0.f, 0.f, 0.f};
    const int d  = 16 * (w & 3) + cl;   // d-column for P1/L2/epilogues
    const int rh = w >> 2;              // row-half for P1/L2/epilogues

    // ========== P1: W@msg (MFMA) + inject(precomputed) + border -> sIn[:,0:64] ==========
    {
        f4v wm[2] = {fzero, fzero};
        float injv[4] = {0.f, 0.f, 0.f, 0.f};
        if (rh == 0 && q == 0) {
            #pragma unroll
            for (int r = 0; r < 4; r++) injv[r] = out_h[tile + r * 64 + d];
        }
        __builtin_amdgcn_s_setprio(1);
        #pragma unroll
        for (int ks = 0; ks < 2; ks++) {
            const int k0 = ks * 32 + q * 8;
            const s8v bf = *(const s8v*)((const char*)sMsgT + SWZ(d * 128 + k0 * 2, d));
            #pragma unroll
            for (int rt2 = 0; rt2 < 2; rt2++) {
                const int ar = (rh * 2 + rt2) * 16 + cl;
                const s8v af = *(const s8v*)((const char*)sW + SWZ(ar * 128 + k0 * 2, ar));
                wm[rt2] = __builtin_amdgcn_mfma_f32_16x16x32_bf16(af, bf, wm[rt2], 0, 0, 0);
            }
        }
        __builtin_amdgcn_s_setprio(0);
        #pragma unroll
        for (int rt2 = 0; rt2 < 2; rt2++)
            #pragma unroll
            for (int r = 0; r < 4; r++) {
                const int n = (rh * 2 + rt2) * 16 + q * 4 + r;
                float v = wm[rt2][r];
                if (n < 4)                 v += injv[r];
                else if (n >= 8 && n < 12) v += s_scr[(n - 8) * 64 + d];
                *(ushort_t*)((char*)sIn + SWZ(n * 256 + d * 2, n)) = f2bf(v);
            }
    }
    __syncthreads();   // B2 (P1's sW/sMsgT reads done -> sHid overlay safe)

    // ===== STATE MLP: two K-half passes (hid cols p*128..p*128+128) =====
    {
        f4v a2[2][2];
        a2[0][0] = fzero; a2[0][1] = fzero; a2[1][0] = fzero; a2[1][1] = fzero;
        const ushort_t* wb1 = wb + OFF_SW1;
        const ushort_t* wb2 = wb + OFF_SW2;
        #pragma unroll
        for (int p = 0; p < 2; p++) {
            {   // L1 half: wave w owns LDS cols [16w, 16w+16)
                f4v acc[4] = {fzero, fzero, fzero, fzero};
                const int lc = 16 * w + cl;          // LDS col (0..127)
                const int hcol = p * 128 + lc;       // global hid col
                __builtin_amdgcn_s_setprio(1);
                #pragma unroll
                for (int ks = 0; ks < 4; ks++) {
                    const int k0 = ks * 32 + q * 8;
                    const s8v bf = *(const s8v*)(wb1 + (size_t)hcol * 128 + k0);
                    #pragma unroll
                    for (int rt = 0; rt < 4; rt++) {
                        const int ar = rt * 16 + cl;
                        const s8v af = *(const s8v*)((const char*)sIn + SWZ(ar * 256 + k0 * 2, ar));
                        acc[rt] = __builtin_amdgcn_mfma_f32_16x16x32_bf16(af, bf, acc[rt], 0, 0, 0);
                    }
                }
                __builtin_amdgcn_s_setprio(0);
                const float b1 = sb1[hcol], g1 = sgs1[g * 256 + hcol], o1 = sgb1[g * 256 + hcol];
                #pragma unroll
                for (int rt = 0; rt < 4; rt++)
                    #pragma unroll
                    for (int r = 0; r < 4; r++) {
                        const int n = rt * 16 + q * 4 + r;
                        const float vv = fast_tanh(fmaf(acc[rt][r] + b1, g1, o1));
                        *(ushort_t*)((char*)sHid + SWZ(n * 256 + lc * 2, n)) = f2bf(vv);
                    }
            }
            __syncthreads();   // hid half visible
            {   // L2 partial over this half's 128 k
                __builtin_amdgcn_s_setprio(1);
                #pragma unroll
                for (int ks = 0; ks < 4; ks++) {
                    const int k0 = ks * 32 + q * 8;
                    const s8v bf = *(const s8v*)(wb2 + (size_t)d * 256 + p * 128 + k0);
                    #pragma unroll
                    for (int rt2 = 0; rt2 < 2; rt2++) {
                        const int ar = (rh * 2 + rt2) * 16 + cl;
                        const s8v af = *(const s8v*)((const char*)sHid + SWZ(ar * 256 + k0 * 2, ar));
                        a2[rt2][ks & 1] = __builtin_amdgcn_mfma_f32_16x16x32_bf16(af, bf, a2[rt2][ks & 1], 0, 0, 0);
                    }
                }
                __builtin_amdgcn_s_setprio(0);
            }
            if (p == 0) __syncthreads();   // hid reads done before overwrite
        }
        // epilogue: cand -> h_new (global store + sIn bf16) + h_mean partials
        const float b2 = sb2[d], g2 = sgs2[g * 64 + d], o2 = sgb2[g * 64 + d];
        float hsum = 0.f;
        #pragma unroll
        for (int rt2 = 0; rt2 < 2; rt2++)
            #pragma unroll
            for (int r = 0; r < 4; r++) {
                const int n = (rh * 2 + rt2) * 16 + q * 4 + r;
                const float cand = fast_tanh(fmaf(a2[rt2][0][r] + a2[rt2][1][r] + b2, g2, o2));
                const ushort_t hu = *(const ushort_t*)((const char*)sIn + SWZ(n * 256 + (64 + d) * 2, n));
                const float hv = __builtin_bit_cast(float, (uint_t)hu << 16);
                const float hn = fmaf(s_dec[n], hv - cand, cand);   // dec*h + (1-dec)*cand
                out_h[tile + (size_t)n * 64 + d] = hn;
                *(ushort_t*)((char*)sIn + SWZ(n * 256 + d * 2, n)) = f2bf(hn);
                hsum += hn;
            }
        hsum += __shfl_xor(hsum, 16);
        hsum += __shfl_xor(hsum, 32);
        if (q == 0) s_scr[rh * 64 + d] = hsum;   // h-part bands [0:128)
    }
    __syncthreads();   // B4: h_new in sIn visible

    // ===== MSG MLP: two K-half passes =====
    {
        float nv[8];
        #pragma unroll
        for (int rt2 = 0; rt2 < 2; rt2++)
            #pragma unroll
            for (int r = 0; r < 4; r++) {
                const int n = (rh * 2 + rt2) * 16 + q * 4 + r;
                nv[rt2 * 4 + r] = nidp[(size_t)c * 4096 + (size_t)n * 64 + d];
            }
        f4v a6[2][2];
        a6[0][0] = fzero; a6[0][1] = fzero; a6[1][0] = fzero; a6[1][1] = fzero;
        const ushort_t* wm1 = wb + OFF_MW1;
        const ushort_t* wm2 = wb + OFF_MW2;
        #pragma unroll
        for (int p = 0; p < 2; p++) {
            {   // msg L1 half (K=64 input): wave w owns LDS cols [16w, 16w+16)
                f4v acc[4] = {fzero, fzero, fzero, fzero};
                const int lc = 16 * w + cl;
                const int hcol = p * 128 + lc;
                __builtin_amdgcn_s_setprio(1);
                #pragma unroll
                for (int ks = 0; ks < 2; ks++) {
                    const int k0 = ks * 32 + q * 8;
                    const s8v bf = *(const s8v*)(wm1 + (size_t)hcol * 64 + k0);
                    #pragma unroll
                    for (int rt = 0; rt < 4; rt++) {
                        const int ar = rt * 16 + cl;
                        const s8v af = *(const s8v*)((const char*)sIn + SWZ(ar * 256 + k0 * 2, ar));
                        acc[rt] = __builtin_amdgcn_mfma_f32_16x16x32_bf16(af, bf, acc[rt], 0, 0, 0);
                    }
                }
                __builtin_amdgcn_s_setprio(0);
                const float b1 = mb1[hcol], g1 = mgs1[g * 256 + hcol], o1 = mgb1[g * 256 + hcol];
                #pragma unroll
                for (int rt = 0; rt < 4; rt++)
                    #pragma unroll
                    for (int r = 0; r < 4; r++) {
                        const int n = rt * 16 + q * 4 + r;
                        const float vv = fast_tanh(fmaf(acc[rt][r] + b1, g1, o1));
                        *(ushort_t*)((char*)sHid + SWZ(n * 256 + lc * 2, n)) = f2bf(vv);
                    }
            }
            __syncthreads();   // mhid half visible
            {   // msg L2 partial
                __builtin_amdgcn_s_setprio(1);
                #pragma unroll
                for (int ks = 0; ks < 4; ks++) {
                    const int k0 = ks * 32 + q * 8;
                    const s8v bf = *(const s8v*)(wm2 + (size_t)d * 256 + p * 128 + k0);
                    #pragma unroll
                    for (int rt2 = 0; rt2 < 2; rt2++) {
                        const int ar = (rh * 2 + rt2) * 16 + cl;
                        const s8v af = *(const s8v*)((const char*)sHid + SWZ(ar * 256 + k0 * 2, ar));
                        a6[rt2][ks & 1] = __builtin_amdgcn_mfma_f32_16x16x32_bf16(af, bf, a6[rt2][ks & 1], 0, 0, 0);
                    }
                }
                __builtin_amdgcn_s_setprio(0);
            }
            if (p == 0) __syncthreads();
        }
        // epilogue: msg_new (+nid), mmean partials, readout
        const float b2 = mb2[d], g2 = mgs2[g * 64 + d], o2 = mgb2[g * 64 + d];
        float msum = 0.f, ro = 0.f;
        #pragma unroll
        for (int rt2 = 0; rt2 < 2; rt2++)
            #pragma unroll
            for (int r = 0; r < 4; r++) {
                const int n = (rh * 2 + rt2) * 16 + q * 4 + r;
                const float mv = fast_tanh(fmaf(a6[rt2][0][r] + a6[rt2][1][r] + b2, g2, o2))
                                 + nv[rt2 * 4 + r];
                out_msg[tile + (size_t)n * 64 + d] = mv;
                msum += mv;
                if (rt2 == 0 && q == 1 && rh == 0) ro += mv;   // output ports n = 4..7
            }
        msum += __shfl_xor(msum, 16);
        msum += __shfl_xor(msum, 32);
        if (q == 0) s_scr[128 + rh * 64 + d] = msum;   // m-part bands [128:256)
        if (rh == 0 && q == 1) out_read[((size_t)b * NCC + c) * 64 + d] = ro * 0.5f;
    }
    __syncthreads();   // B6

    // ================= P7: feats record (130 values) =================
    if (t < 132) {
        float v = 0.f;
        if (t < 64)        v = (s_scr[t] + s_scr[64 + t]) * (1.f / 64.f);
        else if (t < 128)  v = (s_scr[64 + t] + s_scr[128 + t]) * (1.f / 64.f);  // 128+(t-64), 192+(t-64)
        else if (t == 128) v = (s_wsum[0] + s_wsum[1] + s_wsum[2] + s_wsum[3]
                              + s_wsum[4] + s_wsum[5] + s_wsum[6] + s_wsum[7]) * (1.f / 4096.f);
        else if (t == 129) v = s_dsum * (1.f / 64.f);
        wsf[(size_t)bc * 132 + t] = v;
    }
}

// ---------------------------------------------------------------------------
// Kernel 2: per-cell modulation MLP (distinct weights per cell)
// ---------------------------------------------------------------------------
__global__ __launch_bounds__(256, 2)
void mg_mod_kernel(
    const float* __restrict__ wsf,   const float* __restrict__ modw1,
    const float* __restrict__ modb1, const float* __restrict__ modw2,
    const float* __restrict__ modb2, const float* __restrict__ ctxp,
    const float* __restrict__ bglp,  float* __restrict__ out_ctx,
    float* __restrict__ out_bg)
{
    const int c = blockIdx.x;
    const int t = threadIdx.x;
    __shared__ float s_f[8][MODIN];
    __shared__ float s_h2[8][HMODL];

    for (int k = t; k < 8 * MODIN; k += 256) {
        const int b = k / MODIN, f = k - b * MODIN;
        float v;
        if (f < 130)      v = wsf[((size_t)b * NCC + c) * 132 + f];
        else if (f < 194) v = ctxp[((size_t)b * NCC + c) * 64 + (f - 130)];
        else              v = bglp[((size_t)b * NCC + c) * 4 + (f - 194)];
        s_f[b][f] = v;
    }
    __syncthreads();

    {
        const int hh = t & 127, bh = (t >> 7) * 4;
        float a0 = 0.f, a1 = 0.f, a2 = 0.f, a3 = 0.f;
        const float* wp = modw1 + (size_t)c * MODIN * HMODL + hh;
        for (int f = 0; f < MODIN; f++) {
            const float wv = wp[(size_t)f * HMODL];
            a0 = fmaf(s_f[bh + 0][f], wv, a0);
            a1 = fmaf(s_f[bh + 1][f], wv, a1);
            a2 = fmaf(s_f[bh + 2][f], wv, a2);
            a3 = fmaf(s_f[bh + 3][f], wv, a3);
        }
        const float bv = modb1[(size_t)c * HMODL + hh];
        s_h2[bh + 0][hh] = fast_tanh(a0 + bv);
        s_h2[bh + 1][hh] = fast_tanh(a1 + bv);
        s_h2[bh + 2][hh] = fast_tanh(a2 + bv);
        s_h2[bh + 3][hh] = fast_tanh(a3 + bv);
    }
    __syncthreads();

    for (int idx = t; idx < 8 * MODOUT; idx += 256) {
        const int b = idx / MODOUT, o = idx - b * MODOUT;
        float acc = modb2[(size_t)c * MODOUT + o];
        const float* wp = modw2 + (size_t)c * HMODL * MODOUT + o;
        const float* hrow = s_h2[b];
        for (int hh = 0; hh < HMODL; hh++)
            acc = fmaf(hrow[hh], wp[(size_t)hh * MODOUT], acc);
        if (o < 64)
            out_ctx[((size_t)b * NCC + c) * 64 + o] =
                ctxp[((size_t)b * NCC + c) * 64 + o] + acc;
        else
            out_bg[((size_t)b * NCC + c) * 4 + (o - 64)] =
                bglp[((size_t)b * NCC + c) * 4 + (o - 64)] + acc;
    }
}

extern "C" void kernel_launch(void* const* d_in, const int* in_sizes, int n_in,
                              void* d_out, int out_size, void* d_ws, size_t ws_size,
                              hipStream_t stream) {
    const float* xp     = (const float*)d_in[0];
    const float* hp     = (const float*)d_in[1];
    const float* msgp   = (const float*)d_in[2];
    const float* Wp     = (const float*)d_in[3];
    const float* decayp = (const float*)d_in[4];
    const float* ctxp   = (const float*)d_in[5];
    const float* bglp   = (const float*)d_in[6];
    const float* nidp   = (const float*)d_in[7];
    const float* sw1    = (const float*)d_in[8];
    const float* sb1    = (const float*)d_in[9];
    const float* sgs1   = (const float*)d_in[10];
    const float* sgb1   = (const float*)d_in[11];
    const float* sw2    = (const float*)d_in[12];
    const float* sb2    = (const float*)d_in[13];
    const float* sgs2   = (const float*)d_in[14];
    const float* sgb2   = (const float*)d_in[15];
    const float* mw1    = (const float*)d_in[16];
    const float* mb1    = (const float*)d_in[17];
    const float* mgs1   = (const float*)d_in[18];
    const float* mgb1   = (const float*)d_in[19];
    const float* mw2    = (const float*)d_in[20];
    const float* mb2    = (const float*)d_in[21];
    const float* mgs2   = (const float*)d_in[22];
    const float* mgb2   = (const float*)d_in[23];
    const float* iw     = (const float*)d_in[24];
    const float* ibias  = (const float*)d_in[25];
    const float* modw1  = (const float*)d_in[26];
    const float* modb1  = (const float*)d_in[27];
    const float* modw2  = (const float*)d_in[28];
    const float* modb2  = (const float*)d_in[29];
    const int*   c2g    = (const int*)d_in[30];

    float* out      = (float*)d_out;
    float* out_read = out;                 // 524288
    float* out_h    = out_read + 524288;   // 33554432
    float* out_msg  = out_h + 33554432;    // 33554432
    float* out_ctx  = out_msg + 33554432;  // 524288
    float* out_bg   = out_ctx + 524288;    // 32768

    ushort_t* wb  = (ushort_t*)d_ws;                          // 160KB bf16 weights
    float*    wsf = (float*)((char*)d_ws + FEATS_BYTE_OFF);   // 8192 x 132 f32

    mg_cvtw<<<320, 256, 0, stream>>>(sw1, sw2, mw1, mw2, wb);

    // inject -> head of each out_h tile (read by P1, overwritten by state epilogue)
    mg_inject<<<1024, 256, 0, stream>>>(xp, iw, ibias, c2g, out_h);

    mg_cell_kernel<<<8192, 512, 0, stream>>>(
        hp, msgp, Wp, decayp, bglp, nidp,
        sb1, sgs1, sgb1, sb2, sgs2, sgb2,
        mb1, mgs1, mgb1, mb2, mgs2, mgb2,
        c2g, wb, out_read, out_h, out_msg, wsf);

    mg_mod_kernel<<<1024, 256, 0, stream>>>(
        wsf, modw1, modb1, modw2, modb2, ctxp, bglp, out_ctx, out_bg);
}

// Round 15
// 446.026 us; speedup vs baseline: 1.5525x; 1.0437x over previous
//
#include <hip/hip_runtime.h>

#define NCC 1024
#define MODIN 198
#define MODOUT 68
#define HMODL 128

typedef __attribute__((ext_vector_type(8))) short s8v;   // 8 bf16 = 4 VGPR
typedef __attribute__((ext_vector_type(4))) float f4v;   // MFMA acc
typedef unsigned short ushort_t;
typedef unsigned int uint_t;

// ws layout (ushort elems): sw1 @0 (32768), sw2 @32768 (16384), mw1 @49152 (16384), mw2 @65536 (16384)
#define OFF_SW1 0
#define OFF_SW2 32768
#define OFF_MW1 49152
#define OFF_MW2 65536
#define FEATS_BYTE_OFF 262144   // feats: 8192 cells x 132 f32

__device__ __forceinline__ float fast_tanh(float x) {
    const float e = __builtin_amdgcn_exp2f(x * 2.885390081777927f);   // e^{2x}
    const float r = __builtin_amdgcn_rcpf(e + 1.f);
    return fmaf(-2.f, r, 1.f);
}
__device__ __forceinline__ float fast_sigmoid(float x) {
    const float e = __builtin_amdgcn_exp2f(x * -1.4426950408889634f);
    return __builtin_amdgcn_rcpf(e + 1.f);
}
__device__ __forceinline__ ushort_t f2bf(float x) {   // RNE f32->bf16
    uint_t u = __builtin_bit_cast(uint_t, x);
    u += 0x7FFFu + ((u >> 16) & 1u);
    return (ushort_t)(u >> 16);
}
__device__ __forceinline__ uint_t pk2(float a, float b) {
    return (uint_t)f2bf(a) | ((uint_t)f2bf(b) << 16);
}
// XOR swizzle on LDS byte offsets (16B granule)
#define SWZ(byteoff, row) ((byteoff) ^ (((row) & 7) << 4))

// ---------------------------------------------------------------------------
// Kernel 0: convert the 4 shared MLP weight matrices to bf16 once per launch
// ---------------------------------------------------------------------------
__global__ __launch_bounds__(256)
void mg_cvtw(const float* __restrict__ sw1, const float* __restrict__ sw2,
             const float* __restrict__ mw1, const float* __restrict__ mw2,
             ushort_t* __restrict__ o) {
    const int i = blockIdx.x * 256 + threadIdx.x;   // grid 320 -> 81920 exact
    float v;
    if (i < 32768)      v = sw1[i];
    else if (i < 49152) v = sw2[i - 32768];
    else if (i < 65536) v = mw1[i - 49152];
    else                v = mw2[i - 65536];
    o[i] = f2bf(v);
}

// ---------------------------------------------------------------------------
// Kernel 0b: inject[b,c,o] -> head of each out_h tile (read by P1)
// ---------------------------------------------------------------------------
__global__ __launch_bounds__(256, 4)
void mg_inject(const float* __restrict__ xp, const float* __restrict__ iw,
               const float* __restrict__ ibias, const int* __restrict__ c2g,
               float* __restrict__ injb) {
    const int c = blockIdx.x, t = threadIdx.x;
    const int g = c2g[c];
    __shared__ float s_x[8][64];
    for (int idx = t; idx < 512; idx += 256)
        s_x[idx >> 6][idx & 63] = xp[(size_t)(idx >> 6) * (NCC * 64) + c * 64 + (idx & 63)];
    __syncthreads();
    const float* wrow = iw + (size_t)g * 16384 + t * 64;
    float a0 = 0.f, a1 = 0.f, a2 = 0.f, a3 = 0.f, a4 = 0.f, a5 = 0.f, a6 = 0.f, a7 = 0.f;
    #pragma unroll
    for (int i = 0; i < 64; i += 4) {
        const float4 w4 = *(const float4*)(wrow + i);
        const float4 x0 = *(const float4*)&s_x[0][i];
        const float4 x1 = *(const float4*)&s_x[1][i];
        const float4 x2 = *(const float4*)&s_x[2][i];
        const float4 x3 = *(const float4*)&s_x[3][i];
        const float4 x4 = *(const float4*)&s_x[4][i];
        const float4 x5 = *(const float4*)&s_x[5][i];
        const float4 x6 = *(const float4*)&s_x[6][i];
        const float4 x7 = *(const float4*)&s_x[7][i];
        a0 = fmaf(w4.x, x0.x, a0); a0 = fmaf(w4.y, x0.y, a0); a0 = fmaf(w4.z, x0.z, a0); a0 = fmaf(w4.w, x0.w, a0);
        a1 = fmaf(w4.x, x1.x, a1); a1 = fmaf(w4.y, x1.y, a1); a1 = fmaf(w4.z, x1.z, a1); a1 = fmaf(w4.w, x1.w, a1);
        a2 = fmaf(w4.x, x2.x, a2); a2 = fmaf(w4.y, x2.y, a2); a2 = fmaf(w4.z, x2.z, a2); a2 = fmaf(w4.w, x2.w, a2);
        a3 = fmaf(w4.x, x3.x, a3); a3 = fmaf(w4.y, x3.y, a3); a3 = fmaf(w4.z, x3.z, a3); a3 = fmaf(w4.w, x3.w, a3);
        a4 = fmaf(w4.x, x4.x, a4); a4 = fmaf(w4.y, x4.y, a4); a4 = fmaf(w4.z, x4.z, a4); a4 = fmaf(w4.w, x4.w, a4);
        a5 = fmaf(w4.x, x5.x, a5); a5 = fmaf(w4.y, x5.y, a5); a5 = fmaf(w4.z, x5.z, a5); a5 = fmaf(w4.w, x5.w, a5);
        a6 = fmaf(w4.x, x6.x, a6); a6 = fmaf(w4.y, x6.y, a6); a6 = fmaf(w4.z, x6.z, a6); a6 = fmaf(w4.w, x6.w, a6);
        a7 = fmaf(w4.x, x7.x, a7); a7 = fmaf(w4.y, x7.y, a7); a7 = fmaf(w4.z, x7.z, a7); a7 = fmaf(w4.w, x7.w, a7);
    }
    const float bv = ibias[g * 256 + t];
    const float acc[8] = {a0, a1, a2, a3, a4, a5, a6, a7};
    #pragma unroll
    for (int b = 0; b < 8; b++)
        injb[((size_t)b * NCC + c) * 4096 + t] = acc[b] + bv;
}

// ---------------------------------------------------------------------------
// Kernel 1: per (b, cell) block; 512 threads = 8 waves; two-K-half MLPs
// (round-14 structure, LDS ~34KB). Round-15: OPERAND-SWAPPED MFMAs —
// D = mfma(A=weight, B=data) so each lane holds 4 CONSECUTIVE output
// columns for ONE row -> packed b64 LDS writes + float4 global stores.
// Input reads are byte-identical to round 14 (A/B frag reads swap roles).
// D: col(lane&15) = data-row n; row(q*4+r) = output column.
// ---------------------------------------------------------------------------
__global__ __launch_bounds__(512, 4)
void mg_cell_kernel(
    const float* __restrict__ hp,   const float* __restrict__ msgp,
    const float* __restrict__ Wp,   const float* __restrict__ decayp,
    const float* __restrict__ bglp, const float* __restrict__ nidp,
    const float* __restrict__ sb1,  const float* __restrict__ sgs1,
    const float* __restrict__ sgb1, const float* __restrict__ sb2,
    const float* __restrict__ sgs2, const float* __restrict__ sgb2,
    const float* __restrict__ mb1,  const float* __restrict__ mgs1,
    const float* __restrict__ mgb1, const float* __restrict__ mb2,
    const float* __restrict__ mgs2, const float* __restrict__ mgb2,
    const int*   __restrict__ c2g,  const ushort_t* __restrict__ wb,
    float* __restrict__ out_read, float* __restrict__ out_h,
    float* __restrict__ out_msg,  float* __restrict__ wsf)
{
    const int t  = threadIdx.x;
    const int bc = blockIdx.x;
    const int b  = bc >> 10, c = bc & 1023;
    const int gh = c >> 5, gwc = c & 31;
    const int lane = t & 63, w = t >> 6;
    const int cl = lane & 15, q = lane >> 4;
    const int g  = c2g[c];
    const size_t tile = (size_t)bc * 4096;

    __shared__ ushort_t sHid[8192];    // [64][128] bf16 16KB; overlays sW|sMsgT
    __shared__ ushort_t sIn[8192];     // [64][128] bf16: [received/h_new | h]
    __shared__ float s_scr[256];       // border; later h-part[2][64] @0, m-part[2][64] @128
    __shared__ float s_dec[64];
    __shared__ float s_wsum[8];
    __shared__ float s_dsum;

    ushort_t* sW    = sHid;            // [64][64], row stride 128B
    ushort_t* sMsgT = sHid + 4096;     // [64 d][64 m]

    // ================= P0: staging + border + decay =================
    {   // W -> sW bf16 (+ sum|W|): n = t>>3, 8 cols each
        const int n = t >> 3, m0 = (t & 7) * 8;
        const float* src = Wp + tile + n * 64 + m0;
        const float4 v0 = *(const float4*)(src);
        const float4 v1 = *(const float4*)(src + 4);
        float wsum = fabsf(v0.x) + fabsf(v0.y) + fabsf(v0.z) + fabsf(v0.w)
                   + fabsf(v1.x) + fabsf(v1.y) + fabsf(v1.z) + fabsf(v1.w);
        *(uint_t*)((char*)sW + SWZ(n * 128 + (m0 + 0) * 2, n)) = pk2(v0.x, v0.y);
        *(uint_t*)((char*)sW + SWZ(n * 128 + (m0 + 2) * 2, n)) = pk2(v0.z, v0.w);
        *(uint_t*)((char*)sW + SWZ(n * 128 + (m0 + 4) * 2, n)) = pk2(v1.x, v1.y);
        *(uint_t*)((char*)sW + SWZ(n * 128 + (m0 + 6) * 2, n)) = pk2(v1.z, v1.w);
        #pragma unroll
        for (int off = 32; off > 0; off >>= 1) wsum += __shfl_down(wsum, off);
        if (lane == 0) s_wsum[w] = wsum;
    }
    #pragma unroll
    for (int i = 0; i < 2; i++) {   // msg^T -> sMsgT bf16
        const int m = (t >> 4) + i * 32, d0 = (t & 15) * 4;
        const float4 v = *(const float4*)(msgp + tile + (size_t)m * 64 + d0);
        *(ushort_t*)((char*)sMsgT + SWZ((d0 + 0) * 128 + m * 2, d0 + 0)) = f2bf(v.x);
        *(ushort_t*)((char*)sMsgT + SWZ((d0 + 1) * 128 + m * 2, d0 + 1)) = f2bf(v.y);
        *(ushort_t*)((char*)sMsgT + SWZ((d0 + 2) * 128 + m * 2, d0 + 2)) = f2bf(v.z);
        *(ushort_t*)((char*)sMsgT + SWZ((d0 + 3) * 128 + m * 2, d0 + 3)) = f2bf(v.w);
    }
    #pragma unroll
    for (int i = 0; i < 2; i++) {   // h -> sIn[:,64:128] bf16
        const int n = (t >> 4) + i * 32, d0 = (t & 15) * 4;
        const float4 v = *(const float4*)(hp + tile + (size_t)n * 64 + d0);
        *(uint_t*)((char*)sIn + SWZ(n * 256 + (64 + d0) * 2, n))     = pk2(v.x, v.y);
        *(uint_t*)((char*)sIn + SWZ(n * 256 + (64 + d0 + 2) * 2, n)) = pk2(v.z, v.w);
    }
    if (t < 256) {   // gated border incoming: wave p = w (0..3)
        const int p = w, dd = lane;
        int ok, nc2, qq;
        if      (p == 0) { ok = (gh > 0);   nc2 = c - 32; qq = 1; }
        else if (p == 1) { ok = (gh < 31);  nc2 = c + 32; qq = 0; }
        else if (p == 2) { ok = (gwc > 0);  nc2 = c - 1;  qq = 3; }
        else             { ok = (gwc < 31); nc2 = c + 1;  qq = 2; }
        float v = 0.f;
        if (ok) v = msgp[((size_t)b * NCC + nc2) * 4096 + (8 + qq) * 64 + dd];
        s_scr[p * 64 + dd] = fast_sigmoid(bglp[(size_t)bc * 4 + p]) * v;
    }
    if (w == 4) {   // decay sigmoid table + logit sum
        const float dl = decayp[(size_t)bc * 64 + lane];
        s_dec[lane] = fast_sigmoid(dl);
        float v = dl;
        #pragma unroll
        for (int off = 32; off > 0; off >>= 1) v += __shfl_down(v, off);
        if (lane == 0) s_dsum = v;
    }
    __syncthreads();   // B1

    const f4v fzero = {0.f, 0.f, 0.f, 0.f};
    const int d0 = 16 * (w & 3) + q * 4;   // this thread's 4 output cols (epilogues)
    const int dA = 16 * (w & 3) + cl;      // A-operand weight-row index (reads)
    const int rh = w >> 2;                 // row-half

    // ========== P1: received^ = mfma(msgT, W) + inject + border -> sIn[:,0:64] ==========
    {
        f4v wm[2] = {fzero, fzero};
        __builtin_amdgcn_s_setprio(1);
        #pragma unroll
        for (int ks = 0; ks < 2; ks++) {
            const int k0 = ks * 32 + q * 8;
            const s8v am = *(const s8v*)((const char*)sMsgT + SWZ(dA * 128 + k0 * 2, dA));
            #pragma unroll
            for (int nt = 0; nt < 2; nt++) {
                const int ar = (rh * 2 + nt) * 16 + cl;
                const s8v bw = *(const s8v*)((const char*)sW + SWZ(ar * 128 + k0 * 2, ar));
                wm[nt] = __builtin_amdgcn_mfma_f32_16x16x32_bf16(am, bw, wm[nt], 0, 0, 0);
            }
        }
        __builtin_amdgcn_s_setprio(0);
        #pragma unroll
        for (int nt = 0; nt < 2; nt++) {
            const int n = (rh * 2 + nt) * 16 + cl;
            float v0 = wm[nt][0], v1 = wm[nt][1], v2 = wm[nt][2], v3 = wm[nt][3];
            if (n < 4) {
                const float4 inj = *(const float4*)(out_h + tile + (size_t)n * 64 + d0);
                v0 += inj.x; v1 += inj.y; v2 += inj.z; v3 += inj.w;
            } else if (n >= 8 && n < 12) {
                const float4 bin = *(const float4*)&s_scr[(n - 8) * 64 + d0];
                v0 += bin.x; v1 += bin.y; v2 += bin.z; v3 += bin.w;
            }
            uint2 pkd; pkd.x = pk2(v0, v1); pkd.y = pk2(v2, v3);
            *(uint2*)((char*)sIn + SWZ(n * 256 + d0 * 2, n)) = pkd;
        }
    }
    __syncthreads();   // B2 (P1's sW/sMsgT reads done -> sHid overlay safe)

    // ===== STATE MLP: two K-half passes (hid cols p*128..p*128+128) =====
    {
        f4v a2[2][2];
        a2[0][0] = fzero; a2[0][1] = fzero; a2[1][0] = fzero; a2[1][1] = fzero;
        const ushort_t* wb1 = wb + OFF_SW1;
        const ushort_t* wb2 = wb + OFF_SW2;
        #pragma unroll
        for (int p = 0; p < 2; p++) {
            {   // L1 half: wave w owns hid cols [p*128+16w, +16); hid^ = mfma(w1, in)
                f4v acc[4] = {fzero, fzero, fzero, fzero};
                const int hrow = p * 128 + 16 * w + cl;      // w1 row (A operand)
                __builtin_amdgcn_s_setprio(1);
                #pragma unroll
                for (int ks = 0; ks < 4; ks++) {
                    const int k0 = ks * 32 + q * 8;
                    const s8v aw = *(const s8v*)(wb1 + (size_t)hrow * 128 + k0);
                    #pragma unroll
                    for (int rt = 0; rt < 4; rt++) {
                        const int ar = rt * 16 + cl;
                        const s8v bi = *(const s8v*)((const char*)sIn + SWZ(ar * 256 + k0 * 2, ar));
                        acc[rt] = __builtin_amdgcn_mfma_f32_16x16x32_bf16(aw, bi, acc[rt], 0, 0, 0);
                    }
                }
                __builtin_amdgcn_s_setprio(0);
                const int hc0 = p * 128 + 16 * w + q * 4;    // 4 consecutive hid cols
                const float4 b1 = *(const float4*)&sb1[hc0];
                const float4 g1 = *(const float4*)&sgs1[g * 256 + hc0];
                const float4 o1 = *(const float4*)&sgb1[g * 256 + hc0];
                const int lc0 = 16 * w + q * 4;              // local col in sHid
                #pragma unroll
                for (int rt = 0; rt < 4; rt++) {
                    const int n = rt * 16 + cl;
                    const float t0 = fast_tanh(fmaf(acc[rt][0] + b1.x, g1.x, o1.x));
                    const float t1 = fast_tanh(fmaf(acc[rt][1] + b1.y, g1.y, o1.y));
                    const float t2 = fast_tanh(fmaf(acc[rt][2] + b1.z, g1.z, o1.z));
                    const float t3 = fast_tanh(fmaf(acc[rt][3] + b1.w, g1.w, o1.w));
                    uint2 pkd; pkd.x = pk2(t0, t1); pkd.y = pk2(t2, t3);
                    *(uint2*)((char*)sHid + SWZ(n * 256 + lc0 * 2, n)) = pkd;
                }
            }
            __syncthreads();   // hid half visible
            {   // L2 partial: cand^ = mfma(w2, hid)
                __builtin_amdgcn_s_setprio(1);
                #pragma unroll
                for (int ks = 0; ks < 4; ks++) {
                    const int k0 = ks * 32 + q * 8;
                    const s8v aw = *(const s8v*)(wb2 + (size_t)dA * 256 + p * 128 + k0);
                    #pragma unroll
                    for (int nt = 0; nt < 2; nt++) {
                        const int ar = (rh * 2 + nt) * 16 + cl;
                        const s8v bh = *(const s8v*)((const char*)sHid + SWZ(ar * 256 + k0 * 2, ar));
                        a2[nt][ks & 1] = __builtin_amdgcn_mfma_f32_16x16x32_bf16(aw, bh, a2[nt][ks & 1], 0, 0, 0);
                    }
                }
                __builtin_amdgcn_s_setprio(0);
            }
            if (p == 0) __syncthreads();   // hid reads done before overwrite
        }
        // epilogue: cand -> h_new (float4 global + packed sIn) + h_mean partials
        const float4 b2 = *(const float4*)&sb2[d0];
        const float4 g2 = *(const float4*)&sgs2[g * 64 + d0];
        const float4 o2 = *(const float4*)&sgb2[g * 64 + d0];
        float hs0 = 0.f, hs1 = 0.f, hs2 = 0.f, hs3 = 0.f;
        #pragma unroll
        for (int nt = 0; nt < 2; nt++) {
            const int n = (rh * 2 + nt) * 16 + cl;
            const float dec = s_dec[n];
            const uint2 hu = *(const uint2*)((const char*)sIn + SWZ(n * 256 + (64 + d0) * 2, n));
            const float hv0 = __builtin_bit_cast(float, (uint_t)(hu.x << 16));
            const float hv1 = __builtin_bit_cast(float, hu.x & 0xFFFF0000u);
            const float hv2 = __builtin_bit_cast(float, (uint_t)(hu.y << 16));
            const float hv3 = __builtin_bit_cast(float, hu.y & 0xFFFF0000u);
            const float c0 = fast_tanh(fmaf(a2[nt][0][0] + a2[nt][1][0] + b2.x, g2.x, o2.x));
            const float c1 = fast_tanh(fmaf(a2[nt][0][1] + a2[nt][1][1] + b2.y, g2.y, o2.y));
            const float c2 = fast_tanh(fmaf(a2[nt][0][2] + a2[nt][1][2] + b2.z, g2.z, o2.z));
            const float c3 = fast_tanh(fmaf(a2[nt][0][3] + a2[nt][1][3] + b2.w, g2.w, o2.w));
            float4 hn;
            hn.x = fmaf(dec, hv0 - c0, c0);
            hn.y = fmaf(dec, hv1 - c1, c1);
            hn.z = fmaf(dec, hv2 - c2, c2);
            hn.w = fmaf(dec, hv3 - c3, c3);
            *(float4*)(out_h + tile + (size_t)n * 64 + d0) = hn;
            uint2 pkd; pkd.x = pk2(hn.x, hn.y); pkd.y = pk2(hn.z, hn.w);
            *(uint2*)((char*)sIn + SWZ(n * 256 + d0 * 2, n)) = pkd;
            hs0 += hn.x; hs1 += hn.y; hs2 += hn.z; hs3 += hn.w;
        }
        #pragma unroll
        for (int m = 1; m < 16; m <<= 1) {
            hs0 += __shfl_xor(hs0, m); hs1 += __shfl_xor(hs1, m);
            hs2 += __shfl_xor(hs2, m); hs3 += __shfl_xor(hs3, m);
        }
        if (cl == 0) {
            float4 hp4 = {hs0, hs1, hs2, hs3};
            *(float4*)&s_scr[rh * 64 + d0] = hp4;   // h-part bands [0:128)
        }
    }
    __syncthreads();   // B4: h_new in sIn visible

    // ===== MSG MLP: two K-half passes =====
    {
        f4v a6[2][2];
        a6[0][0] = fzero; a6[0][1] = fzero; a6[1][0] = fzero; a6[1][1] = fzero;
        const ushort_t* wm1 = wb + OFF_MW1;
        const ushort_t* wm2 = wb + OFF_MW2;
        #pragma unroll
        for (int p = 0; p < 2; p++) {
            {   // msg L1 half: mhid^ = mfma(mw1, h_new)
                f4v acc[4] = {fzero, fzero, fzero, fzero};
                const int hrow = p * 128 + 16 * w + cl;
                __builtin_amdgcn_s_setprio(1);
                #pragma unroll
                for (int ks = 0; ks < 2; ks++) {
                    const int k0 = ks * 32 + q * 8;
                    const s8v aw = *(const s8v*)(wm1 + (size_t)hrow * 64 + k0);
                    #pragma unroll
                    for (int rt = 0; rt < 4; rt++) {
                        const int ar = rt * 16 + cl;
                        const s8v bi = *(const s8v*)((const char*)sIn + SWZ(ar * 256 + k0 * 2, ar));
                        acc[rt] = __builtin_amdgcn_mfma_f32_16x16x32_bf16(aw, bi, acc[rt], 0, 0, 0);
                    }
                }
                __builtin_amdgcn_s_setprio(0);
                const int hc0 = p * 128 + 16 * w + q * 4;
                const float4 b1 = *(const float4*)&mb1[hc0];
                const float4 g1 = *(const float4*)&mgs1[g * 256 + hc0];
                const float4 o1 = *(const float4*)&mgb1[g * 256 + hc0];
                const int lc0 = 16 * w + q * 4;
                #pragma unroll
                for (int rt = 0; rt < 4; rt++) {
                    const int n = rt * 16 + cl;
                    const float t0 = fast_tanh(fmaf(acc[rt][0] + b1.x, g1.x, o1.x));
                    const float t1 = fast_tanh(fmaf(acc[rt][1] + b1.y, g1.y, o1.y));
                    const float t2 = fast_tanh(fmaf(acc[rt][2] + b1.z, g1.z, o1.z));
                    const float t3 = fast_tanh(fmaf(acc[rt][3] + b1.w, g1.w, o1.w));
                    uint2 pkd; pkd.x = pk2(t0, t1); pkd.y = pk2(t2, t3);
                    *(uint2*)((char*)sHid + SWZ(n * 256 + lc0 * 2, n)) = pkd;
                }
            }
            __syncthreads();   // mhid half visible
            {   // msg L2 partial: mfma(mw2, mhid)
                __builtin_amdgcn_s_setprio(1);
                #pragma unroll
                for (int ks = 0; ks < 4; ks++) {
                    const int k0 = ks * 32 + q * 8;
                    const s8v aw = *(const s8v*)(wm2 + (size_t)dA * 256 + p * 128 + k0);
                    #pragma unroll
                    for (int nt = 0; nt < 2; nt++) {
                        const int ar = (rh * 2 + nt) * 16 + cl;
                        const s8v bh = *(const s8v*)((const char*)sHid + SWZ(ar * 256 + k0 * 2, ar));
                        a6[nt][ks & 1] = __builtin_amdgcn_mfma_f32_16x16x32_bf16(aw, bh, a6[nt][ks & 1], 0, 0, 0);
                    }
                }
                __builtin_amdgcn_s_setprio(0);
            }
            if (p == 0) __syncthreads();
        }
        // epilogue: msg_new (+nid, float4 stores), mmean partials, readout
        const float4 b2 = *(const float4*)&mb2[d0];
        const float4 g2 = *(const float4*)&mgs2[g * 64 + d0];
        const float4 o2 = *(const float4*)&mgb2[g * 64 + d0];
        float ms0 = 0.f, ms1 = 0.f, ms2 = 0.f, ms3 = 0.f;
        float ro0 = 0.f, ro1 = 0.f, ro2 = 0.f, ro3 = 0.f;
        #pragma unroll
        for (int nt = 0; nt < 2; nt++) {
            const int n = (rh * 2 + nt) * 16 + cl;
            const float4 nv = *(const float4*)(nidp + (size_t)c * 4096 + (size_t)n * 64 + d0);
            float4 mv;
            mv.x = fast_tanh(fmaf(a6[nt][0][0] + a6[nt][1][0] + b2.x, g2.x, o2.x)) + nv.x;
            mv.y = fast_tanh(fmaf(a6[nt][0][1] + a6[nt][1][1] + b2.y, g2.y, o2.y)) + nv.y;
            mv.z = fast_tanh(fmaf(a6[nt][0][2] + a6[nt][1][2] + b2.z, g2.z, o2.z)) + nv.z;
            mv.w = fast_tanh(fmaf(a6[nt][0][3] + a6[nt][1][3] + b2.w, g2.w, o2.w)) + nv.w;
            *(float4*)(out_msg + tile + (size_t)n * 64 + d0) = mv;
            ms0 += mv.x; ms1 += mv.y; ms2 += mv.z; ms3 += mv.w;
            if (nt == 0 && rh == 0 && n >= 4 && n < 8) {
                ro0 = mv.x; ro1 = mv.y; ro2 = mv.z; ro3 = mv.w;
            }
        }
        #pragma unroll
        for (int m = 1; m < 16; m <<= 1) {
            ms0 += __shfl_xor(ms0, m); ms1 += __shfl_xor(ms1, m);
            ms2 += __shfl_xor(ms2, m); ms3 += __shfl_xor(ms3, m);
        }
        if (cl == 0) {
            float4 mp4 = {ms0, ms1, ms2, ms3};
            *(float4*)&s_scr[128 + rh * 64 + d0] = mp4;   // m-part bands [128:256)
        }
        // readout: sum over n=4..7 (lanes cl=4..7, rh==0); xor 1,2 stays in group
        ro0 += __shfl_xor(ro0, 1); ro1 += __shfl_xor(ro1, 1);
        ro2 += __shfl_xor(ro2, 1); ro3 += __shfl_xor(ro3, 1);
        ro0 += __shfl_xor(ro0, 2); ro1 += __shfl_xor(ro1, 2);
        ro2 += __shfl_xor(ro2, 2); ro3 += __shfl_xor(ro3, 2);
        if (rh == 0 && cl == 4) {
            float4 o4 = {ro0 * 0.5f, ro1 * 0.5f, ro2 * 0.5f, ro3 * 0.5f};
            *(float4*)(out_read + ((size_t)b * NCC + c) * 64 + d0) = o4;
        }
    }
    __syncthreads();   // B6

    // ================= P7: feats record (130 values) =================
    if (t < 132) {
        float v = 0.f;
        if (t < 64)        v = (s_scr[t] + s_scr[64 + t]) * (1.f / 64.f);
        else if (t < 128)  v = (s_scr[64 + t] + s_scr[128 + t]) * (1.f / 64.f);
        else if (t == 128) v = (s_wsum[0] + s_wsum[1] + s_wsum[2] + s_wsum[3]
                              + s_wsum[4] + s_wsum[5] + s_wsum[6] + s_wsum[7]) * (1.f / 4096.f);
        else if (t == 129) v = s_dsum * (1.f / 64.f);
        wsf[(size_t)bc * 132 + t] = v;
    }
}

// ---------------------------------------------------------------------------
// Kernel 2: per-cell modulation MLP (distinct weights per cell)
// ---------------------------------------------------------------------------
__global__ __launch_bounds__(256, 2)
void mg_mod_kernel(
    const float* __restrict__ wsf,   const float* __restrict__ modw1,
    const float* __restrict__ modb1, const float* __restrict__ modw2,
    const float* __restrict__ modb2, const float* __restrict__ ctxp,
    const float* __restrict__ bglp,  float* __restrict__ out_ctx,
    float* __restrict__ out_bg)
{
    const int c = blockIdx.x;
    const int t = threadIdx.x;
    __shared__ float s_f[8][MODIN];
    __shared__ float s_h2[8][HMODL];

    for (int k = t; k < 8 * MODIN; k += 256) {
        const int b = k / MODIN, f = k - b * MODIN;
        float v;
        if (f < 130)      v = wsf[((size_t)b * NCC + c) * 132 + f];
        else if (f < 194) v = ctxp[((size_t)b * NCC + c) * 64 + (f - 130)];
        else              v = bglp[((size_t)b * NCC + c) * 4 + (f - 194)];
        s_f[b][f] = v;
    }
    __syncthreads();

    {
        const int hh = t & 127, bh = (t >> 7) * 4;
        float a0 = 0.f, a1 = 0.f, a2 = 0.f, a3 = 0.f;
        const float* wp = modw1 + (size_t)c * MODIN * HMODL + hh;
        for (int f = 0; f < MODIN; f++) {
            const float wv = wp[(size_t)f * HMODL];
            a0 = fmaf(s_f[bh + 0][f], wv, a0);
            a1 = fmaf(s_f[bh + 1][f], wv, a1);
            a2 = fmaf(s_f[bh + 2][f], wv, a2);
            a3 = fmaf(s_f[bh + 3][f], wv, a3);
        }
        const float bv = modb1[(size_t)c * HMODL + hh];
        s_h2[bh + 0][hh] = fast_tanh(a0 + bv);
        s_h2[bh + 1][hh] = fast_tanh(a1 + bv);
        s_h2[bh + 2][hh] = fast_tanh(a2 + bv);
        s_h2[bh + 3][hh] = fast_tanh(a3 + bv);
    }
    __syncthreads();

    for (int idx = t; idx < 8 * MODOUT; idx += 256) {
        const int b = idx / MODOUT, o = idx - b * MODOUT;
        float acc = modb2[(size_t)c * MODOUT + o];
        const float* wp = modw2 + (size_t)c * HMODL * MODOUT + o;
        const float* hrow = s_h2[b];
        for (int hh = 0; hh < HMODL; hh++)
            acc = fmaf(hrow[hh], wp[(size_t)hh * MODOUT], acc);
        if (o < 64)
            out_ctx[((size_t)b * NCC + c) * 64 + o] =
                ctxp[((size_t)b * NCC + c) * 64 + o] + acc;
        else
            out_bg[((size_t)b * NCC + c) * 4 + (o - 64)] =
                bglp[((size_t)b * NCC + c) * 4 + (o - 64)] + acc;
    }
}

extern "C" void kernel_launch(void* const* d_in, const int* in_sizes, int n_in,
                              void* d_out, int out_size, void* d_ws, size_t ws_size,
                              hipStream_t stream) {
    const float* xp     = (const float*)d_in[0];
    const float* hp     = (const float*)d_in[1];
    const float* msgp   = (const float*)d_in[2];
    const float* Wp     = (const float*)d_in[3];
    const float* decayp = (const float*)d_in[4];
    const float* ctxp   = (const float*)d_in[5];
    const float* bglp   = (const float*)d_in[6];
    const float* nidp   = (const float*)d_in[7];
    const float* sw1    = (const float*)d_in[8];
    const float* sb1    = (const float*)d_in[9];
    const float* sgs1   = (const float*)d_in[10];
    const float* sgb1   = (const float*)d_in[11];
    const float* sw2    = (const float*)d_in[12];
    const float* sb2    = (const float*)d_in[13];
    const float* sgs2   = (const float*)d_in[14];
    const float* sgb2   = (const float*)d_in[15];
    const float* mw1    = (const float*)d_in[16];
    const float* mb1    = (const float*)d_in[17];
    const float* mgs1   = (const float*)d_in[18];
    const float* mgb1   = (const float*)d_in[19];
    const float* mw2    = (const float*)d_in[20];
    const float* mb2    = (const float*)d_in[21];
    const float* mgs2   = (const float*)d_in[22];
    const float* mgb2   = (const float*)d_in[23];
    const float* iw     = (const float*)d_in[24];
    const float* ibias  = (const float*)d_in[25];
    const float* modw1  = (const float*)d_in[26];
    const float* modb1  = (const float*)d_in[27];
    const float* modw2  = (const float*)d_in[28];
    const float* modb2  = (const float*)d_in[29];
    const int*   c2g    = (const int*)d_in[30];

    float* out      = (float*)d_out;
    float* out_read = out;                 // 524288
    float* out_h    = out_read + 524288;   // 33554432
    float* out_msg  = out_h + 33554432;    // 33554432
    float* out_ctx  = out_msg + 33554432;  // 524288
    float* out_bg   = out_ctx + 524288;    // 32768

    ushort_t* wb  = (ushort_t*)d_ws;                          // 160KB bf16 weights
    float*    wsf = (float*)((char*)d_ws + FEATS_BYTE_OFF);   // 8192 x 132 f32

    mg_cvtw<<<320, 256, 0, stream>>>(sw1, sw2, mw1, mw2, wb);

    // inject -> head of each out_h tile (read by P1, overwritten by state epilogue)
    mg_inject<<<1024, 256, 0, stream>>>(xp, iw, ibias, c2g, out_h);

    mg_cell_kernel<<<8192, 512, 0, stream>>>(
        hp, msgp, Wp, decayp, bglp, nidp,
        sb1, sgs1, sgb1, sb2, sgs2, sgb2,
        mb1, mgs1, mgb1, mb2, mgs2, mgb2,
        c2g, wb, out_read, out_h, out_msg, wsf);

    mg_mod_kernel<<<1024, 256, 0, stream>>>(
        wsf, modw1, modb1, modw2, modb2, ctxp, bglp, out_ctx, out_bg);
}

// Round 16
// 435.049 us; speedup vs baseline: 1.5917x; 1.0252x over previous
//
#include <hip/hip_runtime.h>

#define NCC 1024
#define MODIN 198
#define MODOUT 68
#define HMODL 128

typedef __attribute__((ext_vector_type(8))) short s8v;   // 8 bf16 = 4 VGPR
typedef __attribute__((ext_vector_type(4))) float f4v;   // MFMA acc
typedef unsigned short ushort_t;
typedef unsigned int uint_t;

// ws layout (ushort elems): sw1 @0 (32768), sw2 @32768 (16384), mw1 @49152 (16384), mw2 @65536 (16384)
#define OFF_SW1 0
#define OFF_SW2 32768
#define OFF_MW1 49152
#define OFF_MW2 65536
#define FEATS_BYTE_OFF 262144   // feats: 8192 cells x 132 f32

__device__ __forceinline__ float fast_tanh(float x) {
    const float e = __builtin_amdgcn_exp2f(x * 2.885390081777927f);   // e^{2x}
    const float r = __builtin_amdgcn_rcpf(e + 1.f);
    return fmaf(-2.f, r, 1.f);
}
__device__ __forceinline__ float fast_sigmoid(float x) {
    const float e = __builtin_amdgcn_exp2f(x * -1.4426950408889634f);
    return __builtin_amdgcn_rcpf(e + 1.f);
}
__device__ __forceinline__ ushort_t f2bf(float x) {   // RNE f32->bf16 (scalar path)
    uint_t u = __builtin_bit_cast(uint_t, x);
    u += 0x7FFFu + ((u >> 16) & 1u);
    return (ushort_t)(u >> 16);
}
__device__ __forceinline__ uint_t pk2(float a, float b) {   // HW pack: 1 instr, RNE
    uint_t r;
    asm("v_cvt_pk_bf16_f32 %0, %1, %2" : "=v"(r) : "v"(a), "v"(b));
    return r;
}
// XOR swizzle on LDS byte offsets (16B granule)
#define SWZ(byteoff, row) ((byteoff) ^ (((row) & 7) << 4))

// ---------------------------------------------------------------------------
// Kernel 0: convert the 4 shared MLP weight matrices to bf16 once per launch
// ---------------------------------------------------------------------------
__global__ __launch_bounds__(256)
void mg_cvtw(const float* __restrict__ sw1, const float* __restrict__ sw2,
             const float* __restrict__ mw1, const float* __restrict__ mw2,
             ushort_t* __restrict__ o) {
    const int i = blockIdx.x * 256 + threadIdx.x;   // grid 320 -> 81920 exact
    float v;
    if (i < 32768)      v = sw1[i];
    else if (i < 49152) v = sw2[i - 32768];
    else if (i < 65536) v = mw1[i - 49152];
    else                v = mw2[i - 65536];
    o[i] = f2bf(v);
}

// ---------------------------------------------------------------------------
// Kernel 0b: inject[b,c,o] -> head of each out_h tile (read by P1)
// ---------------------------------------------------------------------------
__global__ __launch_bounds__(256, 4)
void mg_inject(const float* __restrict__ xp, const float* __restrict__ iw,
               const float* __restrict__ ibias, const int* __restrict__ c2g,
               float* __restrict__ injb) {
    const int c = blockIdx.x, t = threadIdx.x;
    const int g = c2g[c];
    __shared__ float s_x[8][64];
    for (int idx = t; idx < 512; idx += 256)
        s_x[idx >> 6][idx & 63] = xp[(size_t)(idx >> 6) * (NCC * 64) + c * 64 + (idx & 63)];
    __syncthreads();
    const float* wrow = iw + (size_t)g * 16384 + t * 64;
    float a0 = 0.f, a1 = 0.f, a2 = 0.f, a3 = 0.f, a4 = 0.f, a5 = 0.f, a6 = 0.f, a7 = 0.f;
    #pragma unroll
    for (int i = 0; i < 64; i += 4) {
        const float4 w4 = *(const float4*)(wrow + i);
        const float4 x0 = *(const float4*)&s_x[0][i];
        const float4 x1 = *(const float4*)&s_x[1][i];
        const float4 x2 = *(const float4*)&s_x[2][i];
        const float4 x3 = *(const float4*)&s_x[3][i];
        const float4 x4 = *(const float4*)&s_x[4][i];
        const float4 x5 = *(const float4*)&s_x[5][i];
        const float4 x6 = *(const float4*)&s_x[6][i];
        const float4 x7 = *(const float4*)&s_x[7][i];
        a0 = fmaf(w4.x, x0.x, a0); a0 = fmaf(w4.y, x0.y, a0); a0 = fmaf(w4.z, x0.z, a0); a0 = fmaf(w4.w, x0.w, a0);
        a1 = fmaf(w4.x, x1.x, a1); a1 = fmaf(w4.y, x1.y, a1); a1 = fmaf(w4.z, x1.z, a1); a1 = fmaf(w4.w, x1.w, a1);
        a2 = fmaf(w4.x, x2.x, a2); a2 = fmaf(w4.y, x2.y, a2); a2 = fmaf(w4.z, x2.z, a2); a2 = fmaf(w4.w, x2.w, a2);
        a3 = fmaf(w4.x, x3.x, a3); a3 = fmaf(w4.y, x3.y, a3); a3 = fmaf(w4.z, x3.z, a3); a3 = fmaf(w4.w, x3.w, a3);
        a4 = fmaf(w4.x, x4.x, a4); a4 = fmaf(w4.y, x4.y, a4); a4 = fmaf(w4.z, x4.z, a4); a4 = fmaf(w4.w, x4.w, a4);
        a5 = fmaf(w4.x, x5.x, a5); a5 = fmaf(w4.y, x5.y, a5); a5 = fmaf(w4.z, x5.z, a5); a5 = fmaf(w4.w, x5.w, a5);
        a6 = fmaf(w4.x, x6.x, a6); a6 = fmaf(w4.y, x6.y, a6); a6 = fmaf(w4.z, x6.z, a6); a6 = fmaf(w4.w, x6.w, a6);
        a7 = fmaf(w4.x, x7.x, a7); a7 = fmaf(w4.y, x7.y, a7); a7 = fmaf(w4.z, x7.z, a7); a7 = fmaf(w4.w, x7.w, a7);
    }
    const float bv = ibias[g * 256 + t];
    const float acc[8] = {a0, a1, a2, a3, a4, a5, a6, a7};
    #pragma unroll
    for (int b = 0; b < 8; b++)
        injb[((size_t)b * NCC + c) * 4096 + t] = acc[b] + bv;
}

// ---------------------------------------------------------------------------
// Kernel 1: per (b, cell) block; 512 threads = 8 waves; two-K-half MLPs
// (round-14 structure, LDS ~34KB), operand-swapped MFMAs (round 15).
// Round-16: all paired f32->bf16 packs via v_cvt_pk_bf16_f32 (1 instr).
// ---------------------------------------------------------------------------
__global__ __launch_bounds__(512, 4)
void mg_cell_kernel(
    const float* __restrict__ hp,   const float* __restrict__ msgp,
    const float* __restrict__ Wp,   const float* __restrict__ decayp,
    const float* __restrict__ bglp, const float* __restrict__ nidp,
    const float* __restrict__ sb1,  const float* __restrict__ sgs1,
    const float* __restrict__ sgb1, const float* __restrict__ sb2,
    const float* __restrict__ sgs2, const float* __restrict__ sgb2,
    const float* __restrict__ mb1,  const float* __restrict__ mgs1,
    const float* __restrict__ mgb1, const float* __restrict__ mb2,
    const float* __restrict__ mgs2, const float* __restrict__ mgb2,
    const int*   __restrict__ c2g,  const ushort_t* __restrict__ wb,
    float* __restrict__ out_read, float* __restrict__ out_h,
    float* __restrict__ out_msg,  float* __restrict__ wsf)
{
    const int t  = threadIdx.x;
    const int bc = blockIdx.x;
    const int b  = bc >> 10, c = bc & 1023;
    const int gh = c >> 5, gwc = c & 31;
    const int lane = t & 63, w = t >> 6;
    const int cl = lane & 15, q = lane >> 4;
    const int g  = c2g[c];
    const size_t tile = (size_t)bc * 4096;

    __shared__ ushort_t sHid[8192];    // [64][128] bf16 16KB; overlays sW|sMsgT
    __shared__ ushort_t sIn[8192];     // [64][128] bf16: [received/h_new | h]
    __shared__ float s_scr[256];       // border; later h-part[2][64] @0, m-part[2][64] @128
    __shared__ float s_dec[64];
    __shared__ float s_wsum[8];
    __shared__ float s_dsum;

    ushort_t* sW    = sHid;            // [64][64], row stride 128B
    ushort_t* sMsgT = sHid + 4096;     // [64 d][64 m]

    // ================= P0: staging + border + decay =================
    {   // W -> sW bf16 (+ sum|W|): n = t>>3, 8 cols each
        const int n = t >> 3, m0 = (t & 7) * 8;
        const float* src = Wp + tile + n * 64 + m0;
        const float4 v0 = *(const float4*)(src);
        const float4 v1 = *(const float4*)(src + 4);
        float wsum = fabsf(v0.x) + fabsf(v0.y) + fabsf(v0.z) + fabsf(v0.w)
                   + fabsf(v1.x) + fabsf(v1.y) + fabsf(v1.z) + fabsf(v1.w);
        *(uint_t*)((char*)sW + SWZ(n * 128 + (m0 + 0) * 2, n)) = pk2(v0.x, v0.y);
        *(uint_t*)((char*)sW + SWZ(n * 128 + (m0 + 2) * 2, n)) = pk2(v0.z, v0.w);
        *(uint_t*)((char*)sW + SWZ(n * 128 + (m0 + 4) * 2, n)) = pk2(v1.x, v1.y);
        *(uint_t*)((char*)sW + SWZ(n * 128 + (m0 + 6) * 2, n)) = pk2(v1.z, v1.w);
        #pragma unroll
        for (int off = 32; off > 0; off >>= 1) wsum += __shfl_down(wsum, off);
        if (lane == 0) s_wsum[w] = wsum;
    }
    #pragma unroll
    for (int i = 0; i < 2; i++) {   // msg^T -> sMsgT bf16
        const int m = (t >> 4) + i * 32, d0 = (t & 15) * 4;
        const float4 v = *(const float4*)(msgp + tile + (size_t)m * 64 + d0);
        *(ushort_t*)((char*)sMsgT + SWZ((d0 + 0) * 128 + m * 2, d0 + 0)) = f2bf(v.x);
        *(ushort_t*)((char*)sMsgT + SWZ((d0 + 1) * 128 + m * 2, d0 + 1)) = f2bf(v.y);
        *(ushort_t*)((char*)sMsgT + SWZ((d0 + 2) * 128 + m * 2, d0 + 2)) = f2bf(v.z);
        *(ushort_t*)((char*)sMsgT + SWZ((d0 + 3) * 128 + m * 2, d0 + 3)) = f2bf(v.w);
    }
    #pragma unroll
    for (int i = 0; i < 2; i++) {   // h -> sIn[:,64:128] bf16
        const int n = (t >> 4) + i * 32, d0 = (t & 15) * 4;
        const float4 v = *(const float4*)(hp + tile + (size_t)n * 64 + d0);
        *(uint_t*)((char*)sIn + SWZ(n * 256 + (64 + d0) * 2, n))     = pk2(v.x, v.y);
        *(uint_t*)((char*)sIn + SWZ(n * 256 + (64 + d0 + 2) * 2, n)) = pk2(v.z, v.w);
    }
    if (t < 256) {   // gated border incoming: wave p = w (0..3)
        const int p = w, dd = lane;
        int ok, nc2, qq;
        if      (p == 0) { ok = (gh > 0);   nc2 = c - 32; qq = 1; }
        else if (p == 1) { ok = (gh < 31);  nc2 = c + 32; qq = 0; }
        else if (p == 2) { ok = (gwc > 0);  nc2 = c - 1;  qq = 3; }
        else             { ok = (gwc < 31); nc2 = c + 1;  qq = 2; }
        float v = 0.f;
        if (ok) v = msgp[((size_t)b * NCC + nc2) * 4096 + (8 + qq) * 64 + dd];
        s_scr[p * 64 + dd] = fast_sigmoid(bglp[(size_t)bc * 4 + p]) * v;
    }
    if (w == 4) {   // decay sigmoid table + logit sum
        const float dl = decayp[(size_t)bc * 64 + lane];
        s_dec[lane] = fast_sigmoid(dl);
        float v = dl;
        #pragma unroll
        for (int off = 32; off > 0; off >>= 1) v += __shfl_down(v, off);
        if (lane == 0) s_dsum = v;
    }
    __syncthreads();   // B1

    const f4v fzero = {0.f, 0.f, 0.f, 0.f};
    const int d0 = 16 * (w & 3) + q * 4;   // this thread's 4 output cols (epilogues)
    const int dA = 16 * (w & 3) + cl;      // A-operand weight-row index (reads)
    const int rh = w >> 2;                 // row-half

    // ========== P1: received^ = mfma(msgT, W) + inject + border -> sIn[:,0:64] ==========
    {
        f4v wm[2] = {fzero, fzero};
        __builtin_amdgcn_s_setprio(1);
        #pragma unroll
        for (int ks = 0; ks < 2; ks++) {
            const int k0 = ks * 32 + q * 8;
            const s8v am = *(const s8v*)((const char*)sMsgT + SWZ(dA * 128 + k0 * 2, dA));
            #pragma unroll
            for (int nt = 0; nt < 2; nt++) {
                const int ar = (rh * 2 + nt) * 16 + cl;
                const s8v bw = *(const s8v*)((const char*)sW + SWZ(ar * 128 + k0 * 2, ar));
                wm[nt] = __builtin_amdgcn_mfma_f32_16x16x32_bf16(am, bw, wm[nt], 0, 0, 0);
            }
        }
        __builtin_amdgcn_s_setprio(0);
        #pragma unroll
        for (int nt = 0; nt < 2; nt++) {
            const int n = (rh * 2 + nt) * 16 + cl;
            float v0 = wm[nt][0], v1 = wm[nt][1], v2 = wm[nt][2], v3 = wm[nt][3];
            if (n < 4) {
                const float4 inj = *(const float4*)(out_h + tile + (size_t)n * 64 + d0);
                v0 += inj.x; v1 += inj.y; v2 += inj.z; v3 += inj.w;
            } else if (n >= 8 && n < 12) {
                const float4 bin = *(const float4*)&s_scr[(n - 8) * 64 + d0];
                v0 += bin.x; v1 += bin.y; v2 += bin.z; v3 += bin.w;
            }
            uint2 pkd; pkd.x = pk2(v0, v1); pkd.y = pk2(v2, v3);
            *(uint2*)((char*)sIn + SWZ(n * 256 + d0 * 2, n)) = pkd;
        }
    }
    __syncthreads();   // B2 (P1's sW/sMsgT reads done -> sHid overlay safe)

    // ===== STATE MLP: two K-half passes (hid cols p*128..p*128+128) =====
    {
        f4v a2[2][2];
        a2[0][0] = fzero; a2[0][1] = fzero; a2[1][0] = fzero; a2[1][1] = fzero;
        const ushort_t* wb1 = wb + OFF_SW1;
        const ushort_t* wb2 = wb + OFF_SW2;
        #pragma unroll
        for (int p = 0; p < 2; p++) {
            {   // L1 half: wave w owns hid cols [p*128+16w, +16); hid^ = mfma(w1, in)
                f4v acc[4] = {fzero, fzero, fzero, fzero};
                const int hrow = p * 128 + 16 * w + cl;      // w1 row (A operand)
                __builtin_amdgcn_s_setprio(1);
                #pragma unroll
                for (int ks = 0; ks < 4; ks++) {
                    const int k0 = ks * 32 + q * 8;
                    const s8v aw = *(const s8v*)(wb1 + (size_t)hrow * 128 + k0);
                    #pragma unroll
                    for (int rt = 0; rt < 4; rt++) {
                        const int ar = rt * 16 + cl;
                        const s8v bi = *(const s8v*)((const char*)sIn + SWZ(ar * 256 + k0 * 2, ar));
                        acc[rt] = __builtin_amdgcn_mfma_f32_16x16x32_bf16(aw, bi, acc[rt], 0, 0, 0);
                    }
                }
                __builtin_amdgcn_s_setprio(0);
                const int hc0 = p * 128 + 16 * w + q * 4;    // 4 consecutive hid cols
                const float4 b1 = *(const float4*)&sb1[hc0];
                const float4 g1 = *(const float4*)&sgs1[g * 256 + hc0];
                const float4 o1 = *(const float4*)&sgb1[g * 256 + hc0];
                const int lc0 = 16 * w + q * 4;              // local col in sHid
                #pragma unroll
                for (int rt = 0; rt < 4; rt++) {
                    const int n = rt * 16 + cl;
                    const float t0 = fast_tanh(fmaf(acc[rt][0] + b1.x, g1.x, o1.x));
                    const float t1 = fast_tanh(fmaf(acc[rt][1] + b1.y, g1.y, o1.y));
                    const float t2 = fast_tanh(fmaf(acc[rt][2] + b1.z, g1.z, o1.z));
                    const float t3 = fast_tanh(fmaf(acc[rt][3] + b1.w, g1.w, o1.w));
                    uint2 pkd; pkd.x = pk2(t0, t1); pkd.y = pk2(t2, t3);
                    *(uint2*)((char*)sHid + SWZ(n * 256 + lc0 * 2, n)) = pkd;
                }
            }
            __syncthreads();   // hid half visible
            {   // L2 partial: cand^ = mfma(w2, hid)
                __builtin_amdgcn_s_setprio(1);
                #pragma unroll
                for (int ks = 0; ks < 4; ks++) {
                    const int k0 = ks * 32 + q * 8;
                    const s8v aw = *(const s8v*)(wb2 + (size_t)dA * 256 + p * 128 + k0);
                    #pragma unroll
                    for (int nt = 0; nt < 2; nt++) {
                        const int ar = (rh * 2 + nt) * 16 + cl;
                        const s8v bh = *(const s8v*)((const char*)sHid + SWZ(ar * 256 + k0 * 2, ar));
                        a2[nt][ks & 1] = __builtin_amdgcn_mfma_f32_16x16x32_bf16(aw, bh, a2[nt][ks & 1], 0, 0, 0);
                    }
                }
                __builtin_amdgcn_s_setprio(0);
            }
            if (p == 0) __syncthreads();   // hid reads done before overwrite
        }
        // epilogue: cand -> h_new (float4 global + packed sIn) + h_mean partials
        const float4 b2 = *(const float4*)&sb2[d0];
        const float4 g2 = *(const float4*)&sgs2[g * 64 + d0];
        const float4 o2 = *(const float4*)&sgb2[g * 64 + d0];
        float hs0 = 0.f, hs1 = 0.f, hs2 = 0.f, hs3 = 0.f;
        #pragma unroll
        for (int nt = 0; nt < 2; nt++) {
            const int n = (rh * 2 + nt) * 16 + cl;
            const float dec = s_dec[n];
            const uint2 hu = *(const uint2*)((const char*)sIn + SWZ(n * 256 + (64 + d0) * 2, n));
            const float hv0 = __builtin_bit_cast(float, (uint_t)(hu.x << 16));
            const float hv1 = __builtin_bit_cast(float, hu.x & 0xFFFF0000u);
            const float hv2 = __builtin_bit_cast(float, (uint_t)(hu.y << 16));
            const float hv3 = __builtin_bit_cast(float, hu.y & 0xFFFF0000u);
            const float c0 = fast_tanh(fmaf(a2[nt][0][0] + a2[nt][1][0] + b2.x, g2.x, o2.x));
            const float c1 = fast_tanh(fmaf(a2[nt][0][1] + a2[nt][1][1] + b2.y, g2.y, o2.y));
            const float c2 = fast_tanh(fmaf(a2[nt][0][2] + a2[nt][1][2] + b2.z, g2.z, o2.z));
            const float c3 = fast_tanh(fmaf(a2[nt][0][3] + a2[nt][1][3] + b2.w, g2.w, o2.w));
            float4 hn;
            hn.x = fmaf(dec, hv0 - c0, c0);
            hn.y = fmaf(dec, hv1 - c1, c1);
            hn.z = fmaf(dec, hv2 - c2, c2);
            hn.w = fmaf(dec, hv3 - c3, c3);
            *(float4*)(out_h + tile + (size_t)n * 64 + d0) = hn;
            uint2 pkd; pkd.x = pk2(hn.x, hn.y); pkd.y = pk2(hn.z, hn.w);
            *(uint2*)((char*)sIn + SWZ(n * 256 + d0 * 2, n)) = pkd;
            hs0 += hn.x; hs1 += hn.y; hs2 += hn.z; hs3 += hn.w;
        }
        #pragma unroll
        for (int m = 1; m < 16; m <<= 1) {
            hs0 += __shfl_xor(hs0, m); hs1 += __shfl_xor(hs1, m);
            hs2 += __shfl_xor(hs2, m); hs3 += __shfl_xor(hs3, m);
        }
        if (cl == 0) {
            float4 hp4 = {hs0, hs1, hs2, hs3};
            *(float4*)&s_scr[rh * 64 + d0] = hp4;   // h-part bands [0:128)
        }
    }
    __syncthreads();   // B4: h_new in sIn visible

    // ===== MSG MLP: two K-half passes =====
    {
        f4v a6[2][2];
        a6[0][0] = fzero; a6[0][1] = fzero; a6[1][0] = fzero; a6[1][1] = fzero;
        const ushort_t* wm1 = wb + OFF_MW1;
        const ushort_t* wm2 = wb + OFF_MW2;
        #pragma unroll
        for (int p = 0; p < 2; p++) {
            {   // msg L1 half: mhid^ = mfma(mw1, h_new)
                f4v acc[4] = {fzero, fzero, fzero, fzero};
                const int hrow = p * 128 + 16 * w + cl;
                __builtin_amdgcn_s_setprio(1);
                #pragma unroll
                for (int ks = 0; ks < 2; ks++) {
                    const int k0 = ks * 32 + q * 8;
                    const s8v aw = *(const s8v*)(wm1 + (size_t)hrow * 64 + k0);
                    #pragma unroll
                    for (int rt = 0; rt < 4; rt++) {
                        const int ar = rt * 16 + cl;
                        const s8v bi = *(const s8v*)((const char*)sIn + SWZ(ar * 256 + k0 * 2, ar));
                        acc[rt] = __builtin_amdgcn_mfma_f32_16x16x32_bf16(aw, bi, acc[rt], 0, 0, 0);
                    }
                }
                __builtin_amdgcn_s_setprio(0);
                const int hc0 = p * 128 + 16 * w + q * 4;
                const float4 b1 = *(const float4*)&mb1[hc0];
                const float4 g1 = *(const float4*)&mgs1[g * 256 + hc0];
                const float4 o1 = *(const float4*)&mgb1[g * 256 + hc0];
                const int lc0 = 16 * w + q * 4;
                #pragma unroll
                for (int rt = 0; rt < 4; rt++) {
                    const int n = rt * 16 + cl;
                    const float t0 = fast_tanh(fmaf(acc[rt][0] + b1.x, g1.x, o1.x));
                    const float t1 = fast_tanh(fmaf(acc[rt][1] + b1.y, g1.y, o1.y));
                    const float t2 = fast_tanh(fmaf(acc[rt][2] + b1.z, g1.z, o1.z));
                    const float t3 = fast_tanh(fmaf(acc[rt][3] + b1.w, g1.w, o1.w));
                    uint2 pkd; pkd.x = pk2(t0, t1); pkd.y = pk2(t2, t3);
                    *(uint2*)((char*)sHid + SWZ(n * 256 + lc0 * 2, n)) = pkd;
                }
            }
            __syncthreads();   // mhid half visible
            {   // msg L2 partial: mfma(mw2, mhid)
                __builtin_amdgcn_s_setprio(1);
                #pragma unroll
                for (int ks = 0; ks < 4; ks++) {
                    const int k0 = ks * 32 + q * 8;
                    const s8v aw = *(const s8v*)(wm2 + (size_t)dA * 256 + p * 128 + k0);
                    #pragma unroll
                    for (int nt = 0; nt < 2; nt++) {
                        const int ar = (rh * 2 + nt) * 16 + cl;
                        const s8v bh = *(const s8v*)((const char*)sHid + SWZ(ar * 256 + k0 * 2, ar));
                        a6[nt][ks & 1] = __builtin_amdgcn_mfma_f32_16x16x32_bf16(aw, bh, a6[nt][ks & 1], 0, 0, 0);
                    }
                }
                __builtin_amdgcn_s_setprio(0);
            }
            if (p == 0) __syncthreads();
        }
        // epilogue: msg_new (+nid, float4 stores), mmean partials, readout
        const float4 b2 = *(const float4*)&mb2[d0];
        const float4 g2 = *(const float4*)&mgs2[g * 64 + d0];
        const float4 o2 = *(const float4*)&mgb2[g * 64 + d0];
        float ms0 = 0.f, ms1 = 0.f, ms2 = 0.f, ms3 = 0.f;
        float ro0 = 0.f, ro1 = 0.f, ro2 = 0.f, ro3 = 0.f;
        #pragma unroll
        for (int nt = 0; nt < 2; nt++) {
            const int n = (rh * 2 + nt) * 16 + cl;
            const float4 nv = *(const float4*)(nidp + (size_t)c * 4096 + (size_t)n * 64 + d0);
            float4 mv;
            mv.x = fast_tanh(fmaf(a6[nt][0][0] + a6[nt][1][0] + b2.x, g2.x, o2.x)) + nv.x;
            mv.y = fast_tanh(fmaf(a6[nt][0][1] + a6[nt][1][1] + b2.y, g2.y, o2.y)) + nv.y;
            mv.z = fast_tanh(fmaf(a6[nt][0][2] + a6[nt][1][2] + b2.z, g2.z, o2.z)) + nv.z;
            mv.w = fast_tanh(fmaf(a6[nt][0][3] + a6[nt][1][3] + b2.w, g2.w, o2.w)) + nv.w;
            *(float4*)(out_msg + tile + (size_t)n * 64 + d0) = mv;
            ms0 += mv.x; ms1 += mv.y; ms2 += mv.z; ms3 += mv.w;
            if (nt == 0 && rh == 0 && n >= 4 && n < 8) {
                ro0 = mv.x; ro1 = mv.y; ro2 = mv.z; ro3 = mv.w;
            }
        }
        #pragma unroll
        for (int m = 1; m < 16; m <<= 1) {
            ms0 += __shfl_xor(ms0, m); ms1 += __shfl_xor(ms1, m);
            ms2 += __shfl_xor(ms2, m); ms3 += __shfl_xor(ms3, m);
        }
        if (cl == 0) {
            float4 mp4 = {ms0, ms1, ms2, ms3};
            *(float4*)&s_scr[128 + rh * 64 + d0] = mp4;   // m-part bands [128:256)
        }
        // readout: sum over n=4..7 (lanes cl=4..7, rh==0); xor 1,2 stays in group
        ro0 += __shfl_xor(ro0, 1); ro1 += __shfl_xor(ro1, 1);
        ro2 += __shfl_xor(ro2, 1); ro3 += __shfl_xor(ro3, 1);
        ro0 += __shfl_xor(ro0, 2); ro1 += __shfl_xor(ro1, 2);
        ro2 += __shfl_xor(ro2, 2); ro3 += __shfl_xor(ro3, 2);
        if (rh == 0 && cl == 4) {
            float4 o4 = {ro0 * 0.5f, ro1 * 0.5f, ro2 * 0.5f, ro3 * 0.5f};
            *(float4*)(out_read + ((size_t)b * NCC + c) * 64 + d0) = o4;
        }
    }
    __syncthreads();   // B6

    // ================= P7: feats record (130 values) =================
    if (t < 132) {
        float v = 0.f;
        if (t < 64)        v = (s_scr[t] + s_scr[64 + t]) * (1.f / 64.f);
        else if (t < 128)  v = (s_scr[64 + t] + s_scr[128 + t]) * (1.f / 64.f);
        else if (t == 128) v = (s_wsum[0] + s_wsum[1] + s_wsum[2] + s_wsum[3]
                              + s_wsum[4] + s_wsum[5] + s_wsum[6] + s_wsum[7]) * (1.f / 4096.f);
        else if (t == 129) v = s_dsum * (1.f / 64.f);
        wsf[(size_t)bc * 132 + t] = v;
    }
}

// ---------------------------------------------------------------------------
// Kernel 2: per-cell modulation MLP (distinct weights per cell)
// ---------------------------------------------------------------------------
__global__ __launch_bounds__(256, 2)
void mg_mod_kernel(
    const float* __restrict__ wsf,   const float* __restrict__ modw1,
    const float* __restrict__ modb1, const float* __restrict__ modw2,
    const float* __restrict__ modb2, const float* __restrict__ ctxp,
    const float* __restrict__ bglp,  float* __restrict__ out_ctx,
    float* __restrict__ out_bg)
{
    const int c = blockIdx.x;
    const int t = threadIdx.x;
    __shared__ float s_f[8][MODIN];
    __shared__ float s_h2[8][HMODL];

    for (int k = t; k < 8 * MODIN; k += 256) {
        const int b = k / MODIN, f = k - b * MODIN;
        float v;
        if (f < 130)      v = wsf[((size_t)b * NCC + c) * 132 + f];
        else if (f < 194) v = ctxp[((size_t)b * NCC + c) * 64 + (f - 130)];
        else              v = bglp[((size_t)b * NCC + c) * 4 + (f - 194)];
        s_f[b][f] = v;
    }
    __syncthreads();

    {
        const int hh = t & 127, bh = (t >> 7) * 4;
        float a0 = 0.f, a1 = 0.f, a2 = 0.f, a3 = 0.f;
        const float* wp = modw1 + (size_t)c * MODIN * HMODL + hh;
        for (int f = 0; f < MODIN; f++) {
            const float wv = wp[(size_t)f * HMODL];
            a0 = fmaf(s_f[bh + 0][f], wv, a0);
            a1 = fmaf(s_f[bh + 1][f], wv, a1);
            a2 = fmaf(s_f[bh + 2][f], wv, a2);
            a3 = fmaf(s_f[bh + 3][f], wv, a3);
        }
        const float bv = modb1[(size_t)c * HMODL + hh];
        s_h2[bh + 0][hh] = fast_tanh(a0 + bv);
        s_h2[bh + 1][hh] = fast_tanh(a1 + bv);
        s_h2[bh + 2][hh] = fast_tanh(a2 + bv);
        s_h2[bh + 3][hh] = fast_tanh(a3 + bv);
    }
    __syncthreads();

    for (int idx = t; idx < 8 * MODOUT; idx += 256) {
        const int b = idx / MODOUT, o = idx - b * MODOUT;
        float acc = modb2[(size_t)c * MODOUT + o];
        const float* wp = modw2 + (size_t)c * HMODL * MODOUT + o;
        const float* hrow = s_h2[b];
        for (int hh = 0; hh < HMODL; hh++)
            acc = fmaf(hrow[hh], wp[(size_t)hh * MODOUT], acc);
        if (o < 64)
            out_ctx[((size_t)b * NCC + c) * 64 + o] =
                ctxp[((size_t)b * NCC + c) * 64 + o] + acc;
        else
            out_bg[((size_t)b * NCC + c) * 4 + (o - 64)] =
                bglp[((size_t)b * NCC + c) * 4 + (o - 64)] + acc;
    }
}

extern "C" void kernel_launch(void* const* d_in, const int* in_sizes, int n_in,
                              void* d_out, int out_size, void* d_ws, size_t ws_size,
                              hipStream_t stream) {
    const float* xp     = (const float*)d_in[0];
    const float* hp     = (const float*)d_in[1];
    const float* msgp   = (const float*)d_in[2];
    const float* Wp     = (const float*)d_in[3];
    const float* decayp = (const float*)d_in[4];
    const float* ctxp   = (const float*)d_in[5];
    const float* bglp   = (const float*)d_in[6];
    const float* nidp   = (const float*)d_in[7];
    const float* sw1    = (const float*)d_in[8];
    const float* sb1    = (const float*)d_in[9];
    const float* sgs1   = (const float*)d_in[10];
    const float* sgb1   = (const float*)d_in[11];
    const float* sw2    = (const float*)d_in[12];
    const float* sb2    = (const float*)d_in[13];
    const float* sgs2   = (const float*)d_in[14];
    const float* sgb2   = (const float*)d_in[15];
    const float* mw1    = (const float*)d_in[16];
    const float* mb1    = (const float*)d_in[17];
    const float* mgs1   = (const float*)d_in[18];
    const float* mgb1   = (const float*)d_in[19];
    const float* mw2    = (const float*)d_in[20];
    const float* mb2    = (const float*)d_in[21];
    const float* mgs2   = (const float*)d_in[22];
    const float* mgb2   = (const float*)d_in[23];
    const float* iw     = (const float*)d_in[24];
    const float* ibias  = (const float*)d_in[25];
    const float* modw1  = (const float*)d_in[26];
    const float* modb1  = (const float*)d_in[27];
    const float* modw2  = (const float*)d_in[28];
    const float* modb2  = (const float*)d_in[29];
    const int*   c2g    = (const int*)d_in[30];

    float* out      = (float*)d_out;
    float* out_read = out;                 // 524288
    float* out_h    = out_read + 524288;   // 33554432
    float* out_msg  = out_h + 33554432;    // 33554432
    float* out_ctx  = out_msg + 33554432;  // 524288
    float* out_bg   = out_ctx + 524288;    // 32768

    ushort_t* wb  = (ushort_t*)d_ws;                          // 160KB bf16 weights
    float*    wsf = (float*)((char*)d_ws + FEATS_BYTE_OFF);   // 8192 x 132 f32

    mg_cvtw<<<320, 256, 0, stream>>>(sw1, sw2, mw1, mw2, wb);

    // inject -> head of each out_h tile (read by P1, overwritten by state epilogue)
    mg_inject<<<1024, 256, 0, stream>>>(xp, iw, ibias, c2g, out_h);

    mg_cell_kernel<<<8192, 512, 0, stream>>>(
        hp, msgp, Wp, decayp, bglp, nidp,
        sb1, sgs1, sgb1, sb2, sgs2, sgb2,
        mb1, mgs1, mgb1, mb2, mgs2, mgb2,
        c2g, wb, out_read, out_h, out_msg, wsf);

    mg_mod_kernel<<<1024, 256, 0, stream>>>(
        wsf, modw1, modb1, modw2, modb2, ctxp, bglp, out_ctx, out_bg);
}

// Round 17
// 413.101 us; speedup vs baseline: 1.6763x; 1.0531x over previous
//
#include <hip/hip_runtime.h>

#define NCC 1024
#define MODIN 198
#define MODOUT 68
#define HMODL 128

typedef __attribute__((ext_vector_type(8))) short s8v;   // 8 bf16 = 4 VGPR
typedef __attribute__((ext_vector_type(4))) float f4v;   // MFMA acc
typedef unsigned short ushort_t;
typedef unsigned int uint_t;

// ws layout (ushort elems): sw1 @0 (32768), sw2 @32768 (16384), mw1 @49152 (16384), mw2 @65536 (16384)
#define OFF_SW1 0
#define OFF_SW2 32768
#define OFF_MW1 49152
#define OFF_MW2 65536
#define FEATS_BYTE_OFF 262144   // feats: 8192 cells x 132 f32

__device__ __forceinline__ float fast_tanh(float x) {
    const float e = __builtin_amdgcn_exp2f(x * 2.885390081777927f);   // e^{2x}
    const float r = __builtin_amdgcn_rcpf(e + 1.f);
    return fmaf(-2.f, r, 1.f);
}
__device__ __forceinline__ float fast_sigmoid(float x) {
    const float e = __builtin_amdgcn_exp2f(x * -1.4426950408889634f);
    return __builtin_amdgcn_rcpf(e + 1.f);
}
__device__ __forceinline__ ushort_t f2bf(float x) {   // RNE f32->bf16 (scalar path)
    uint_t u = __builtin_bit_cast(uint_t, x);
    u += 0x7FFFu + ((u >> 16) & 1u);
    return (ushort_t)(u >> 16);
}
__device__ __forceinline__ uint_t pk2(float a, float b) {   // HW pack: 1 instr, RNE
    uint_t r;
    asm("v_cvt_pk_bf16_f32 %0, %1, %2" : "=v"(r) : "v"(a), "v"(b));
    return r;
}
// XOR swizzle on LDS byte offsets (16B granule)
#define SWZ(byteoff, row) ((byteoff) ^ (((row) & 7) << 4))

// ---------------------------------------------------------------------------
// Kernel 0: convert the 4 shared MLP weight matrices to bf16 once per launch
// ---------------------------------------------------------------------------
__global__ __launch_bounds__(256)
void mg_cvtw(const float* __restrict__ sw1, const float* __restrict__ sw2,
             const float* __restrict__ mw1, const float* __restrict__ mw2,
             ushort_t* __restrict__ o) {
    const int i = blockIdx.x * 256 + threadIdx.x;   // grid 320 -> 81920 exact
    float v;
    if (i < 32768)      v = sw1[i];
    else if (i < 49152) v = sw2[i - 32768];
    else if (i < 65536) v = mw1[i - 49152];
    else                v = mw2[i - 65536];
    o[i] = f2bf(v);
}

// ---------------------------------------------------------------------------
// Kernel 0b: inject[b,c,o] -> head of each out_h tile (read by P1)
// ---------------------------------------------------------------------------
__global__ __launch_bounds__(256, 4)
void mg_inject(const float* __restrict__ xp, const float* __restrict__ iw,
               const float* __restrict__ ibias, const int* __restrict__ c2g,
               float* __restrict__ injb) {
    const int c = blockIdx.x, t = threadIdx.x;
    const int g = c2g[c];
    __shared__ float s_x[8][64];
    for (int idx = t; idx < 512; idx += 256)
        s_x[idx >> 6][idx & 63] = xp[(size_t)(idx >> 6) * (NCC * 64) + c * 64 + (idx & 63)];
    __syncthreads();
    const float* wrow = iw + (size_t)g * 16384 + t * 64;
    float a0 = 0.f, a1 = 0.f, a2 = 0.f, a3 = 0.f, a4 = 0.f, a5 = 0.f, a6 = 0.f, a7 = 0.f;
    #pragma unroll
    for (int i = 0; i < 64; i += 4) {
        const float4 w4 = *(const float4*)(wrow + i);
        const float4 x0 = *(const float4*)&s_x[0][i];
        const float4 x1 = *(const float4*)&s_x[1][i];
        const float4 x2 = *(const float4*)&s_x[2][i];
        const float4 x3 = *(const float4*)&s_x[3][i];
        const float4 x4 = *(const float4*)&s_x[4][i];
        const float4 x5 = *(const float4*)&s_x[5][i];
        const float4 x6 = *(const float4*)&s_x[6][i];
        const float4 x7 = *(const float4*)&s_x[7][i];
        a0 = fmaf(w4.x, x0.x, a0); a0 = fmaf(w4.y, x0.y, a0); a0 = fmaf(w4.z, x0.z, a0); a0 = fmaf(w4.w, x0.w, a0);
        a1 = fmaf(w4.x, x1.x, a1); a1 = fmaf(w4.y, x1.y, a1); a1 = fmaf(w4.z, x1.z, a1); a1 = fmaf(w4.w, x1.w, a1);
        a2 = fmaf(w4.x, x2.x, a2); a2 = fmaf(w4.y, x2.y, a2); a2 = fmaf(w4.z, x2.z, a2); a2 = fmaf(w4.w, x2.w, a2);
        a3 = fmaf(w4.x, x3.x, a3); a3 = fmaf(w4.y, x3.y, a3); a3 = fmaf(w4.z, x3.z, a3); a3 = fmaf(w4.w, x3.w, a3);
        a4 = fmaf(w4.x, x4.x, a4); a4 = fmaf(w4.y, x4.y, a4); a4 = fmaf(w4.z, x4.z, a4); a4 = fmaf(w4.w, x4.w, a4);
        a5 = fmaf(w4.x, x5.x, a5); a5 = fmaf(w4.y, x5.y, a5); a5 = fmaf(w4.z, x5.z, a5); a5 = fmaf(w4.w, x5.w, a5);
        a6 = fmaf(w4.x, x6.x, a6); a6 = fmaf(w4.y, x6.y, a6); a6 = fmaf(w4.z, x6.z, a6); a6 = fmaf(w4.w, x6.w, a6);
        a7 = fmaf(w4.x, x7.x, a7); a7 = fmaf(w4.y, x7.y, a7); a7 = fmaf(w4.z, x7.z, a7); a7 = fmaf(w4.w, x7.w, a7);
    }
    const float bv = ibias[g * 256 + t];
    const float acc[8] = {a0, a1, a2, a3, a4, a5, a6, a7};
    #pragma unroll
    for (int b = 0; b < 8; b++)
        injb[((size_t)b * NCC + c) * 4096 + t] = acc[b] + bv;
}

// ---------------------------------------------------------------------------
// Kernel 1: per (b, cell) block; 512 threads = 8 waves; two-K-half MLPs,
// operand-swapped MFMAs, cvt_pk packs (rounds 14-16). Round-17: every
// phase's weight A-fragments are PREFETCHED during the preceding phase
// (before its barrier) — __syncthreads' vmcnt(0) drain lands them exactly
// at phase start, hiding the ~200cyc L2 latency the compiler can't hoist.
// ---------------------------------------------------------------------------
__global__ __launch_bounds__(512, 4)
void mg_cell_kernel(
    const float* __restrict__ hp,   const float* __restrict__ msgp,
    const float* __restrict__ Wp,   const float* __restrict__ decayp,
    const float* __restrict__ bglp, const float* __restrict__ nidp,
    const float* __restrict__ sb1,  const float* __restrict__ sgs1,
    const float* __restrict__ sgb1, const float* __restrict__ sb2,
    const float* __restrict__ sgs2, const float* __restrict__ sgb2,
    const float* __restrict__ mb1,  const float* __restrict__ mgs1,
    const float* __restrict__ mgb1, const float* __restrict__ mb2,
    const float* __restrict__ mgs2, const float* __restrict__ mgb2,
    const int*   __restrict__ c2g,  const ushort_t* __restrict__ wb,
    float* __restrict__ out_read, float* __restrict__ out_h,
    float* __restrict__ out_msg,  float* __restrict__ wsf)
{
    const int t  = threadIdx.x;
    const int bc = blockIdx.x;
    const int b  = bc >> 10, c = bc & 1023;
    const int gh = c >> 5, gwc = c & 31;
    const int lane = t & 63, w = t >> 6;
    const int cl = lane & 15, q = lane >> 4;
    const int g  = c2g[c];
    const size_t tile = (size_t)bc * 4096;

    __shared__ ushort_t sHid[8192];    // [64][128] bf16 16KB; overlays sW|sMsgT
    __shared__ ushort_t sIn[8192];     // [64][128] bf16: [received/h_new | h]
    __shared__ float s_scr[256];       // border; later h-part[2][64] @0, m-part[2][64] @128
    __shared__ float s_dec[64];
    __shared__ float s_wsum[8];
    __shared__ float s_dsum;

    ushort_t* sW    = sHid;            // [64][64], row stride 128B
    ushort_t* sMsgT = sHid + 4096;     // [64 d][64 m]

    // ================= P0: staging + border + decay =================
    {   // W -> sW bf16 (+ sum|W|): n = t>>3, 8 cols each
        const int n = t >> 3, m0 = (t & 7) * 8;
        const float* src = Wp + tile + n * 64 + m0;
        const float4 v0 = *(const float4*)(src);
        const float4 v1 = *(const float4*)(src + 4);
        float wsum = fabsf(v0.x) + fabsf(v0.y) + fabsf(v0.z) + fabsf(v0.w)
                   + fabsf(v1.x) + fabsf(v1.y) + fabsf(v1.z) + fabsf(v1.w);
        *(uint_t*)((char*)sW + SWZ(n * 128 + (m0 + 0) * 2, n)) = pk2(v0.x, v0.y);
        *(uint_t*)((char*)sW + SWZ(n * 128 + (m0 + 2) * 2, n)) = pk2(v0.z, v0.w);
        *(uint_t*)((char*)sW + SWZ(n * 128 + (m0 + 4) * 2, n)) = pk2(v1.x, v1.y);
        *(uint_t*)((char*)sW + SWZ(n * 128 + (m0 + 6) * 2, n)) = pk2(v1.z, v1.w);
        #pragma unroll
        for (int off = 32; off > 0; off >>= 1) wsum += __shfl_down(wsum, off);
        if (lane == 0) s_wsum[w] = wsum;
    }
    #pragma unroll
    for (int i = 0; i < 2; i++) {   // msg^T -> sMsgT bf16
        const int m = (t >> 4) + i * 32, d0 = (t & 15) * 4;
        const float4 v = *(const float4*)(msgp + tile + (size_t)m * 64 + d0);
        *(ushort_t*)((char*)sMsgT + SWZ((d0 + 0) * 128 + m * 2, d0 + 0)) = f2bf(v.x);
        *(ushort_t*)((char*)sMsgT + SWZ((d0 + 1) * 128 + m * 2, d0 + 1)) = f2bf(v.y);
        *(ushort_t*)((char*)sMsgT + SWZ((d0 + 2) * 128 + m * 2, d0 + 2)) = f2bf(v.z);
        *(ushort_t*)((char*)sMsgT + SWZ((d0 + 3) * 128 + m * 2, d0 + 3)) = f2bf(v.w);
    }
    #pragma unroll
    for (int i = 0; i < 2; i++) {   // h -> sIn[:,64:128] bf16
        const int n = (t >> 4) + i * 32, d0 = (t & 15) * 4;
        const float4 v = *(const float4*)(hp + tile + (size_t)n * 64 + d0);
        *(uint_t*)((char*)sIn + SWZ(n * 256 + (64 + d0) * 2, n))     = pk2(v.x, v.y);
        *(uint_t*)((char*)sIn + SWZ(n * 256 + (64 + d0 + 2) * 2, n)) = pk2(v.z, v.w);
    }
    if (t < 256) {   // gated border incoming: wave p = w (0..3)
        const int p = w, dd = lane;
        int ok, nc2, qq;
        if      (p == 0) { ok = (gh > 0);   nc2 = c - 32; qq = 1; }
        else if (p == 1) { ok = (gh < 31);  nc2 = c + 32; qq = 0; }
        else if (p == 2) { ok = (gwc > 0);  nc2 = c - 1;  qq = 3; }
        else             { ok = (gwc < 31); nc2 = c + 1;  qq = 2; }
        float v = 0.f;
        if (ok) v = msgp[((size_t)b * NCC + nc2) * 4096 + (8 + qq) * 64 + dd];
        s_scr[p * 64 + dd] = fast_sigmoid(bglp[(size_t)bc * 4 + p]) * v;
    }
    if (w == 4) {   // decay sigmoid table + logit sum
        const float dl = decayp[(size_t)bc * 64 + lane];
        s_dec[lane] = fast_sigmoid(dl);
        float v = dl;
        #pragma unroll
        for (int off = 32; off > 0; off >>= 1) v += __shfl_down(v, off);
        if (lane == 0) s_dsum = v;
    }
    __syncthreads();   // B1

    const f4v fzero = {0.f, 0.f, 0.f, 0.f};
    const int d0 = 16 * (w & 3) + q * 4;   // this thread's 4 output cols (epilogues)
    const int dA = 16 * (w & 3) + cl;      // A-operand weight-row index (reads)
    const int rh = w >> 2;                 // row-half
    const ushort_t* wb1 = wb + OFF_SW1;
    const ushort_t* wb2 = wb + OFF_SW2;
    const ushort_t* wm1 = wb + OFF_MW1;
    const ushort_t* wm2 = wb + OFF_MW2;

    s8v awA[4], awB[4];   // double-buffered weight A-fragment prefetch

    // ========== P1: received^ = mfma(msgT, W) + inject + border -> sIn[:,0:64] ==========
    {
        f4v wm[2] = {fzero, fzero};
        __builtin_amdgcn_s_setprio(1);
        #pragma unroll
        for (int ks = 0; ks < 2; ks++) {
            const int k0 = ks * 32 + q * 8;
            const s8v am = *(const s8v*)((const char*)sMsgT + SWZ(dA * 128 + k0 * 2, dA));
            #pragma unroll
            for (int nt = 0; nt < 2; nt++) {
                const int ar = (rh * 2 + nt) * 16 + cl;
                const s8v bw = *(const s8v*)((const char*)sW + SWZ(ar * 128 + k0 * 2, ar));
                wm[nt] = __builtin_amdgcn_mfma_f32_16x16x32_bf16(am, bw, wm[nt], 0, 0, 0);
            }
        }
        __builtin_amdgcn_s_setprio(0);
        // PREFETCH: state L1 p=0 A-frags (drained by B2)
        #pragma unroll
        for (int ks = 0; ks < 4; ks++)
            awA[ks] = *(const s8v*)(wb1 + (size_t)(16 * w + cl) * 128 + ks * 32 + q * 8);
        #pragma unroll
        for (int nt = 0; nt < 2; nt++) {
            const int n = (rh * 2 + nt) * 16 + cl;
            float v0 = wm[nt][0], v1 = wm[nt][1], v2 = wm[nt][2], v3 = wm[nt][3];
            if (n < 4) {
                const float4 inj = *(const float4*)(out_h + tile + (size_t)n * 64 + d0);
                v0 += inj.x; v1 += inj.y; v2 += inj.z; v3 += inj.w;
            } else if (n >= 8 && n < 12) {
                const float4 bin = *(const float4*)&s_scr[(n - 8) * 64 + d0];
                v0 += bin.x; v1 += bin.y; v2 += bin.z; v3 += bin.w;
            }
            uint2 pkd; pkd.x = pk2(v0, v1); pkd.y = pk2(v2, v3);
            *(uint2*)((char*)sIn + SWZ(n * 256 + d0 * 2, n)) = pkd;
        }
    }
    __syncthreads();   // B2

    // ===== STATE MLP (manually unrolled two K-half passes, prefetched frags) =====
    {
        f4v a2[2][2];
        a2[0][0] = fzero; a2[0][1] = fzero; a2[1][0] = fzero; a2[1][1] = fzero;

        // ---- L1 p=0 (uses awA) ----
        {
            f4v acc[4] = {fzero, fzero, fzero, fzero};
            // PREFETCH: state L2 p=0 frags
            #pragma unroll
            for (int ks = 0; ks < 4; ks++)
                awB[ks] = *(const s8v*)(wb2 + (size_t)dA * 256 + ks * 32 + q * 8);
            __builtin_amdgcn_s_setprio(1);
            #pragma unroll
            for (int ks = 0; ks < 4; ks++) {
                const int k0 = ks * 32 + q * 8;
                #pragma unroll
                for (int rt = 0; rt < 4; rt++) {
                    const int ar = rt * 16 + cl;
                    const s8v bi = *(const s8v*)((const char*)sIn + SWZ(ar * 256 + k0 * 2, ar));
                    acc[rt] = __builtin_amdgcn_mfma_f32_16x16x32_bf16(awA[ks], bi, acc[rt], 0, 0, 0);
                }
            }
            __builtin_amdgcn_s_setprio(0);
            const int hc0 = 16 * w + q * 4;
            const float4 b1 = *(const float4*)&sb1[hc0];
            const float4 g1 = *(const float4*)&sgs1[g * 256 + hc0];
            const float4 o1 = *(const float4*)&sgb1[g * 256 + hc0];
            #pragma unroll
            for (int rt = 0; rt < 4; rt++) {
                const int n = rt * 16 + cl;
                const float t0 = fast_tanh(fmaf(acc[rt][0] + b1.x, g1.x, o1.x));
                const float t1 = fast_tanh(fmaf(acc[rt][1] + b1.y, g1.y, o1.y));
                const float t2 = fast_tanh(fmaf(acc[rt][2] + b1.z, g1.z, o1.z));
                const float t3 = fast_tanh(fmaf(acc[rt][3] + b1.w, g1.w, o1.w));
                uint2 pkd; pkd.x = pk2(t0, t1); pkd.y = pk2(t2, t3);
                *(uint2*)((char*)sHid + SWZ(n * 256 + (16 * w + q * 4) * 2, n)) = pkd;
            }
        }
        __syncthreads();   // hid p=0 visible

        // ---- L2 p=0 (uses awB) ----
        {
            // PREFETCH: state L1 p=1 frags
            #pragma unroll
            for (int ks = 0; ks < 4; ks++)
                awA[ks] = *(const s8v*)(wb1 + (size_t)(128 + 16 * w + cl) * 128 + ks * 32 + q * 8);
            __builtin_amdgcn_s_setprio(1);
            #pragma unroll
            for (int ks = 0; ks < 4; ks++) {
                const int k0 = ks * 32 + q * 8;
                #pragma unroll
                for (int nt = 0; nt < 2; nt++) {
                    const int ar = (rh * 2 + nt) * 16 + cl;
                    const s8v bh = *(const s8v*)((const char*)sHid + SWZ(ar * 256 + k0 * 2, ar));
                    a2[nt][ks & 1] = __builtin_amdgcn_mfma_f32_16x16x32_bf16(awB[ks], bh, a2[nt][ks & 1], 0, 0, 0);
                }
            }
            __builtin_amdgcn_s_setprio(0);
        }
        __syncthreads();   // hid reads done before overwrite

        // ---- L1 p=1 (uses awA) ----
        {
            f4v acc[4] = {fzero, fzero, fzero, fzero};
            // PREFETCH: state L2 p=1 frags
            #pragma unroll
            for (int ks = 0; ks < 4; ks++)
                awB[ks] = *(const s8v*)(wb2 + (size_t)dA * 256 + 128 + ks * 32 + q * 8);
            __builtin_amdgcn_s_setprio(1);
            #pragma unroll
            for (int ks = 0; ks < 4; ks++) {
                const int k0 = ks * 32 + q * 8;
                #pragma unroll
                for (int rt = 0; rt < 4; rt++) {
                    const int ar = rt * 16 + cl;
                    const s8v bi = *(const s8v*)((const char*)sIn + SWZ(ar * 256 + k0 * 2, ar));
                    acc[rt] = __builtin_amdgcn_mfma_f32_16x16x32_bf16(awA[ks], bi, acc[rt], 0, 0, 0);
                }
            }
            __builtin_amdgcn_s_setprio(0);
            const int hc0 = 128 + 16 * w + q * 4;
            const float4 b1 = *(const float4*)&sb1[hc0];
            const float4 g1 = *(const float4*)&sgs1[g * 256 + hc0];
            const float4 o1 = *(const float4*)&sgb1[g * 256 + hc0];
            #pragma unroll
            for (int rt = 0; rt < 4; rt++) {
                const int n = rt * 16 + cl;
                const float t0 = fast_tanh(fmaf(acc[rt][0] + b1.x, g1.x, o1.x));
                const float t1 = fast_tanh(fmaf(acc[rt][1] + b1.y, g1.y, o1.y));
                const float t2 = fast_tanh(fmaf(acc[rt][2] + b1.z, g1.z, o1.z));
                const float t3 = fast_tanh(fmaf(acc[rt][3] + b1.w, g1.w, o1.w));
                uint2 pkd; pkd.x = pk2(t0, t1); pkd.y = pk2(t2, t3);
                *(uint2*)((char*)sHid + SWZ(n * 256 + (16 * w + q * 4) * 2, n)) = pkd;
            }
        }
        __syncthreads();   // hid p=1 visible

        // ---- L2 p=1 (uses awB) ----
        {
            // PREFETCH: msg L1 p=0 frags (2)
            #pragma unroll
            for (int ks = 0; ks < 2; ks++)
                awA[ks] = *(const s8v*)(wm1 + (size_t)(16 * w + cl) * 64 + ks * 32 + q * 8);
            __builtin_amdgcn_s_setprio(1);
            #pragma unroll
            for (int ks = 0; ks < 4; ks++) {
                const int k0 = ks * 32 + q * 8;
                #pragma unroll
                for (int nt = 0; nt < 2; nt++) {
                    const int ar = (rh * 2 + nt) * 16 + cl;
                    const s8v bh = *(const s8v*)((const char*)sHid + SWZ(ar * 256 + k0 * 2, ar));
                    a2[nt][ks & 1] = __builtin_amdgcn_mfma_f32_16x16x32_bf16(awB[ks], bh, a2[nt][ks & 1], 0, 0, 0);
                }
            }
            __builtin_amdgcn_s_setprio(0);
        }

        // epilogue: cand -> h_new (float4 global + packed sIn) + h_mean partials
        const float4 b2 = *(const float4*)&sb2[d0];
        const float4 g2 = *(const float4*)&sgs2[g * 64 + d0];
        const float4 o2 = *(const float4*)&sgb2[g * 64 + d0];
        float hs0 = 0.f, hs1 = 0.f, hs2 = 0.f, hs3 = 0.f;
        #pragma unroll
        for (int nt = 0; nt < 2; nt++) {
            const int n = (rh * 2 + nt) * 16 + cl;
            const float dec = s_dec[n];
            const uint2 hu = *(const uint2*)((const char*)sIn + SWZ(n * 256 + (64 + d0) * 2, n));
            const float hv0 = __builtin_bit_cast(float, (uint_t)(hu.x << 16));
            const float hv1 = __builtin_bit_cast(float, hu.x & 0xFFFF0000u);
            const float hv2 = __builtin_bit_cast(float, (uint_t)(hu.y << 16));
            const float hv3 = __builtin_bit_cast(float, hu.y & 0xFFFF0000u);
            const float c0 = fast_tanh(fmaf(a2[nt][0][0] + a2[nt][1][0] + b2.x, g2.x, o2.x));
            const float c1 = fast_tanh(fmaf(a2[nt][0][1] + a2[nt][1][1] + b2.y, g2.y, o2.y));
            const float c2 = fast_tanh(fmaf(a2[nt][0][2] + a2[nt][1][2] + b2.z, g2.z, o2.z));
            const float c3 = fast_tanh(fmaf(a2[nt][0][3] + a2[nt][1][3] + b2.w, g2.w, o2.w));
            float4 hn;
            hn.x = fmaf(dec, hv0 - c0, c0);
            hn.y = fmaf(dec, hv1 - c1, c1);
            hn.z = fmaf(dec, hv2 - c2, c2);
            hn.w = fmaf(dec, hv3 - c3, c3);
            *(float4*)(out_h + tile + (size_t)n * 64 + d0) = hn;
            uint2 pkd; pkd.x = pk2(hn.x, hn.y); pkd.y = pk2(hn.z, hn.w);
            *(uint2*)((char*)sIn + SWZ(n * 256 + d0 * 2, n)) = pkd;
            hs0 += hn.x; hs1 += hn.y; hs2 += hn.z; hs3 += hn.w;
        }
        #pragma unroll
        for (int m = 1; m < 16; m <<= 1) {
            hs0 += __shfl_xor(hs0, m); hs1 += __shfl_xor(hs1, m);
            hs2 += __shfl_xor(hs2, m); hs3 += __shfl_xor(hs3, m);
        }
        if (cl == 0) {
            float4 hp4 = {hs0, hs1, hs2, hs3};
            *(float4*)&s_scr[rh * 64 + d0] = hp4;   // h-part bands [0:128)
        }
    }
    __syncthreads();   // B4: h_new in sIn visible

    // ===== MSG MLP (manually unrolled, prefetched frags; awA[0..1] hold msg L1 p=0) =====
    {
        f4v a6[2][2];
        a6[0][0] = fzero; a6[0][1] = fzero; a6[1][0] = fzero; a6[1][1] = fzero;

        // ---- msg L1 p=0 (uses awA[0..1]) ----
        {
            f4v acc[4] = {fzero, fzero, fzero, fzero};
            // PREFETCH: msg L2 p=0 frags
            #pragma unroll
            for (int ks = 0; ks < 4; ks++)
                awB[ks] = *(const s8v*)(wm2 + (size_t)dA * 256 + ks * 32 + q * 8);
            __builtin_amdgcn_s_setprio(1);
            #pragma unroll
            for (int ks = 0; ks < 2; ks++) {
                const int k0 = ks * 32 + q * 8;
                #pragma unroll
                for (int rt = 0; rt < 4; rt++) {
                    const int ar = rt * 16 + cl;
                    const s8v bi = *(const s8v*)((const char*)sIn + SWZ(ar * 256 + k0 * 2, ar));
                    acc[rt] = __builtin_amdgcn_mfma_f32_16x16x32_bf16(awA[ks], bi, acc[rt], 0, 0, 0);
                }
            }
            __builtin_amdgcn_s_setprio(0);
            const int hc0 = 16 * w + q * 4;
            const float4 b1 = *(const float4*)&mb1[hc0];
            const float4 g1 = *(const float4*)&mgs1[g * 256 + hc0];
            const float4 o1 = *(const float4*)&mgb1[g * 256 + hc0];
            #pragma unroll
            for (int rt = 0; rt < 4; rt++) {
                const int n = rt * 16 + cl;
                const float t0 = fast_tanh(fmaf(acc[rt][0] + b1.x, g1.x, o1.x));
                const float t1 = fast_tanh(fmaf(acc[rt][1] + b1.y, g1.y, o1.y));
                const float t2 = fast_tanh(fmaf(acc[rt][2] + b1.z, g1.z, o1.z));
                const float t3 = fast_tanh(fmaf(acc[rt][3] + b1.w, g1.w, o1.w));
                uint2 pkd; pkd.x = pk2(t0, t1); pkd.y = pk2(t2, t3);
                *(uint2*)((char*)sHid + SWZ(n * 256 + (16 * w + q * 4) * 2, n)) = pkd;
            }
        }
        __syncthreads();   // mhid p=0 visible

        // ---- msg L2 p=0 (uses awB) ----
        {
            // PREFETCH: msg L1 p=1 frags (2)
            #pragma unroll
            for (int ks = 0; ks < 2; ks++)
                awA[ks] = *(const s8v*)(wm1 + (size_t)(128 + 16 * w + cl) * 64 + ks * 32 + q * 8);
            __builtin_amdgcn_s_setprio(1);
            #pragma unroll
            for (int ks = 0; ks < 4; ks++) {
                const int k0 = ks * 32 + q * 8;
                #pragma unroll
                for (int nt = 0; nt < 2; nt++) {
                    const int ar = (rh * 2 + nt) * 16 + cl;
                    const s8v bh = *(const s8v*)((const char*)sHid + SWZ(ar * 256 + k0 * 2, ar));
                    a6[nt][ks & 1] = __builtin_amdgcn_mfma_f32_16x16x32_bf16(awB[ks], bh, a6[nt][ks & 1], 0, 0, 0);
                }
            }
            __builtin_amdgcn_s_setprio(0);
        }
        __syncthreads();   // mhid reads done before overwrite

        // ---- msg L1 p=1 (uses awA[0..1]) ----
        {
            f4v acc[4] = {fzero, fzero, fzero, fzero};
            // PREFETCH: msg L2 p=1 frags
            #pragma unroll
            for (int ks = 0; ks < 4; ks++)
                awB[ks] = *(const s8v*)(wm2 + (size_t)dA * 256 + 128 + ks * 32 + q * 8);
            __builtin_amdgcn_s_setprio(1);
            #pragma unroll
            for (int ks = 0; ks < 2; ks++) {
                const int k0 = ks * 32 + q * 8;
                #pragma unroll
                for (int rt = 0; rt < 4; rt++) {
                    const int ar = rt * 16 + cl;
                    const s8v bi = *(const s8v*)((const char*)sIn + SWZ(ar * 256 + k0 * 2, ar));
                    acc[rt] = __builtin_amdgcn_mfma_f32_16x16x32_bf16(awA[ks], bi, acc[rt], 0, 0, 0);
                }
            }
            __builtin_amdgcn_s_setprio(0);
            const int hc0 = 128 + 16 * w + q * 4;
            const float4 b1 = *(const float4*)&mb1[hc0];
            const float4 g1 = *(const float4*)&mgs1[g * 256 + hc0];
            const float4 o1 = *(const float4*)&mgb1[g * 256 + hc0];
            #pragma unroll
            for (int rt = 0; rt < 4; rt++) {
                const int n = rt * 16 + cl;
                const float t0 = fast_tanh(fmaf(acc[rt][0] + b1.x, g1.x, o1.x));
                const float t1 = fast_tanh(fmaf(acc[rt][1] + b1.y, g1.y, o1.y));
                const float t2 = fast_tanh(fmaf(acc[rt][2] + b1.z, g1.z, o1.z));
                const float t3 = fast_tanh(fmaf(acc[rt][3] + b1.w, g1.w, o1.w));
                uint2 pkd; pkd.x = pk2(t0, t1); pkd.y = pk2(t2, t3);
                *(uint2*)((char*)sHid + SWZ(n * 256 + (16 * w + q * 4) * 2, n)) = pkd;
            }
        }
        __syncthreads();   // mhid p=1 visible

        // ---- msg L2 p=1 (uses awB) ----
        {
            __builtin_amdgcn_s_setprio(1);
            #pragma unroll
            for (int ks = 0; ks < 4; ks++) {
                const int k0 = ks * 32 + q * 8;
                #pragma unroll
                for (int nt = 0; nt < 2; nt++) {
                    const int ar = (rh * 2 + nt) * 16 + cl;
                    const s8v bh = *(const s8v*)((const char*)sHid + SWZ(ar * 256 + k0 * 2, ar));
                    a6[nt][ks & 1] = __builtin_amdgcn_mfma_f32_16x16x32_bf16(awB[ks], bh, a6[nt][ks & 1], 0, 0, 0);
                }
            }
            __builtin_amdgcn_s_setprio(0);
        }

        // epilogue: msg_new (+nid, float4 stores), mmean partials, readout
        const float4 b2 = *(const float4*)&mb2[d0];
        const float4 g2 = *(const float4*)&mgs2[g * 64 + d0];
        const float4 o2 = *(const float4*)&mgb2[g * 64 + d0];
        float ms0 = 0.f, ms1 = 0.f, ms2 = 0.f, ms3 = 0.f;
        float ro0 = 0.f, ro1 = 0.f, ro2 = 0.f, ro3 = 0.f;
        #pragma unroll
        for (int nt = 0; nt < 2; nt++) {
            const int n = (rh * 2 + nt) * 16 + cl;
            const float4 nv = *(const float4*)(nidp + (size_t)c * 4096 + (size_t)n * 64 + d0);
            float4 mv;
            mv.x = fast_tanh(fmaf(a6[nt][0][0] + a6[nt][1][0] + b2.x, g2.x, o2.x)) + nv.x;
            mv.y = fast_tanh(fmaf(a6[nt][0][1] + a6[nt][1][1] + b2.y, g2.y, o2.y)) + nv.y;
            mv.z = fast_tanh(fmaf(a6[nt][0][2] + a6[nt][1][2] + b2.z, g2.z, o2.z)) + nv.z;
            mv.w = fast_tanh(fmaf(a6[nt][0][3] + a6[nt][1][3] + b2.w, g2.w, o2.w)) + nv.w;
            *(float4*)(out_msg + tile + (size_t)n * 64 + d0) = mv;
            ms0 += mv.x; ms1 += mv.y; ms2 += mv.z; ms3 += mv.w;
            if (nt == 0 && rh == 0 && n >= 4 && n < 8) {
                ro0 = mv.x; ro1 = mv.y; ro2 = mv.z; ro3 = mv.w;
            }
        }
        #pragma unroll
        for (int m = 1; m < 16; m <<= 1) {
            ms0 += __shfl_xor(ms0, m); ms1 += __shfl_xor(ms1, m);
            ms2 += __shfl_xor(ms2, m); ms3 += __shfl_xor(ms3, m);
        }
        if (cl == 0) {
            float4 mp4 = {ms0, ms1, ms2, ms3};
            *(float4*)&s_scr[128 + rh * 64 + d0] = mp4;   // m-part bands [128:256)
        }
        // readout: sum over n=4..7 (lanes cl=4..7, rh==0)
        ro0 += __shfl_xor(ro0, 1); ro1 += __shfl_xor(ro1, 1);
        ro2 += __shfl_xor(ro2, 1); ro3 += __shfl_xor(ro3, 1);
        ro0 += __shfl_xor(ro0, 2); ro1 += __shfl_xor(ro1, 2);
        ro2 += __shfl_xor(ro2, 2); ro3 += __shfl_xor(ro3, 2);
        if (rh == 0 && cl == 4) {
            float4 o4 = {ro0 * 0.5f, ro1 * 0.5f, ro2 * 0.5f, ro3 * 0.5f};
            *(float4*)(out_read + ((size_t)b * NCC + c) * 64 + d0) = o4;
        }
    }
    __syncthreads();   // B6

    // ================= P7: feats record (130 values) =================
    if (t < 132) {
        float v = 0.f;
        if (t < 64)        v = (s_scr[t] + s_scr[64 + t]) * (1.f / 64.f);
        else if (t < 128)  v = (s_scr[64 + t] + s_scr[128 + t]) * (1.f / 64.f);
        else if (t == 128) v = (s_wsum[0] + s_wsum[1] + s_wsum[2] + s_wsum[3]
                              + s_wsum[4] + s_wsum[5] + s_wsum[6] + s_wsum[7]) * (1.f / 4096.f);
        else if (t == 129) v = s_dsum * (1.f / 64.f);
        wsf[(size_t)bc * 132 + t] = v;
    }
}

// ---------------------------------------------------------------------------
// Kernel 2: per-cell modulation MLP (distinct weights per cell)
// ---------------------------------------------------------------------------
__global__ __launch_bounds__(256, 2)
void mg_mod_kernel(
    const float* __restrict__ wsf,   const float* __restrict__ modw1,
    const float* __restrict__ modb1, const float* __restrict__ modw2,
    const float* __restrict__ modb2, const float* __restrict__ ctxp,
    const float* __restrict__ bglp,  float* __restrict__ out_ctx,
    float* __restrict__ out_bg)
{
    const int c = blockIdx.x;
    const int t = threadIdx.x;
    __shared__ float s_f[8][MODIN];
    __shared__ float s_h2[8][HMODL];

    for (int k = t; k < 8 * MODIN; k += 256) {
        const int b = k / MODIN, f = k - b * MODIN;
        float v;
        if (f < 130)      v = wsf[((size_t)b * NCC + c) * 132 + f];
        else if (f < 194) v = ctxp[((size_t)b * NCC + c) * 64 + (f - 130)];
        else              v = bglp[((size_t)b * NCC + c) * 4 + (f - 194)];
        s_f[b][f] = v;
    }
    __syncthreads();

    {
        const int hh = t & 127, bh = (t >> 7) * 4;
        float a0 = 0.f, a1 = 0.f, a2 = 0.f, a3 = 0.f;
        const float* wp = modw1 + (size_t)c * MODIN * HMODL + hh;
        for (int f = 0; f < MODIN; f++) {
            const float wv = wp[(size_t)f * HMODL];
            a0 = fmaf(s_f[bh + 0][f], wv, a0);
            a1 = fmaf(s_f[bh + 1][f], wv, a1);
            a2 = fmaf(s_f[bh + 2][f], wv, a2);
            a3 = fmaf(s_f[bh + 3][f], wv, a3);
        }
        const float bv = modb1[(size_t)c * HMODL + hh];
        s_h2[bh + 0][hh] = fast_tanh(a0 + bv);
        s_h2[bh + 1][hh] = fast_tanh(a1 + bv);
        s_h2[bh + 2][hh] = fast_tanh(a2 + bv);
        s_h2[bh + 3][hh] = fast_tanh(a3 + bv);
    }
    __syncthreads();

    for (int idx = t; idx < 8 * MODOUT; idx += 256) {
        const int b = idx / MODOUT, o = idx - b * MODOUT;
        float acc = modb2[(size_t)c * MODOUT + o];
        const float* wp = modw2 + (size_t)c * HMODL * MODOUT + o;
        const float* hrow = s_h2[b];
        for (int hh = 0; hh < HMODL; hh++)
            acc = fmaf(hrow[hh], wp[(size_t)hh * MODOUT], acc);
        if (o < 64)
            out_ctx[((size_t)b * NCC + c) * 64 + o] =
                ctxp[((size_t)b * NCC + c) * 64 + o] + acc;
        else
            out_bg[((size_t)b * NCC + c) * 4 + (o - 64)] =
                bglp[((size_t)b * NCC + c) * 4 + (o - 64)] + acc;
    }
}

extern "C" void kernel_launch(void* const* d_in, const int* in_sizes, int n_in,
                              void* d_out, int out_size, void* d_ws, size_t ws_size,
                              hipStream_t stream) {
    const float* xp     = (const float*)d_in[0];
    const float* hp     = (const float*)d_in[1];
    const float* msgp   = (const float*)d_in[2];
    const float* Wp     = (const float*)d_in[3];
    const float* decayp = (const float*)d_in[4];
    const float* ctxp   = (const float*)d_in[5];
    const float* bglp   = (const float*)d_in[6];
    const float* nidp   = (const float*)d_in[7];
    const float* sw1    = (const float*)d_in[8];
    const float* sb1    = (const float*)d_in[9];
    const float* sgs1   = (const float*)d_in[10];
    const float* sgb1   = (const float*)d_in[11];
    const float* sw2    = (const float*)d_in[12];
    const float* sb2    = (const float*)d_in[13];
    const float* sgs2   = (const float*)d_in[14];
    const float* sgb2   = (const float*)d_in[15];
    const float* mw1    = (const float*)d_in[16];
    const float* mb1    = (const float*)d_in[17];
    const float* mgs1   = (const float*)d_in[18];
    const float* mgb1   = (const float*)d_in[19];
    const float* mw2    = (const float*)d_in[20];
    const float* mb2    = (const float*)d_in[21];
    const float* mgs2   = (const float*)d_in[22];
    const float* mgb2   = (const float*)d_in[23];
    const float* iw     = (const float*)d_in[24];
    const float* ibias  = (const float*)d_in[25];
    const float* modw1  = (const float*)d_in[26];
    const float* modb1  = (const float*)d_in[27];
    const float* modw2  = (const float*)d_in[28];
    const float* modb2  = (const float*)d_in[29];
    const int*   c2g    = (const int*)d_in[30];

    float* out      = (float*)d_out;
    float* out_read = out;                 // 524288
    float* out_h    = out_read + 524288;   // 33554432
    float* out_msg  = out_h + 33554432;    // 33554432
    float* out_ctx  = out_msg + 33554432;  // 524288
    float* out_bg   = out_ctx + 524288;    // 32768

    ushort_t* wb  = (ushort_t*)d_ws;                          // 160KB bf16 weights
    float*    wsf = (float*)((char*)d_ws + FEATS_BYTE_OFF);   // 8192 x 132 f32

    mg_cvtw<<<320, 256, 0, stream>>>(sw1, sw2, mw1, mw2, wb);

    // inject -> head of each out_h tile (read by P1, overwritten by state epilogue)
    mg_inject<<<1024, 256, 0, stream>>>(xp, iw, ibias, c2g, out_h);

    mg_cell_kernel<<<8192, 512, 0, stream>>>(
        hp, msgp, Wp, decayp, bglp, nidp,
        sb1, sgs1, sgb1, sb2, sgs2, sgb2,
        mb1, mgs1, mgb1, mb2, mgs2, mgb2,
        c2g, wb, out_read, out_h, out_msg, wsf);

    mg_mod_kernel<<<1024, 256, 0, stream>>>(
        wsf, modw1, modb1, modw2, modb2, ctxp, bglp, out_ctx, out_bg);
}

// Round 18
// 395.578 us; speedup vs baseline: 1.7505x; 1.0443x over previous
//
#include <hip/hip_runtime.h>

#define NCC 1024
#define MODIN 198
#define MODOUT 68
#define HMODL 128

typedef __attribute__((ext_vector_type(8))) short s8v;   // 8 bf16 = 4 VGPR
typedef __attribute__((ext_vector_type(4))) float f4v;   // MFMA acc
typedef unsigned short ushort_t;
typedef unsigned int uint_t;

#define OFF_SW1 0
#define OFF_SW2 32768
#define OFF_MW1 49152
#define OFF_MW2 65536
#define FEATS_BYTE_OFF 262144   // feats: 8192 cells x 132 f32

__device__ __forceinline__ float fast_tanh(float x) {
    const float e = __builtin_amdgcn_exp2f(x * 2.885390081777927f);   // e^{2x}
    const float r = __builtin_amdgcn_rcpf(e + 1.f);
    return fmaf(-2.f, r, 1.f);
}
__device__ __forceinline__ float fast_sigmoid(float x) {
    const float e = __builtin_amdgcn_exp2f(x * -1.4426950408889634f);
    return __builtin_amdgcn_rcpf(e + 1.f);
}
__device__ __forceinline__ ushort_t f2bf(float x) {   // RNE f32->bf16 (scalar path)
    uint_t u = __builtin_bit_cast(uint_t, x);
    u += 0x7FFFu + ((u >> 16) & 1u);
    return (ushort_t)(u >> 16);
}
__device__ __forceinline__ uint_t pk2(float a, float b) {   // HW pack: 1 instr, RNE
    uint_t r;
    asm("v_cvt_pk_bf16_f32 %0, %1, %2" : "=v"(r) : "v"(a), "v"(b));
    return r;
}
// XOR swizzle on LDS byte offsets (16B granule)
#define SWZ(byteoff, row) ((byteoff) ^ (((row) & 7) << 4))

// ---------------------------------------------------------------------------
// Kernel 0: weights -> bf16 once per launch
// ---------------------------------------------------------------------------
__global__ __launch_bounds__(256)
void mg_cvtw(const float* __restrict__ sw1, const float* __restrict__ sw2,
             const float* __restrict__ mw1, const float* __restrict__ mw2,
             ushort_t* __restrict__ o) {
    const int i = blockIdx.x * 256 + threadIdx.x;   // grid 320 -> 81920 exact
    float v;
    if (i < 32768)      v = sw1[i];
    else if (i < 49152) v = sw2[i - 32768];
    else if (i < 65536) v = mw1[i - 49152];
    else                v = mw2[i - 65536];
    o[i] = f2bf(v);
}

// ---------------------------------------------------------------------------
// Kernel 0b: inject[b,c,o] -> head of each out_h tile (read by P1)
// ---------------------------------------------------------------------------
__global__ __launch_bounds__(256, 4)
void mg_inject(const float* __restrict__ xp, const float* __restrict__ iw,
               const float* __restrict__ ibias, const int* __restrict__ c2g,
               float* __restrict__ injb) {
    const int c = blockIdx.x, t = threadIdx.x;
    const int g = c2g[c];
    __shared__ float s_x[8][64];
    for (int idx = t; idx < 512; idx += 256)
        s_x[idx >> 6][idx & 63] = xp[(size_t)(idx >> 6) * (NCC * 64) + c * 64 + (idx & 63)];
    __syncthreads();
    const float* wrow = iw + (size_t)g * 16384 + t * 64;
    float a0 = 0.f, a1 = 0.f, a2 = 0.f, a3 = 0.f, a4 = 0.f, a5 = 0.f, a6 = 0.f, a7 = 0.f;
    #pragma unroll
    for (int i = 0; i < 64; i += 4) {
        const float4 w4 = *(const float4*)(wrow + i);
        const float4 x0 = *(const float4*)&s_x[0][i];
        const float4 x1 = *(const float4*)&s_x[1][i];
        const float4 x2 = *(const float4*)&s_x[2][i];
        const float4 x3 = *(const float4*)&s_x[3][i];
        const float4 x4 = *(const float4*)&s_x[4][i];
        const float4 x5 = *(const float4*)&s_x[5][i];
        const float4 x6 = *(const float4*)&s_x[6][i];
        const float4 x7 = *(const float4*)&s_x[7][i];
        a0 = fmaf(w4.x, x0.x, a0); a0 = fmaf(w4.y, x0.y, a0); a0 = fmaf(w4.z, x0.z, a0); a0 = fmaf(w4.w, x0.w, a0);
        a1 = fmaf(w4.x, x1.x, a1); a1 = fmaf(w4.y, x1.y, a1); a1 = fmaf(w4.z, x1.z, a1); a1 = fmaf(w4.w, x1.w, a1);
        a2 = fmaf(w4.x, x2.x, a2); a2 = fmaf(w4.y, x2.y, a2); a2 = fmaf(w4.z, x2.z, a2); a2 = fmaf(w4.w, x2.w, a2);
        a3 = fmaf(w4.x, x3.x, a3); a3 = fmaf(w4.y, x3.y, a3); a3 = fmaf(w4.z, x3.z, a3); a3 = fmaf(w4.w, x3.w, a3);
        a4 = fmaf(w4.x, x4.x, a4); a4 = fmaf(w4.y, x4.y, a4); a4 = fmaf(w4.z, x4.z, a4); a4 = fmaf(w4.w, x4.w, a4);
        a5 = fmaf(w4.x, x5.x, a5); a5 = fmaf(w4.y, x5.y, a5); a5 = fmaf(w4.z, x5.z, a5); a5 = fmaf(w4.w, x5.w, a5);
        a6 = fmaf(w4.x, x6.x, a6); a6 = fmaf(w4.y, x6.y, a6); a6 = fmaf(w4.z, x6.z, a6); a6 = fmaf(w4.w, x6.w, a6);
        a7 = fmaf(w4.x, x7.x, a7); a7 = fmaf(w4.y, x7.y, a7); a7 = fmaf(w4.z, x7.z, a7); a7 = fmaf(w4.w, x7.w, a7);
    }
    const float bv = ibias[g * 256 + t];
    const float acc[8] = {a0, a1, a2, a3, a4, a5, a6, a7};
    #pragma unroll
    for (int b = 0; b < 8; b++)
        injb[((size_t)b * NCC + c) * 4096 + t] = acc[b] + bv;
}

// ---------------------------------------------------------------------------
// Kernel 1: per (b, cell) block; 512 threads = 8 waves; FULL sHid [64][256]
// (6 barriers), operand-swapped MFMAs, cvt_pk, cross-barrier prefetch.
// Round-18: L1 phases give each wave 32 output cols (2 weight frags/ks) so
// each data B-frag LDS read feeds TWO MFMAs (ds_read:MFMA = 1:2).
// ---------------------------------------------------------------------------
__global__ __launch_bounds__(512, 4)
void mg_cell_kernel(
    const float* __restrict__ hp,   const float* __restrict__ msgp,
    const float* __restrict__ Wp,   const float* __restrict__ decayp,
    const float* __restrict__ bglp, const float* __restrict__ nidp,
    const float* __restrict__ sb1,  const float* __restrict__ sgs1,
    const float* __restrict__ sgb1, const float* __restrict__ sb2,
    const float* __restrict__ sgs2, const float* __restrict__ sgb2,
    const float* __restrict__ mb1,  const float* __restrict__ mgs1,
    const float* __restrict__ mgb1, const float* __restrict__ mb2,
    const float* __restrict__ mgs2, const float* __restrict__ mgb2,
    const int*   __restrict__ c2g,  const ushort_t* __restrict__ wb,
    float* __restrict__ out_read, float* __restrict__ out_h,
    float* __restrict__ out_msg,  float* __restrict__ wsf)
{
    const int t  = threadIdx.x;
    const int bc = blockIdx.x;
    const int b  = bc >> 10, c = bc & 1023;
    const int gh = c >> 5, gwc = c & 31;
    const int lane = t & 63, w = t >> 6;
    const int cl = lane & 15, q = lane >> 4;
    const int g  = c2g[c];
    const size_t tile = (size_t)bc * 4096;

    __shared__ ushort_t sHid[16384];   // [64][256] bf16 32KB; first 16KB overlays sW|sMsgT
    __shared__ ushort_t sIn[8192];     // [64][128] bf16: [received/h_new | h]
    __shared__ float s_scr[256];       // border; later h-part[2][64] @0, m-part[2][64] @128
    __shared__ float s_dec[64];
    __shared__ float s_wsum[8];
    __shared__ float s_dsum;

    ushort_t* sW    = sHid;            // [64][64], row stride 128B
    ushort_t* sMsgT = sHid + 4096;     // [64 d][64 m]

    // ================= P0: staging + border + decay =================
    {   // W -> sW bf16 (+ sum|W|): n = t>>3, 8 cols each
        const int n = t >> 3, m0 = (t & 7) * 8;
        const float* src = Wp + tile + n * 64 + m0;
        const float4 v0 = *(const float4*)(src);
        const float4 v1 = *(const float4*)(src + 4);
        float wsum = fabsf(v0.x) + fabsf(v0.y) + fabsf(v0.z) + fabsf(v0.w)
                   + fabsf(v1.x) + fabsf(v1.y) + fabsf(v1.z) + fabsf(v1.w);
        *(uint_t*)((char*)sW + SWZ(n * 128 + (m0 + 0) * 2, n)) = pk2(v0.x, v0.y);
        *(uint_t*)((char*)sW + SWZ(n * 128 + (m0 + 2) * 2, n)) = pk2(v0.z, v0.w);
        *(uint_t*)((char*)sW + SWZ(n * 128 + (m0 + 4) * 2, n)) = pk2(v1.x, v1.y);
        *(uint_t*)((char*)sW + SWZ(n * 128 + (m0 + 6) * 2, n)) = pk2(v1.z, v1.w);
        #pragma unroll
        for (int off = 32; off > 0; off >>= 1) wsum += __shfl_down(wsum, off);
        if (lane == 0) s_wsum[w] = wsum;
    }
    #pragma unroll
    for (int i = 0; i < 2; i++) {   // msg^T -> sMsgT bf16
        const int m = (t >> 4) + i * 32, d0 = (t & 15) * 4;
        const float4 v = *(const float4*)(msgp + tile + (size_t)m * 64 + d0);
        *(ushort_t*)((char*)sMsgT + SWZ((d0 + 0) * 128 + m * 2, d0 + 0)) = f2bf(v.x);
        *(ushort_t*)((char*)sMsgT + SWZ((d0 + 1) * 128 + m * 2, d0 + 1)) = f2bf(v.y);
        *(ushort_t*)((char*)sMsgT + SWZ((d0 + 2) * 128 + m * 2, d0 + 2)) = f2bf(v.z);
        *(ushort_t*)((char*)sMsgT + SWZ((d0 + 3) * 128 + m * 2, d0 + 3)) = f2bf(v.w);
    }
    #pragma unroll
    for (int i = 0; i < 2; i++) {   // h -> sIn[:,64:128] bf16
        const int n = (t >> 4) + i * 32, d0 = (t & 15) * 4;
        const float4 v = *(const float4*)(hp + tile + (size_t)n * 64 + d0);
        *(uint_t*)((char*)sIn + SWZ(n * 256 + (64 + d0) * 2, n))     = pk2(v.x, v.y);
        *(uint_t*)((char*)sIn + SWZ(n * 256 + (64 + d0 + 2) * 2, n)) = pk2(v.z, v.w);
    }
    if (t < 256) {   // gated border incoming: wave p = w (0..3)
        const int p = w, dd = lane;
        int ok, nc2, qq;
        if      (p == 0) { ok = (gh > 0);   nc2 = c - 32; qq = 1; }
        else if (p == 1) { ok = (gh < 31);  nc2 = c + 32; qq = 0; }
        else if (p == 2) { ok = (gwc > 0);  nc2 = c - 1;  qq = 3; }
        else             { ok = (gwc < 31); nc2 = c + 1;  qq = 2; }
        float v = 0.f;
        if (ok) v = msgp[((size_t)b * NCC + nc2) * 4096 + (8 + qq) * 64 + dd];
        s_scr[p * 64 + dd] = fast_sigmoid(bglp[(size_t)bc * 4 + p]) * v;
    }
    if (w == 4) {   // decay sigmoid table + logit sum
        const float dl = decayp[(size_t)bc * 64 + lane];
        s_dec[lane] = fast_sigmoid(dl);
        float v = dl;
        #pragma unroll
        for (int off = 32; off > 0; off >>= 1) v += __shfl_down(v, off);
        if (lane == 0) s_dsum = v;
    }
    __syncthreads();   // B1

    const f4v fzero = {0.f, 0.f, 0.f, 0.f};
    const int d0 = 16 * (w & 3) + q * 4;   // 4 output cols (L2 epilogues)
    const int dA = 16 * (w & 3) + cl;      // L2 weight-row index
    const int rh = w >> 2;                 // row-half (L2 phases, P1)
    const ushort_t* wb1 = wb + OFF_SW1;
    const ushort_t* wb2 = wb + OFF_SW2;
    const ushort_t* wm1 = wb + OFF_MW1;
    const ushort_t* wm2 = wb + OFF_MW2;

    s8v awP0, awP1;   // cross-barrier first-fragment prefetch pair

    // ========== P1: received^ = mfma(msgT, W) + inject + border -> sIn[:,0:64] ==========
    {
        f4v wm[2] = {fzero, fzero};
        __builtin_amdgcn_s_setprio(1);
        #pragma unroll
        for (int ks = 0; ks < 2; ks++) {
            const int k0 = ks * 32 + q * 8;
            const s8v am = *(const s8v*)((const char*)sMsgT + SWZ(dA * 128 + k0 * 2, dA));
            #pragma unroll
            for (int nt = 0; nt < 2; nt++) {
                const int ar = (rh * 2 + nt) * 16 + cl;
                const s8v bw = *(const s8v*)((const char*)sW + SWZ(ar * 128 + k0 * 2, ar));
                wm[nt] = __builtin_amdgcn_mfma_f32_16x16x32_bf16(am, bw, wm[nt], 0, 0, 0);
            }
        }
        __builtin_amdgcn_s_setprio(0);
        // PREFETCH: state L1 ks=0 frags (ct=0,1); drained by B2
        awP0 = *(const s8v*)(wb1 + (size_t)(32 * w + cl) * 128 + q * 8);
        awP1 = *(const s8v*)(wb1 + (size_t)(32 * w + 16 + cl) * 128 + q * 8);
        #pragma unroll
        for (int nt = 0; nt < 2; nt++) {
            const int n = (rh * 2 + nt) * 16 + cl;
            float v0 = wm[nt][0], v1 = wm[nt][1], v2 = wm[nt][2], v3 = wm[nt][3];
            if (n < 4) {
                const float4 inj = *(const float4*)(out_h + tile + (size_t)n * 64 + d0);
                v0 += inj.x; v1 += inj.y; v2 += inj.z; v3 += inj.w;
            } else if (n >= 8 && n < 12) {
                const float4 bin = *(const float4*)&s_scr[(n - 8) * 64 + d0];
                v0 += bin.x; v1 += bin.y; v2 += bin.z; v3 += bin.w;
            }
            uint2 pkd; pkd.x = pk2(v0, v1); pkd.y = pk2(v2, v3);
            *(uint2*)((char*)sIn + SWZ(n * 256 + d0 * 2, n)) = pkd;
        }
    }
    __syncthreads();   // B2 (sW/sMsgT reads done -> sHid full overlay safe)

    // ===== state L1: K=128, wave w owns cols [32w, 32w+32); 16 reads / 32 MFMA =====
    {
        f4v acc[2][4];
        #pragma unroll
        for (int i = 0; i < 2; i++)
            #pragma unroll
            for (int j = 0; j < 4; j++) acc[i][j] = fzero;
        __builtin_amdgcn_s_setprio(1);
        #pragma unroll
        for (int ks = 0; ks < 4; ks++) {
            const int k0 = ks * 32 + q * 8;
            const s8v aw0 = (ks == 0) ? awP0
                : *(const s8v*)(wb1 + (size_t)(32 * w + cl) * 128 + k0);
            const s8v aw1 = (ks == 0) ? awP1
                : *(const s8v*)(wb1 + (size_t)(32 * w + 16 + cl) * 128 + k0);
            #pragma unroll
            for (int rt = 0; rt < 4; rt++) {
                const int ar = rt * 16 + cl;
                const s8v bi = *(const s8v*)((const char*)sIn + SWZ(ar * 256 + k0 * 2, ar));
                acc[0][rt] = __builtin_amdgcn_mfma_f32_16x16x32_bf16(aw0, bi, acc[0][rt], 0, 0, 0);
                acc[1][rt] = __builtin_amdgcn_mfma_f32_16x16x32_bf16(aw1, bi, acc[1][rt], 0, 0, 0);
            }
        }
        __builtin_amdgcn_s_setprio(0);
        // PREFETCH: state L2 ks=0,1 frags
        awP0 = *(const s8v*)(wb2 + (size_t)dA * 256 + q * 8);
        awP1 = *(const s8v*)(wb2 + (size_t)dA * 256 + 32 + q * 8);
        #pragma unroll
        for (int ct = 0; ct < 2; ct++) {
            const int hc0 = 32 * w + ct * 16 + q * 4;
            const float4 b1 = *(const float4*)&sb1[hc0];
            const float4 g1 = *(const float4*)&sgs1[g * 256 + hc0];
            const float4 o1 = *(const float4*)&sgb1[g * 256 + hc0];
            #pragma unroll
            for (int rt = 0; rt < 4; rt++) {
                const int n = rt * 16 + cl;
                const float t0 = fast_tanh(fmaf(acc[ct][rt][0] + b1.x, g1.x, o1.x));
                const float t1 = fast_tanh(fmaf(acc[ct][rt][1] + b1.y, g1.y, o1.y));
                const float t2 = fast_tanh(fmaf(acc[ct][rt][2] + b1.z, g1.z, o1.z));
                const float t3 = fast_tanh(fmaf(acc[ct][rt][3] + b1.w, g1.w, o1.w));
                uint2 pkd; pkd.x = pk2(t0, t1); pkd.y = pk2(t2, t3);
                *(uint2*)((char*)sHid + SWZ(n * 512 + hc0 * 2, n)) = pkd;
            }
        }
    }
    __syncthreads();   // B3: full hid visible

    // ===== state L2: K=256 single pass + h_new epilogue =====
    {
        f4v a2[2][2];
        a2[0][0] = fzero; a2[0][1] = fzero; a2[1][0] = fzero; a2[1][1] = fzero;
        __builtin_amdgcn_s_setprio(1);
        #pragma unroll
        for (int ks = 0; ks < 8; ks++) {
            const int k0 = ks * 32 + q * 8;
            const s8v aw = (ks == 0) ? awP0 : (ks == 1) ? awP1
                : *(const s8v*)(wb2 + (size_t)dA * 256 + k0);
            #pragma unroll
            for (int nt = 0; nt < 2; nt++) {
                const int ar = (rh * 2 + nt) * 16 + cl;
                const s8v bh = *(const s8v*)((const char*)sHid + SWZ(ar * 512 + k0 * 2, ar));
                a2[nt][ks & 1] = __builtin_amdgcn_mfma_f32_16x16x32_bf16(aw, bh, a2[nt][ks & 1], 0, 0, 0);
            }
        }
        __builtin_amdgcn_s_setprio(0);
        // PREFETCH: msg L1 ks=0 frags (ct=0,1)
        awP0 = *(const s8v*)(wm1 + (size_t)(32 * w + cl) * 64 + q * 8);
        awP1 = *(const s8v*)(wm1 + (size_t)(32 * w + 16 + cl) * 64 + q * 8);
        // epilogue: cand -> h_new (float4 global + packed sIn) + h_mean partials
        const float4 b2 = *(const float4*)&sb2[d0];
        const float4 g2 = *(const float4*)&sgs2[g * 64 + d0];
        const float4 o2 = *(const float4*)&sgb2[g * 64 + d0];
        float hs0 = 0.f, hs1 = 0.f, hs2 = 0.f, hs3 = 0.f;
        #pragma unroll
        for (int nt = 0; nt < 2; nt++) {
            const int n = (rh * 2 + nt) * 16 + cl;
            const float dec = s_dec[n];
            const uint2 hu = *(const uint2*)((const char*)sIn + SWZ(n * 256 + (64 + d0) * 2, n));
            const float hv0 = __builtin_bit_cast(float, (uint_t)(hu.x << 16));
            const float hv1 = __builtin_bit_cast(float, hu.x & 0xFFFF0000u);
            const float hv2 = __builtin_bit_cast(float, (uint_t)(hu.y << 16));
            const float hv3 = __builtin_bit_cast(float, hu.y & 0xFFFF0000u);
            const float c0 = fast_tanh(fmaf(a2[nt][0][0] + a2[nt][1][0] + b2.x, g2.x, o2.x));
            const float c1 = fast_tanh(fmaf(a2[nt][0][1] + a2[nt][1][1] + b2.y, g2.y, o2.y));
            const float c2 = fast_tanh(fmaf(a2[nt][0][2] + a2[nt][1][2] + b2.z, g2.z, o2.z));
            const float c3 = fast_tanh(fmaf(a2[nt][0][3] + a2[nt][1][3] + b2.w, g2.w, o2.w));
            float4 hn;
            hn.x = fmaf(dec, hv0 - c0, c0);
            hn.y = fmaf(dec, hv1 - c1, c1);
            hn.z = fmaf(dec, hv2 - c2, c2);
            hn.w = fmaf(dec, hv3 - c3, c3);
            *(float4*)(out_h + tile + (size_t)n * 64 + d0) = hn;
            uint2 pkd; pkd.x = pk2(hn.x, hn.y); pkd.y = pk2(hn.z, hn.w);
            *(uint2*)((char*)sIn + SWZ(n * 256 + d0 * 2, n)) = pkd;
            hs0 += hn.x; hs1 += hn.y; hs2 += hn.z; hs3 += hn.w;
        }
        #pragma unroll
        for (int m = 1; m < 16; m <<= 1) {
            hs0 += __shfl_xor(hs0, m); hs1 += __shfl_xor(hs1, m);
            hs2 += __shfl_xor(hs2, m); hs3 += __shfl_xor(hs3, m);
        }
        if (cl == 0) {
            float4 hp4 = {hs0, hs1, hs2, hs3};
            *(float4*)&s_scr[rh * 64 + d0] = hp4;   // h-part bands [0:128)
        }
    }
    __syncthreads();   // B4: h_new in sIn visible; sHid reads done

    // ===== msg L1: K=64, wave w owns cols [32w, 32w+32); 8 reads / 16 MFMA =====
    {
        f4v acc[2][4];
        #pragma unroll
        for (int i = 0; i < 2; i++)
            #pragma unroll
            for (int j = 0; j < 4; j++) acc[i][j] = fzero;
        __builtin_amdgcn_s_setprio(1);
        #pragma unroll
        for (int ks = 0; ks < 2; ks++) {
            const int k0 = ks * 32 + q * 8;
            const s8v aw0 = (ks == 0) ? awP0
                : *(const s8v*)(wm1 + (size_t)(32 * w + cl) * 64 + k0);
            const s8v aw1 = (ks == 0) ? awP1
                : *(const s8v*)(wm1 + (size_t)(32 * w + 16 + cl) * 64 + k0);
            #pragma unroll
            for (int rt = 0; rt < 4; rt++) {
                const int ar = rt * 16 + cl;
                const s8v bi = *(const s8v*)((const char*)sIn + SWZ(ar * 256 + k0 * 2, ar));
                acc[0][rt] = __builtin_amdgcn_mfma_f32_16x16x32_bf16(aw0, bi, acc[0][rt], 0, 0, 0);
                acc[1][rt] = __builtin_amdgcn_mfma_f32_16x16x32_bf16(aw1, bi, acc[1][rt], 0, 0, 0);
            }
        }
        __builtin_amdgcn_s_setprio(0);
        // PREFETCH: msg L2 ks=0,1 frags
        awP0 = *(const s8v*)(wm2 + (size_t)dA * 256 + q * 8);
        awP1 = *(const s8v*)(wm2 + (size_t)dA * 256 + 32 + q * 8);
        #pragma unroll
        for (int ct = 0; ct < 2; ct++) {
            const int hc0 = 32 * w + ct * 16 + q * 4;
            const float4 b1 = *(const float4*)&mb1[hc0];
            const float4 g1 = *(const float4*)&mgs1[g * 256 + hc0];
            const float4 o1 = *(const float4*)&mgb1[g * 256 + hc0];
            #pragma unroll
            for (int rt = 0; rt < 4; rt++) {
                const int n = rt * 16 + cl;
                const float t0 = fast_tanh(fmaf(acc[ct][rt][0] + b1.x, g1.x, o1.x));
                const float t1 = fast_tanh(fmaf(acc[ct][rt][1] + b1.y, g1.y, o1.y));
                const float t2 = fast_tanh(fmaf(acc[ct][rt][2] + b1.z, g1.z, o1.z));
                const float t3 = fast_tanh(fmaf(acc[ct][rt][3] + b1.w, g1.w, o1.w));
                uint2 pkd; pkd.x = pk2(t0, t1); pkd.y = pk2(t2, t3);
                *(uint2*)((char*)sHid + SWZ(n * 512 + hc0 * 2, n)) = pkd;
            }
        }
    }
    __syncthreads();   // B5: full mhid visible

    // ===== msg L2: K=256 single pass + msg epilogue =====
    {
        f4v a6[2][2];
        a6[0][0] = fzero; a6[0][1] = fzero; a6[1][0] = fzero; a6[1][1] = fzero;
        __builtin_amdgcn_s_setprio(1);
        #pragma unroll
        for (int ks = 0; ks < 8; ks++) {
            const int k0 = ks * 32 + q * 8;
            const s8v aw = (ks == 0) ? awP0 : (ks == 1) ? awP1
                : *(const s8v*)(wm2 + (size_t)dA * 256 + k0);
            #pragma unroll
            for (int nt = 0; nt < 2; nt++) {
                const int ar = (rh * 2 + nt) * 16 + cl;
                const s8v bh = *(const s8v*)((const char*)sHid + SWZ(ar * 512 + k0 * 2, ar));
                a6[nt][ks & 1] = __builtin_amdgcn_mfma_f32_16x16x32_bf16(aw, bh, a6[nt][ks & 1], 0, 0, 0);
            }
        }
        __builtin_amdgcn_s_setprio(0);
        // epilogue: msg_new (+nid, float4 stores), mmean partials, readout
        const float4 b2 = *(const float4*)&mb2[d0];
        const float4 g2 = *(const float4*)&mgs2[g * 64 + d0];
        const float4 o2 = *(const float4*)&mgb2[g * 64 + d0];
        float ms0 = 0.f, ms1 = 0.f, ms2 = 0.f, ms3 = 0.f;
        float ro0 = 0.f, ro1 = 0.f, ro2 = 0.f, ro3 = 0.f;
        #pragma unroll
        for (int nt = 0; nt < 2; nt++) {
            const int n = (rh * 2 + nt) * 16 + cl;
            const float4 nv = *(const float4*)(nidp + (size_t)c * 4096 + (size_t)n * 64 + d0);
            float4 mv;
            mv.x = fast_tanh(fmaf(a6[nt][0][0] + a6[nt][1][0] + b2.x, g2.x, o2.x)) + nv.x;
            mv.y = fast_tanh(fmaf(a6[nt][0][1] + a6[nt][1][1] + b2.y, g2.y, o2.y)) + nv.y;
            mv.z = fast_tanh(fmaf(a6[nt][0][2] + a6[nt][1][2] + b2.z, g2.z, o2.z)) + nv.z;
            mv.w = fast_tanh(fmaf(a6[nt][0][3] + a6[nt][1][3] + b2.w, g2.w, o2.w)) + nv.w;
            *(float4*)(out_msg + tile + (size_t)n * 64 + d0) = mv;
            ms0 += mv.x; ms1 += mv.y; ms2 += mv.z; ms3 += mv.w;
            if (nt == 0 && rh == 0 && n >= 4 && n < 8) {
                ro0 = mv.x; ro1 = mv.y; ro2 = mv.z; ro3 = mv.w;
            }
        }
        #pragma unroll
        for (int m = 1; m < 16; m <<= 1) {
            ms0 += __shfl_xor(ms0, m); ms1 += __shfl_xor(ms1, m);
            ms2 += __shfl_xor(ms2, m); ms3 += __shfl_xor(ms3, m);
        }
        if (cl == 0) {
            float4 mp4 = {ms0, ms1, ms2, ms3};
            *(float4*)&s_scr[128 + rh * 64 + d0] = mp4;   // m-part bands [128:256)
        }
        // readout: sum over n=4..7 (lanes cl=4..7, rh==0)
        ro0 += __shfl_xor(ro0, 1); ro1 += __shfl_xor(ro1, 1);
        ro2 += __shfl_xor(ro2, 1); ro3 += __shfl_xor(ro3, 1);
        ro0 += __shfl_xor(ro0, 2); ro1 += __shfl_xor(ro1, 2);
        ro2 += __shfl_xor(ro2, 2); ro3 += __shfl_xor(ro3, 2);
        if (rh == 0 && cl == 4) {
            float4 o4 = {ro0 * 0.5f, ro1 * 0.5f, ro2 * 0.5f, ro3 * 0.5f};
            *(float4*)(out_read + ((size_t)b * NCC + c) * 64 + d0) = o4;
        }
    }
    __syncthreads();   // B6

    // ================= P7: feats record (130 values) =================
    if (t < 132) {
        float v = 0.f;
        if (t < 64)        v = (s_scr[t] + s_scr[64 + t]) * (1.f / 64.f);
        else if (t < 128)  v = (s_scr[64 + t] + s_scr[128 + t]) * (1.f / 64.f);
        else if (t == 128) v = (s_wsum[0] + s_wsum[1] + s_wsum[2] + s_wsum[3]
                              + s_wsum[4] + s_wsum[5] + s_wsum[6] + s_wsum[7]) * (1.f / 4096.f);
        else if (t == 129) v = s_dsum * (1.f / 64.f);
        wsf[(size_t)bc * 132 + t] = v;
    }
}

// ---------------------------------------------------------------------------
// Kernel 2: per-cell modulation MLP (distinct weights per cell)
// ---------------------------------------------------------------------------
__global__ __launch_bounds__(256, 2)
void mg_mod_kernel(
    const float* __restrict__ wsf,   const float* __restrict__ modw1,
    const float* __restrict__ modb1, const float* __restrict__ modw2,
    const float* __restrict__ modb2, const float* __restrict__ ctxp,
    const float* __restrict__ bglp,  float* __restrict__ out_ctx,
    float* __restrict__ out_bg)
{
    const int c = blockIdx.x;
    const int t = threadIdx.x;
    __shared__ float s_f[8][MODIN];
    __shared__ float s_h2[8][HMODL];

    for (int k = t; k < 8 * MODIN; k += 256) {
        const int b = k / MODIN, f = k - b * MODIN;
        float v;
        if (f < 130)      v = wsf[((size_t)b * NCC + c) * 132 + f];
        else if (f < 194) v = ctxp[((size_t)b * NCC + c) * 64 + (f - 130)];
        else              v = bglp[((size_t)b * NCC + c) * 4 + (f - 194)];
        s_f[b][f] = v;
    }
    __syncthreads();

    {
        const int hh = t & 127, bh = (t >> 7) * 4;
        float a0 = 0.f, a1 = 0.f, a2 = 0.f, a3 = 0.f;
        const float* wp = modw1 + (size_t)c * MODIN * HMODL + hh;
        for (int f = 0; f < MODIN; f++) {
            const float wv = wp[(size_t)f * HMODL];
            a0 = fmaf(s_f[bh + 0][f], wv, a0);
            a1 = fmaf(s_f[bh + 1][f], wv, a1);
            a2 = fmaf(s_f[bh + 2][f], wv, a2);
            a3 = fmaf(s_f[bh + 3][f], wv, a3);
        }
        const float bv = modb1[(size_t)c * HMODL + hh];
        s_h2[bh + 0][hh] = fast_tanh(a0 + bv);
        s_h2[bh + 1][hh] = fast_tanh(a1 + bv);
        s_h2[bh + 2][hh] = fast_tanh(a2 + bv);
        s_h2[bh + 3][hh] = fast_tanh(a3 + bv);
    }
    __syncthreads();

    for (int idx = t; idx < 8 * MODOUT; idx += 256) {
        const int b = idx / MODOUT, o = idx - b * MODOUT;
        float acc = modb2[(size_t)c * MODOUT + o];
        const float* wp = modw2 + (size_t)c * HMODL * MODOUT + o;
        const float* hrow = s_h2[b];
        for (int hh = 0; hh < HMODL; hh++)
            acc = fmaf(hrow[hh], wp[(size_t)hh * MODOUT], acc);
        if (o < 64)
            out_ctx[((size_t)b * NCC + c) * 64 + o] =
                ctxp[((size_t)b * NCC + c) * 64 + o] + acc;
        else
            out_bg[((size_t)b * NCC + c) * 4 + (o - 64)] =
                bglp[((size_t)b * NCC + c) * 4 + (o - 64)] + acc;
    }
}

extern "C" void kernel_launch(void* const* d_in, const int* in_sizes, int n_in,
                              void* d_out, int out_size, void* d_ws, size_t ws_size,
                              hipStream_t stream) {
    const float* xp     = (const float*)d_in[0];
    const float* hp     = (const float*)d_in[1];
    const float* msgp   = (const float*)d_in[2];
    const float* Wp     = (const float*)d_in[3];
    const float* decayp = (const float*)d_in[4];
    const float* ctxp   = (const float*)d_in[5];
    const float* bglp   = (const float*)d_in[6];
    const float* nidp   = (const float*)d_in[7];
    const float* sw1    = (const float*)d_in[8];
    const float* sb1    = (const float*)d_in[9];
    const float* sgs1   = (const float*)d_in[10];
    const float* sgb1   = (const float*)d_in[11];
    const float* sw2    = (const float*)d_in[12];
    const float* sb2    = (const float*)d_in[13];
    const float* sgs2   = (const float*)d_in[14];
    const float* sgb2   = (const float*)d_in[15];
    const float* mw1    = (const float*)d_in[16];
    const float* mb1    = (const float*)d_in[17];
    const float* mgs1   = (const float*)d_in[18];
    const float* mgb1   = (const float*)d_in[19];
    const float* mw2    = (const float*)d_in[20];
    const float* mb2    = (const float*)d_in[21];
    const float* mgs2   = (const float*)d_in[22];
    const float* mgb2   = (const float*)d_in[23];
    const float* iw     = (const float*)d_in[24];
    const float* ibias  = (const float*)d_in[25];
    const float* modw1  = (const float*)d_in[26];
    const float* modb1  = (const float*)d_in[27];
    const float* modw2  = (const float*)d_in[28];
    const float* modb2  = (const float*)d_in[29];
    const int*   c2g    = (const int*)d_in[30];

    float* out      = (float*)d_out;
    float* out_read = out;                 // 524288
    float* out_h    = out_read + 524288;   // 33554432
    float* out_msg  = out_h + 33554432;    // 33554432
    float* out_ctx  = out_msg + 33554432;  // 524288
    float* out_bg   = out_ctx + 524288;    // 32768

    ushort_t* wb  = (ushort_t*)d_ws;                          // 160KB bf16 weights
    float*    wsf = (float*)((char*)d_ws + FEATS_BYTE_OFF);   // 8192 x 132 f32

    mg_cvtw<<<320, 256, 0, stream>>>(sw1, sw2, mw1, mw2, wb);

    // inject -> head of each out_h tile (read by P1, overwritten by state epilogue)
    mg_inject<<<1024, 256, 0, stream>>>(xp, iw, ibias, c2g, out_h);

    mg_cell_kernel<<<8192, 512, 0, stream>>>(
        hp, msgp, Wp, decayp, bglp, nidp,
        sb1, sgs1, sgb1, sb2, sgs2, sgb2,
        mb1, mgs1, mgb1, mb2, mgs2, mgb2,
        c2g, wb, out_read, out_h, out_msg, wsf);

    mg_mod_kernel<<<1024, 256, 0, stream>>>(
        wsf, modw1, modb1, modw2, modb2, ctxp, bglp, out_ctx, out_bg);
}